// Round 2
// baseline (1062.496 us; speedup 1.0000x reference)
//
#include <hip/hip_runtime.h>
#include <hip/hip_bf16.h>

typedef __bf16 bf16x8 __attribute__((ext_vector_type(8)));
typedef float f32x4 __attribute__((ext_vector_type(4)));

#define TOKENS 4096
#define EDIM 512
#define FDIM 2048
#define SEQ 512
#define NHEAD 8
#define HDIM 64

// ---------------- transpose + f32->bf16 convert: dst[c*R + r] = src[r*C + c]
__global__ __launch_bounds__(256) void transpose_bf16(
    const float* __restrict__ src, __bf16* __restrict__ dst, int R, int C) {
  __shared__ float t[32][33];
  int c0 = blockIdx.x * 32, r0 = blockIdx.y * 32;
  int tx = threadIdx.x & 31, ty = threadIdx.x >> 5;  // ty 0..7
  for (int rr = ty; rr < 32; rr += 8) {
    int r = r0 + rr, c = c0 + tx;
    if (r < R && c < C) t[rr][tx] = src[(size_t)r * C + c];
  }
  __syncthreads();
  for (int rr = ty; rr < 32; rr += 8) {
    int c = c0 + rr, r = r0 + tx;
    if (r < R && c < C) dst[(size_t)c * R + r] = (__bf16)t[tx][rr];
  }
}

// ---------------- generic bf16 MFMA GEMM: C = op(A(f32,MxK) @ Bt(bf16,NxK) + bias [+ resid])
__global__ __launch_bounds__(256) void gemm_bf16(
    const float* __restrict__ A, const __bf16* __restrict__ Bt,
    const float* __restrict__ bias, const float* __restrict__ resid,
    float* __restrict__ C, int M, int N, int K, int relu) {
  __shared__ __attribute__((aligned(16))) __bf16 As[64][40];
  __shared__ __attribute__((aligned(16))) __bf16 Bs[64][40];
  int tid = threadIdx.x;
  int m0 = blockIdx.y * 64, n0 = blockIdx.x * 64;
  int wave = tid >> 6, lane = tid & 63;
  int wr = (wave >> 1) * 32, wc = (wave & 1) * 32;
  f32x4 acc[2][2] = {};
  int srow = tid >> 2;         // 0..63
  int skg = (tid & 3) * 8;     // 0,8,16,24
  const int fr = lane & 15, fk = (lane >> 4) * 8;
  for (int k0 = 0; k0 < K; k0 += 32) {
    const float* ap = A + (size_t)(m0 + srow) * K + k0 + skg;
    float4 v0 = *(const float4*)ap;
    float4 v1 = *(const float4*)(ap + 4);
    bf16x8 pk;
    pk[0] = (__bf16)v0.x; pk[1] = (__bf16)v0.y; pk[2] = (__bf16)v0.z; pk[3] = (__bf16)v0.w;
    pk[4] = (__bf16)v1.x; pk[5] = (__bf16)v1.y; pk[6] = (__bf16)v1.z; pk[7] = (__bf16)v1.w;
    *(bf16x8*)&As[srow][skg] = pk;
    bf16x8 bv = *(const bf16x8*)(Bt + (size_t)(n0 + srow) * K + k0 + skg);
    *(bf16x8*)&Bs[srow][skg] = bv;
    __syncthreads();
    bf16x8 a0 = *(const bf16x8*)&As[wr + fr][fk];
    bf16x8 a1 = *(const bf16x8*)&As[wr + 16 + fr][fk];
    bf16x8 b0 = *(const bf16x8*)&Bs[wc + fr][fk];
    bf16x8 b1 = *(const bf16x8*)&Bs[wc + 16 + fr][fk];
    acc[0][0] = __builtin_amdgcn_mfma_f32_16x16x32_bf16(a0, b0, acc[0][0], 0, 0, 0);
    acc[0][1] = __builtin_amdgcn_mfma_f32_16x16x32_bf16(a0, b1, acc[0][1], 0, 0, 0);
    acc[1][0] = __builtin_amdgcn_mfma_f32_16x16x32_bf16(a1, b0, acc[1][0], 0, 0, 0);
    acc[1][1] = __builtin_amdgcn_mfma_f32_16x16x32_bf16(a1, b1, acc[1][1], 0, 0, 0);
    __syncthreads();
  }
  for (int mi = 0; mi < 2; mi++)
    for (int ni = 0; ni < 2; ni++)
      for (int r = 0; r < 4; r++) {
        int row = m0 + wr + mi * 16 + ((lane >> 4) * 4) + r;
        int col = n0 + wc + ni * 16 + (lane & 15);
        float v = acc[mi][ni][r] + bias[col];
        if (resid) v += resid[(size_t)row * N + col];
        if (relu) v = fmaxf(v, 0.f);
        C[(size_t)row * N + col] = v;
      }
}

// ---------------- attention: 1 wave per (b,h,i) row; 4 rows per block
__global__ __launch_bounds__(256) void attn_kernel(
    const float* __restrict__ qb, const float* __restrict__ kb,
    const float* __restrict__ vb, const float* __restrict__ dist,
    const int* __restrict__ dtimes, const int* __restrict__ maskp,
    const float* __restrict__ pos_emb, float* __restrict__ outp) {
  __shared__ __attribute__((aligned(16))) float peT[64][133];  // peT[d][t]
  __shared__ int dts[SEQ];
  __shared__ int msk[SEQ];
  __shared__ __attribute__((aligned(16))) float qrow[4][64];
  __shared__ float qz[4][132];
  __shared__ float aw[4][SEQ];

  int tid = threadIdx.x, wave = tid >> 6, lane = tid & 63;
  int g = blockIdx.x;
  int i4 = g & 127;            // S/4 = 128
  int bh = g >> 7;
  int h = bh & 7, b = bh >> 3;
  int i = i4 * 4 + wave;

  for (int idx = tid; idx < 129 * 64; idx += 256) {
    int t = idx >> 6, d = idx & 63;
    peT[d][t] = pos_emb[idx];
  }
  for (int j = tid; j < SEQ; j += 256) {
    dts[j] = dtimes[b * SEQ + j];
    msk[j] = maskp[b * SEQ + j];
  }
  float qd = qb[((size_t)b * SEQ + i) * EDIM + h * HDIM + lane];
  qrow[wave][lane] = qd;
  __syncthreads();

  int dti = dts[i];
  // qz[t] = q . pos_emb[t]
  for (int p = 0; p < 3; p++) {
    int t = lane + p * 64;
    if (t < 129) {
      float s = 0.f;
#pragma unroll 8
      for (int d = 0; d < 64; d++) s += qrow[wave][d] * peT[d][t];
      qz[wave][t] = s;
    }
  }
  // scores: lane owns j = jj*64 + lane
  float sreg[8];
  float mx = -1e30f;
  const float scale = 0.125f;
  const float* kbase = kb + (size_t)b * SEQ * EDIM + h * HDIM;
  const float* drow = dist + ((size_t)b * SEQ + i) * SEQ;
  for (int jj = 0; jj < 8; jj++) {
    int j = jj * 64 + lane;
    const float4* kp = (const float4*)(kbase + (size_t)j * EDIM);
    float acc = 0.f;
#pragma unroll
    for (int d4 = 0; d4 < 16; d4++) {
      float4 kv = kp[d4];
      float4 qv = *(const float4*)&qrow[wave][d4 * 4];
      acc += kv.x * qv.x + kv.y * qv.y + kv.z * qv.z + kv.w * qv.w;
    }
    int t = dts[j] - dti;
    t = min(max(t, -64), 64) + 64;
    float s = (acc + qz[wave][t]) * scale + 0.6f * drow[j];
    if (msk[j] == 0) s = -1e9f;
    sreg[jj] = s;
    mx = fmaxf(mx, s);
  }
  for (int o = 32; o; o >>= 1) mx = fmaxf(mx, __shfl_xor(mx, o));
  float sum = 0.f;
  for (int jj = 0; jj < 8; jj++) {
    sreg[jj] = __expf(sreg[jj] - mx);
    sum += sreg[jj];
  }
  for (int o = 32; o; o >>= 1) sum += __shfl_xor(sum, o);
  float inv = 1.0f / sum;
  for (int jj = 0; jj < 8; jj++) aw[wave][jj * 64 + lane] = sreg[jj] * inv;
  // PV: lane owns d = lane
  const float* vbase = vb + (size_t)b * SEQ * EDIM + h * HDIM + lane;
  float acc = 0.f;
#pragma unroll 4
  for (int j = 0; j < SEQ; j++) {
    float a = aw[wave][j];
    int t = dts[j] - dti;
    t = min(max(t, -64), 64) + 64;
    acc += a * (vbase[(size_t)j * EDIM] + peT[lane][t]);
  }
  outp[((size_t)b * SEQ + i) * EDIM + h * HDIM + lane] = acc;
}

// ---------------- layernorm over rows of 512
__global__ __launch_bounds__(64) void ln_kernel(
    const float* __restrict__ in, const float* __restrict__ g,
    const float* __restrict__ bta, float* __restrict__ out) {
  int row = blockIdx.x, lane = threadIdx.x;
  const float* p = in + (size_t)row * EDIM;
  float4 v0 = *(const float4*)(p + lane * 8);
  float4 v1 = *(const float4*)(p + lane * 8 + 4);
  float vals[8] = {v0.x, v0.y, v0.z, v0.w, v1.x, v1.y, v1.z, v1.w};
  float s = 0.f;
  for (int j = 0; j < 8; j++) s += vals[j];
  for (int o = 32; o; o >>= 1) s += __shfl_xor(s, o);
  float mu = s * (1.0f / EDIM);
  float vs = 0.f;
  for (int j = 0; j < 8; j++) {
    vals[j] -= mu;
    vs += vals[j] * vals[j];
  }
  for (int o = 32; o; o >>= 1) vs += __shfl_xor(vs, o);
  float rs = rsqrtf(vs * (1.0f / EDIM) + 1e-5f);
  for (int j = 0; j < 8; j++) {
    int col = lane * 8 + j;
    out[(size_t)row * EDIM + col] = vals[j] * rs * g[col] + bta[col];
  }
}

extern "C" void kernel_launch(void* const* d_in, const int* in_sizes, int n_in,
                              void* d_out, int out_size, void* d_ws, size_t ws_size,
                              hipStream_t stream) {
  const float* x = (const float*)d_in[0];
  const float* dist = (const float*)d_in[1];
  const int* dtimes = (const int*)d_in[2];
  const int* maskp = (const int*)d_in[3];
  const float* wq_w = (const float*)d_in[4];
  const float* wq_b = (const float*)d_in[5];
  const float* wk_w = (const float*)d_in[6];
  const float* wk_b = (const float*)d_in[7];
  const float* wv_w = (const float*)d_in[8];
  const float* wv_b = (const float*)d_in[9];
  const float* wo_w = (const float*)d_in[10];
  const float* wo_b = (const float*)d_in[11];
  const float* pos_emb = (const float*)d_in[12];
  const float* w1 = (const float*)d_in[13];
  const float* b1 = (const float*)d_in[14];
  const float* w2 = (const float*)d_in[15];
  const float* b2 = (const float*)d_in[16];
  const float* ln1_g = (const float*)d_in[17];
  const float* ln1_b = (const float*)d_in[18];
  const float* ln2_g = (const float*)d_in[19];
  const float* ln2_b = (const float*)d_in[20];
  float* out = (float*)d_out;

  const int M = TOKENS, E = EDIM, F = FDIM;
  float* fws = (float*)d_ws;
  float* qbuf = fws;                         // reused as tmp1 after attention
  float* kbuf = qbuf + (size_t)M * E;        // reused as tmp2 after w2 gemm input read
  float* vbuf = kbuf + (size_t)M * E;
  float* attnb = vbuf + (size_t)M * E;
  float* attno = attnb + (size_t)M * E;
  float* hid = attno + (size_t)M * E;
  __bf16* wqt = (__bf16*)(hid + (size_t)M * F);
  __bf16* wkt = wqt + (size_t)E * E;
  __bf16* wvt = wkt + (size_t)E * E;
  __bf16* wot = wvt + (size_t)E * E;
  __bf16* w1t = wot + (size_t)E * E;
  __bf16* w2t = w1t + (size_t)E * F;

  // weight transposes (f32 -> bf16, [K][N] -> [N][K])
  transpose_bf16<<<dim3(E / 32, E / 32), 256, 0, stream>>>(wq_w, wqt, E, E);
  transpose_bf16<<<dim3(E / 32, E / 32), 256, 0, stream>>>(wk_w, wkt, E, E);
  transpose_bf16<<<dim3(E / 32, E / 32), 256, 0, stream>>>(wv_w, wvt, E, E);
  transpose_bf16<<<dim3(E / 32, E / 32), 256, 0, stream>>>(wo_w, wot, E, E);
  transpose_bf16<<<dim3(F / 32, E / 32), 256, 0, stream>>>(w1, w1t, E, F);
  transpose_bf16<<<dim3(E / 32, F / 32), 256, 0, stream>>>(w2, w2t, F, E);

  // QKV projections
  gemm_bf16<<<dim3(E / 64, M / 64), 256, 0, stream>>>(x, wqt, wq_b, nullptr, qbuf, M, E, E, 0);
  gemm_bf16<<<dim3(E / 64, M / 64), 256, 0, stream>>>(x, wkt, wk_b, nullptr, kbuf, M, E, E, 0);
  gemm_bf16<<<dim3(E / 64, M / 64), 256, 0, stream>>>(x, wvt, wv_b, nullptr, vbuf, M, E, E, 0);

  // attention
  attn_kernel<<<8 * NHEAD * (SEQ / 4), 256, 0, stream>>>(qbuf, kbuf, vbuf, dist, dtimes,
                                                         maskp, pos_emb, attnb);

  // output projection + residual, then LN1
  gemm_bf16<<<dim3(E / 64, M / 64), 256, 0, stream>>>(attnb, wot, wo_b, x, qbuf, M, E, E, 0);
  ln_kernel<<<M, 64, 0, stream>>>(qbuf, ln1_g, ln1_b, attno);

  // FFN
  gemm_bf16<<<dim3(F / 64, M / 64), 256, 0, stream>>>(attno, w1t, b1, nullptr, hid, M, F, E, 1);
  gemm_bf16<<<dim3(E / 64, M / 64), 256, 0, stream>>>(hid, w2t, b2, attno, kbuf, M, E, F, 0);
  ln_kernel<<<M, 64, 0, stream>>>(kbuf, ln2_g, ln2_b, out);
}

// Round 3
// 507.236 us; speedup vs baseline: 2.0947x; 2.0947x over previous
//
#include <hip/hip_runtime.h>
#include <hip/hip_bf16.h>

typedef __bf16 bf16x8 __attribute__((ext_vector_type(8)));
typedef float f32x4 __attribute__((ext_vector_type(4)));

#define TOKENS 4096
#define EDIM 512
#define FDIM 2048
#define SEQ 512
#define NHEAD 8
#define HDIM 64

// ---------------- transpose + f32->bf16 convert: dst[c*R + r] = src[r*C + c]
__global__ __launch_bounds__(256) void transpose_bf16(
    const float* __restrict__ src, __bf16* __restrict__ dst, int R, int C) {
  __shared__ float t[32][33];
  int c0 = blockIdx.x * 32, r0 = blockIdx.y * 32;
  int tx = threadIdx.x & 31, ty = threadIdx.x >> 5;
  for (int rr = ty; rr < 32; rr += 8) {
    int r = r0 + rr, c = c0 + tx;
    if (r < R && c < C) t[rr][tx] = src[(size_t)r * C + c];
  }
  __syncthreads();
  for (int rr = ty; rr < 32; rr += 8) {
    int c = c0 + rr, r = r0 + tx;
    if (r < R && c < C) dst[(size_t)c * R + r] = (__bf16)t[tx][rr];
  }
}

// ---------------- generic bf16 MFMA GEMM (unchanged from round 0)
__global__ __launch_bounds__(256) void gemm_bf16(
    const float* __restrict__ A, const __bf16* __restrict__ Bt,
    const float* __restrict__ bias, const float* __restrict__ resid,
    float* __restrict__ C, int M, int N, int K, int relu) {
  __shared__ __attribute__((aligned(16))) __bf16 As[64][40];
  __shared__ __attribute__((aligned(16))) __bf16 Bs[64][40];
  int tid = threadIdx.x;
  int m0 = blockIdx.y * 64, n0 = blockIdx.x * 64;
  int wave = tid >> 6, lane = tid & 63;
  int wr = (wave >> 1) * 32, wc = (wave & 1) * 32;
  f32x4 acc[2][2] = {};
  int srow = tid >> 2;
  int skg = (tid & 3) * 8;
  const int fr = lane & 15, fk = (lane >> 4) * 8;
  for (int k0 = 0; k0 < K; k0 += 32) {
    const float* ap = A + (size_t)(m0 + srow) * K + k0 + skg;
    float4 v0 = *(const float4*)ap;
    float4 v1 = *(const float4*)(ap + 4);
    bf16x8 pk;
    pk[0] = (__bf16)v0.x; pk[1] = (__bf16)v0.y; pk[2] = (__bf16)v0.z; pk[3] = (__bf16)v0.w;
    pk[4] = (__bf16)v1.x; pk[5] = (__bf16)v1.y; pk[6] = (__bf16)v1.z; pk[7] = (__bf16)v1.w;
    *(bf16x8*)&As[srow][skg] = pk;
    bf16x8 bv = *(const bf16x8*)(Bt + (size_t)(n0 + srow) * K + k0 + skg);
    *(bf16x8*)&Bs[srow][skg] = bv;
    __syncthreads();
    bf16x8 a0 = *(const bf16x8*)&As[wr + fr][fk];
    bf16x8 a1 = *(const bf16x8*)&As[wr + 16 + fr][fk];
    bf16x8 b0 = *(const bf16x8*)&Bs[wc + fr][fk];
    bf16x8 b1 = *(const bf16x8*)&Bs[wc + 16 + fr][fk];
    acc[0][0] = __builtin_amdgcn_mfma_f32_16x16x32_bf16(a0, b0, acc[0][0], 0, 0, 0);
    acc[0][1] = __builtin_amdgcn_mfma_f32_16x16x32_bf16(a0, b1, acc[0][1], 0, 0, 0);
    acc[1][0] = __builtin_amdgcn_mfma_f32_16x16x32_bf16(a1, b0, acc[1][0], 0, 0, 0);
    acc[1][1] = __builtin_amdgcn_mfma_f32_16x16x32_bf16(a1, b1, acc[1][1], 0, 0, 0);
    __syncthreads();
  }
  for (int mi = 0; mi < 2; mi++)
    for (int ni = 0; ni < 2; ni++)
      for (int r = 0; r < 4; r++) {
        int row = m0 + wr + mi * 16 + ((lane >> 4) * 4) + r;
        int col = n0 + wc + ni * 16 + (lane & 15);
        float v = acc[mi][ni][r] + bias[col];
        if (resid) v += resid[(size_t)row * N + col];
        if (relu) v = fmaxf(v, 0.f);
        C[(size_t)row * N + col] = v;
      }
}

// read 16 f32, convert, store as two bf16x8 (dst 16B-aligned)
__device__ inline void cvt16(const float* __restrict__ src, __bf16* dst) {
  float4 f0 = *(const float4*)(src);
  float4 f1 = *(const float4*)(src + 4);
  float4 f2 = *(const float4*)(src + 8);
  float4 f3 = *(const float4*)(src + 12);
  bf16x8 p0, p1;
  p0[0]=(__bf16)f0.x; p0[1]=(__bf16)f0.y; p0[2]=(__bf16)f0.z; p0[3]=(__bf16)f0.w;
  p0[4]=(__bf16)f1.x; p0[5]=(__bf16)f1.y; p0[6]=(__bf16)f1.z; p0[7]=(__bf16)f1.w;
  p1[0]=(__bf16)f2.x; p1[1]=(__bf16)f2.y; p1[2]=(__bf16)f2.z; p1[3]=(__bf16)f2.w;
  p1[4]=(__bf16)f3.x; p1[5]=(__bf16)f3.y; p1[6]=(__bf16)f3.z; p1[7]=(__bf16)f3.w;
  *(bf16x8*)(dst) = p0;
  *(bf16x8*)(dst + 8) = p1;
}

// ---------------- MFMA attention: block = (b, h, 64-row q-tile); 4 waves x 16 rows
__global__ __launch_bounds__(256) void attn_mfma(
    const float* __restrict__ qb, const float* __restrict__ kb,
    const float* __restrict__ vb, const float* __restrict__ dist,
    const int* __restrict__ dtimes, const int* __restrict__ maskp,
    const float* __restrict__ pos_emb, float* __restrict__ outp) {
  __shared__ __attribute__((aligned(16))) __bf16 QL[64][72];
  __shared__ __attribute__((aligned(16))) __bf16 KL[64][72];
  __shared__ __attribute__((aligned(16))) __bf16 VT[64][72];    // VT[d][j]
  __shared__ __attribute__((aligned(16))) __bf16 peL[144][72];  // [t][d], rows >=129 zero
  __shared__ __attribute__((aligned(16))) __bf16 peT[64][136];  // [d][t]
  __shared__ __bf16 qzL[64][132];                               // [i][t]
  __shared__ __attribute__((aligned(16))) __bf16 distL[64][72];
  __shared__ __attribute__((aligned(16))) __bf16 PL[4][16][72];
  __shared__ __attribute__((aligned(16))) float psumL[64][132]; // [i][t]
  __shared__ int dtsL[SEQ];
  __shared__ int mskL[SEQ];

  const int tid = threadIdx.x;
  const int w = tid >> 6, l = tid & 63;
  const int c = l & 15, g = l >> 4;
  const int bid = blockIdx.x;
  const int qt = bid & 7, h = (bid >> 3) & 7, b = bid >> 6;
  const int qbase = qt * 64;

  // ---- one-time staging
  {
    int r = tid >> 2, d0 = (tid & 3) * 16;
    for (int sweep = 0; sweep < 3; sweep++) {
      int rr = r + sweep * 64;
      if (rr >= 144) break;
      if (rr < 129) {
        float vals[16];
        *(float4*)&vals[0]  = *(const float4*)(pos_emb + rr * 64 + d0);
        *(float4*)&vals[4]  = *(const float4*)(pos_emb + rr * 64 + d0 + 4);
        *(float4*)&vals[8]  = *(const float4*)(pos_emb + rr * 64 + d0 + 8);
        *(float4*)&vals[12] = *(const float4*)(pos_emb + rr * 64 + d0 + 12);
        bf16x8 p0, p1;
        for (int q = 0; q < 8; q++) { p0[q] = (__bf16)vals[q]; p1[q] = (__bf16)vals[q + 8]; }
        *(bf16x8*)&peL[rr][d0] = p0;
        *(bf16x8*)&peL[rr][d0 + 8] = p1;
        for (int q = 0; q < 16; q++) {
          int kk = (q + rr) & 15;  // swizzle to spread LDS banks
          peT[d0 + kk][rr] = (__bf16)vals[kk];
        }
      } else {
        bf16x8 z = {};
        *(bf16x8*)&peL[rr][d0] = z;
        *(bf16x8*)&peL[rr][d0 + 8] = z;
      }
    }
    cvt16(qb + ((size_t)(b * SEQ + qbase + r)) * EDIM + h * HDIM + d0, &QL[r][d0]);
    for (int idx = tid; idx < SEQ; idx += 256) {
      dtsL[idx] = dtimes[b * SEQ + idx];
      mskL[idx] = maskp[b * SEQ + idx];
    }
    for (int idx = tid; idx < 64 * 132; idx += 256) ((float*)psumL)[idx] = 0.f;
  }
  __syncthreads();

  // cached Q A-fragments (row = c, k = g*8 [+32])
  bf16x8 aq0 = *(bf16x8*)&QL[w * 16 + c][g * 8];
  bf16x8 aq1 = *(bf16x8*)&QL[w * 16 + c][32 + g * 8];

  // ---- qz[i][t] = q_i . pos_emb[t]  via MFMA (9 n-tiles cover t<144)
  for (int n = 0; n < 9; n++) {
    f32x4 acc = {};
    bf16x8 b0 = *(bf16x8*)&peL[n * 16 + c][g * 8];
    bf16x8 b1 = *(bf16x8*)&peL[n * 16 + c][32 + g * 8];
    acc = __builtin_amdgcn_mfma_f32_16x16x32_bf16(aq0, b0, acc, 0, 0, 0);
    acc = __builtin_amdgcn_mfma_f32_16x16x32_bf16(aq1, b1, acc, 0, 0, 0);
    int t = n * 16 + c;
    if (t < 132)
      for (int r = 0; r < 4; r++) qzL[w * 16 + g * 4 + r][t] = (__bf16)acc[r];
  }
  __syncthreads();

  int dti_r[4];
  for (int r = 0; r < 4; r++) dti_r[r] = dtsL[qbase + w * 16 + g * 4 + r];

  // ---- pass 1: exact row max
  float mrow[4] = {-3e38f, -3e38f, -3e38f, -3e38f};
  for (int jt = 0; jt < 8; jt++) {
    __syncthreads();
    {
      int r = tid >> 2, d0 = (tid & 3) * 16;
      cvt16(kb + ((size_t)(b * SEQ + jt * 64 + r)) * EDIM + h * HDIM + d0, &KL[r][d0]);
      cvt16(dist + ((size_t)(b * SEQ + qbase + r)) * SEQ + jt * 64 + d0, &distL[r][d0]);
    }
    __syncthreads();
    for (int n = 0; n < 4; n++) {
      f32x4 acc = {};
      bf16x8 bk0 = *(bf16x8*)&KL[n * 16 + c][g * 8];
      bf16x8 bk1 = *(bf16x8*)&KL[n * 16 + c][32 + g * 8];
      acc = __builtin_amdgcn_mfma_f32_16x16x32_bf16(aq0, bk0, acc, 0, 0, 0);
      acc = __builtin_amdgcn_mfma_f32_16x16x32_bf16(aq1, bk1, acc, 0, 0, 0);
      int jl = n * 16 + c, jg = jt * 64 + jl;
      int dtj = dtsL[jg];
      bool mk = (mskL[jg] == 0);
      for (int r = 0; r < 4; r++) {
        int il = w * 16 + g * 4 + r;
        int t = min(max(dtj - dti_r[r], -64), 64) + 64;
        float s = (acc[r] + (float)qzL[il][t]) * 0.125f + 0.6f * (float)distL[il][jl];
        if (mk) s = -1e9f;
        mrow[r] = fmaxf(mrow[r], s);
      }
    }
  }
  for (int r = 0; r < 4; r++)
    for (int off = 1; off < 16; off <<= 1)
      mrow[r] = fmaxf(mrow[r], __shfl_xor(mrow[r], off));

  // ---- pass 2: normalized P via exp(s-m); PV MFMA; psum bins
  float lsum[4] = {0.f, 0.f, 0.f, 0.f};
  f32x4 Oacc[4] = {};
  for (int jt = 0; jt < 8; jt++) {
    __syncthreads();
    {
      int r = tid >> 2, d0 = (tid & 3) * 16;
      cvt16(kb + ((size_t)(b * SEQ + jt * 64 + r)) * EDIM + h * HDIM + d0, &KL[r][d0]);
      cvt16(dist + ((size_t)(b * SEQ + qbase + r)) * SEQ + jt * 64 + d0, &distL[r][d0]);
      float vals[16];
      const float* vp = vb + ((size_t)(b * SEQ + jt * 64 + r)) * EDIM + h * HDIM + d0;
      *(float4*)&vals[0]  = *(const float4*)(vp);
      *(float4*)&vals[4]  = *(const float4*)(vp + 4);
      *(float4*)&vals[8]  = *(const float4*)(vp + 8);
      *(float4*)&vals[12] = *(const float4*)(vp + 12);
      for (int q = 0; q < 16; q++) {
        int kk = (q + r) & 15;
        VT[d0 + kk][r] = (__bf16)vals[kk];
      }
    }
    __syncthreads();
    for (int n = 0; n < 4; n++) {
      f32x4 acc = {};
      bf16x8 bk0 = *(bf16x8*)&KL[n * 16 + c][g * 8];
      bf16x8 bk1 = *(bf16x8*)&KL[n * 16 + c][32 + g * 8];
      acc = __builtin_amdgcn_mfma_f32_16x16x32_bf16(aq0, bk0, acc, 0, 0, 0);
      acc = __builtin_amdgcn_mfma_f32_16x16x32_bf16(aq1, bk1, acc, 0, 0, 0);
      int jl = n * 16 + c, jg = jt * 64 + jl;
      int dtj = dtsL[jg];
      bool mk = (mskL[jg] == 0);
      for (int r = 0; r < 4; r++) {
        int il = w * 16 + g * 4 + r;
        int t = min(max(dtj - dti_r[r], -64), 64) + 64;
        float s = (acc[r] + (float)qzL[il][t]) * 0.125f + 0.6f * (float)distL[il][jl];
        if (mk) s = -1e9f;
        float p = __expf(s - mrow[r]);
        lsum[r] += p;
        atomicAdd(&psumL[il][t], p);
        PL[w][g * 4 + r][jl] = (__bf16)p;
      }
    }
    __syncthreads();
    bf16x8 ap0 = *(bf16x8*)&PL[w][c][g * 8];
    bf16x8 ap1 = *(bf16x8*)&PL[w][c][32 + g * 8];
    for (int dn = 0; dn < 4; dn++) {
      bf16x8 bv0 = *(bf16x8*)&VT[dn * 16 + c][g * 8];
      bf16x8 bv1 = *(bf16x8*)&VT[dn * 16 + c][32 + g * 8];
      Oacc[dn] = __builtin_amdgcn_mfma_f32_16x16x32_bf16(ap0, bv0, Oacc[dn], 0, 0, 0);
      Oacc[dn] = __builtin_amdgcn_mfma_f32_16x16x32_bf16(ap1, bv1, Oacc[dn], 0, 0, 0);
    }
  }
  __syncthreads();

  float linv[4];
  for (int r = 0; r < 4; r++) {
    float s = lsum[r];
    for (int off = 1; off < 16; off <<= 1) s += __shfl_xor(s, off);
    linv[r] = 1.0f / s;
  }

  // ---- z-term (psum @ pos_emb) + output
  for (int dn = 0; dn < 4; dn++) {
    int col = dn * 16 + c;
    for (int r = 0; r < 4; r++) {
      int iw = w * 16 + g * 4 + r;
      float z = 0.f;
      for (int t0 = 0; t0 < 16; t0++) {
        bf16x8 pe8 = *(bf16x8*)&peT[col][t0 * 8];
        f32x4 ps0 = *(f32x4*)&psumL[iw][t0 * 8];
        f32x4 ps1 = *(f32x4*)&psumL[iw][t0 * 8 + 4];
        z += ps0[0] * (float)pe8[0] + ps0[1] * (float)pe8[1] + ps0[2] * (float)pe8[2] +
             ps0[3] * (float)pe8[3] + ps1[0] * (float)pe8[4] + ps1[1] * (float)pe8[5] +
             ps1[2] * (float)pe8[6] + ps1[3] * (float)pe8[7];
      }
      z += psumL[iw][128] * (float)peT[col][128];
      outp[((size_t)(b * SEQ + qbase + iw)) * EDIM + h * HDIM + col] =
          (Oacc[dn][r] + z) * linv[r];
    }
  }
}

// ---------------- layernorm over rows of 512
__global__ __launch_bounds__(64) void ln_kernel(
    const float* __restrict__ in, const float* __restrict__ g,
    const float* __restrict__ bta, float* __restrict__ out) {
  int row = blockIdx.x, lane = threadIdx.x;
  const float* p = in + (size_t)row * EDIM;
  float4 v0 = *(const float4*)(p + lane * 8);
  float4 v1 = *(const float4*)(p + lane * 8 + 4);
  float vals[8] = {v0.x, v0.y, v0.z, v0.w, v1.x, v1.y, v1.z, v1.w};
  float s = 0.f;
  for (int j = 0; j < 8; j++) s += vals[j];
  for (int o = 32; o; o >>= 1) s += __shfl_xor(s, o);
  float mu = s * (1.0f / EDIM);
  float vs = 0.f;
  for (int j = 0; j < 8; j++) {
    vals[j] -= mu;
    vs += vals[j] * vals[j];
  }
  for (int o = 32; o; o >>= 1) vs += __shfl_xor(vs, o);
  float rs = rsqrtf(vs * (1.0f / EDIM) + 1e-5f);
  for (int j = 0; j < 8; j++) {
    int col = lane * 8 + j;
    out[(size_t)row * EDIM + col] = vals[j] * rs * g[col] + bta[col];
  }
}

extern "C" void kernel_launch(void* const* d_in, const int* in_sizes, int n_in,
                              void* d_out, int out_size, void* d_ws, size_t ws_size,
                              hipStream_t stream) {
  const float* x = (const float*)d_in[0];
  const float* dist = (const float*)d_in[1];
  const int* dtimes = (const int*)d_in[2];
  const int* maskp = (const int*)d_in[3];
  const float* wq_w = (const float*)d_in[4];
  const float* wq_b = (const float*)d_in[5];
  const float* wk_w = (const float*)d_in[6];
  const float* wk_b = (const float*)d_in[7];
  const float* wv_w = (const float*)d_in[8];
  const float* wv_b = (const float*)d_in[9];
  const float* wo_w = (const float*)d_in[10];
  const float* wo_b = (const float*)d_in[11];
  const float* pos_emb = (const float*)d_in[12];
  const float* w1 = (const float*)d_in[13];
  const float* b1 = (const float*)d_in[14];
  const float* w2 = (const float*)d_in[15];
  const float* b2 = (const float*)d_in[16];
  const float* ln1_g = (const float*)d_in[17];
  const float* ln1_b = (const float*)d_in[18];
  const float* ln2_g = (const float*)d_in[19];
  const float* ln2_b = (const float*)d_in[20];
  float* out = (float*)d_out;

  const int M = TOKENS, E = EDIM, F = FDIM;
  float* fws = (float*)d_ws;
  float* qbuf = fws;
  float* kbuf = qbuf + (size_t)M * E;
  float* vbuf = kbuf + (size_t)M * E;
  float* attnb = vbuf + (size_t)M * E;
  float* attno = attnb + (size_t)M * E;
  float* hid = attno + (size_t)M * E;
  __bf16* wqt = (__bf16*)(hid + (size_t)M * F);
  __bf16* wkt = wqt + (size_t)E * E;
  __bf16* wvt = wkt + (size_t)E * E;
  __bf16* wot = wvt + (size_t)E * E;
  __bf16* w1t = wot + (size_t)E * E;
  __bf16* w2t = w1t + (size_t)E * F;

  transpose_bf16<<<dim3(E / 32, E / 32), 256, 0, stream>>>(wq_w, wqt, E, E);
  transpose_bf16<<<dim3(E / 32, E / 32), 256, 0, stream>>>(wk_w, wkt, E, E);
  transpose_bf16<<<dim3(E / 32, E / 32), 256, 0, stream>>>(wv_w, wvt, E, E);
  transpose_bf16<<<dim3(E / 32, E / 32), 256, 0, stream>>>(wo_w, wot, E, E);
  transpose_bf16<<<dim3(F / 32, E / 32), 256, 0, stream>>>(w1, w1t, E, F);
  transpose_bf16<<<dim3(E / 32, F / 32), 256, 0, stream>>>(w2, w2t, F, E);

  gemm_bf16<<<dim3(E / 64, M / 64), 256, 0, stream>>>(x, wqt, wq_b, nullptr, qbuf, M, E, E, 0);
  gemm_bf16<<<dim3(E / 64, M / 64), 256, 0, stream>>>(x, wkt, wk_b, nullptr, kbuf, M, E, E, 0);
  gemm_bf16<<<dim3(E / 64, M / 64), 256, 0, stream>>>(x, wvt, wv_b, nullptr, vbuf, M, E, E, 0);

  attn_mfma<<<8 * NHEAD * (SEQ / 64), 256, 0, stream>>>(qbuf, kbuf, vbuf, dist, dtimes,
                                                        maskp, pos_emb, attnb);

  gemm_bf16<<<dim3(E / 64, M / 64), 256, 0, stream>>>(attnb, wot, wo_b, x, qbuf, M, E, E, 0);
  ln_kernel<<<M, 64, 0, stream>>>(qbuf, ln1_g, ln1_b, attno);

  gemm_bf16<<<dim3(F / 64, M / 64), 256, 0, stream>>>(attno, w1t, b1, nullptr, hid, M, F, E, 1);
  gemm_bf16<<<dim3(E / 64, M / 64), 256, 0, stream>>>(hid, w2t, b2, attno, kbuf, M, E, F, 0);
  ln_kernel<<<M, 64, 0, stream>>>(kbuf, ln2_g, ln2_b, out);
}

// Round 5
// 368.291 us; speedup vs baseline: 2.8849x; 1.3773x over previous
//
#include <hip/hip_runtime.h>
#include <hip/hip_bf16.h>

typedef __bf16 bf16x8 __attribute__((ext_vector_type(8)));
typedef float f32x4 __attribute__((ext_vector_type(4)));

#define TOKENS 4096
#define EDIM 512
#define FDIM 2048
#define SEQ 512
#define NHEAD 8
#define HDIM 64

// ---------------- transpose + f32->bf16 convert: dst[c*R + r] = src[r*C + c]
__global__ __launch_bounds__(256) void transpose_bf16(
    const float* __restrict__ src, __bf16* __restrict__ dst, int R, int C) {
  __shared__ float t[32][33];
  int c0 = blockIdx.x * 32, r0 = blockIdx.y * 32;
  int tx = threadIdx.x & 31, ty = threadIdx.x >> 5;
  for (int rr = ty; rr < 32; rr += 8) {
    int r = r0 + rr, c = c0 + tx;
    if (r < R && c < C) t[rr][tx] = src[(size_t)r * C + c];
  }
  __syncthreads();
  for (int rr = ty; rr < 32; rr += 8) {
    int c = c0 + rr, r = r0 + tx;
    if (r < R && c < C) dst[(size_t)c * R + r] = (__bf16)t[tx][rr];
  }
}

// ---------------- generic bf16 MFMA GEMM (unchanged)
__global__ __launch_bounds__(256) void gemm_bf16(
    const float* __restrict__ A, const __bf16* __restrict__ Bt,
    const float* __restrict__ bias, const float* __restrict__ resid,
    float* __restrict__ C, int M, int N, int K, int relu) {
  __shared__ __attribute__((aligned(16))) __bf16 As[64][40];
  __shared__ __attribute__((aligned(16))) __bf16 Bs[64][40];
  int tid = threadIdx.x;
  int m0 = blockIdx.y * 64, n0 = blockIdx.x * 64;
  int wave = tid >> 6, lane = tid & 63;
  int wr = (wave >> 1) * 32, wc = (wave & 1) * 32;
  f32x4 acc[2][2] = {};
  int srow = tid >> 2;
  int skg = (tid & 3) * 8;
  const int fr = lane & 15, fk = (lane >> 4) * 8;
  for (int k0 = 0; k0 < K; k0 += 32) {
    const float* ap = A + (size_t)(m0 + srow) * K + k0 + skg;
    float4 v0 = *(const float4*)ap;
    float4 v1 = *(const float4*)(ap + 4);
    bf16x8 pk;
    pk[0] = (__bf16)v0.x; pk[1] = (__bf16)v0.y; pk[2] = (__bf16)v0.z; pk[3] = (__bf16)v0.w;
    pk[4] = (__bf16)v1.x; pk[5] = (__bf16)v1.y; pk[6] = (__bf16)v1.z; pk[7] = (__bf16)v1.w;
    *(bf16x8*)&As[srow][skg] = pk;
    bf16x8 bv = *(const bf16x8*)(Bt + (size_t)(n0 + srow) * K + k0 + skg);
    *(bf16x8*)&Bs[srow][skg] = bv;
    __syncthreads();
    bf16x8 a0 = *(const bf16x8*)&As[wr + fr][fk];
    bf16x8 a1 = *(const bf16x8*)&As[wr + 16 + fr][fk];
    bf16x8 b0 = *(const bf16x8*)&Bs[wc + fr][fk];
    bf16x8 b1 = *(const bf16x8*)&Bs[wc + 16 + fr][fk];
    acc[0][0] = __builtin_amdgcn_mfma_f32_16x16x32_bf16(a0, b0, acc[0][0], 0, 0, 0);
    acc[0][1] = __builtin_amdgcn_mfma_f32_16x16x32_bf16(a0, b1, acc[0][1], 0, 0, 0);
    acc[1][0] = __builtin_amdgcn_mfma_f32_16x16x32_bf16(a1, b0, acc[1][0], 0, 0, 0);
    acc[1][1] = __builtin_amdgcn_mfma_f32_16x16x32_bf16(a1, b1, acc[1][1], 0, 0, 0);
    __syncthreads();
  }
  for (int mi = 0; mi < 2; mi++)
    for (int ni = 0; ni < 2; ni++)
      for (int r = 0; r < 4; r++) {
        int row = m0 + wr + mi * 16 + ((lane >> 4) * 4) + r;
        int col = n0 + wc + ni * 16 + (lane & 15);
        float v = acc[mi][ni][r] + bias[col];
        if (resid) v += resid[(size_t)row * N + col];
        if (relu) v = fmaxf(v, 0.f);
        C[(size_t)row * N + col] = v;
      }
}

// read 16 f32, convert, store as two bf16x8 (dst 16B-aligned)
__device__ inline void cvt16(const float* __restrict__ src, __bf16* dst) {
  float4 f0 = *(const float4*)(src);
  float4 f1 = *(const float4*)(src + 4);
  float4 f2 = *(const float4*)(src + 8);
  float4 f3 = *(const float4*)(src + 12);
  bf16x8 p0, p1;
  p0[0]=(__bf16)f0.x; p0[1]=(__bf16)f0.y; p0[2]=(__bf16)f0.z; p0[3]=(__bf16)f0.w;
  p0[4]=(__bf16)f1.x; p0[5]=(__bf16)f1.y; p0[6]=(__bf16)f1.z; p0[7]=(__bf16)f1.w;
  p1[0]=(__bf16)f2.x; p1[1]=(__bf16)f2.y; p1[2]=(__bf16)f2.z; p1[3]=(__bf16)f2.w;
  p1[4]=(__bf16)f3.x; p1[5]=(__bf16)f3.y; p1[6]=(__bf16)f3.z; p1[7]=(__bf16)f3.w;
  *(bf16x8*)(dst) = p0;
  *(bf16x8*)(dst + 8) = p1;
}

// ---------------- kernel 1: QZ'[bh][i][tau] = (q_i . pe)[clip(tau - dti,-64,64)+64]
__global__ __launch_bounds__(256) void qz_shift(
    const float* __restrict__ qb, const float* __restrict__ pos_emb,
    const int* __restrict__ dtimes, __bf16* __restrict__ QZg) {
  __shared__ __attribute__((aligned(16))) __bf16 peL[144][72];
  __shared__ __attribute__((aligned(16))) __bf16 QL[64][72];
  __shared__ __attribute__((aligned(16))) float qzf[64][144];
  const int tid = threadIdx.x, w = tid >> 6, l = tid & 63, c = l & 15, g = l >> 4;
  const int bid = blockIdx.x, qt = bid & 7, bh = bid >> 3, h = bh & 7, b = bh >> 3;
  const int qbase = qt * 64;
  const int r = tid >> 2, d0 = (tid & 3) * 16;

  for (int s = 0; s < 3; s++) {
    int rr = r + s * 64;
    if (rr >= 144) break;
    if (rr < 129) {
      cvt16(pos_emb + rr * 64 + d0, &peL[rr][d0]);
    } else {
      bf16x8 z = {};
      *(bf16x8*)&peL[rr][d0] = z;
      *(bf16x8*)&peL[rr][d0 + 8] = z;
    }
  }
  cvt16(qb + ((size_t)(b * SEQ + qbase + r)) * EDIM + h * HDIM + d0, &QL[r][d0]);
  __syncthreads();

  bf16x8 aq0 = *(bf16x8*)&QL[w * 16 + c][g * 8];
  bf16x8 aq1 = *(bf16x8*)&QL[w * 16 + c][32 + g * 8];
  for (int n = 0; n < 9; n++) {
    f32x4 acc = {};
    bf16x8 b0 = *(bf16x8*)&peL[n * 16 + c][g * 8];
    bf16x8 b1 = *(bf16x8*)&peL[n * 16 + c][32 + g * 8];
    acc = __builtin_amdgcn_mfma_f32_16x16x32_bf16(aq0, b0, acc, 0, 0, 0);
    acc = __builtin_amdgcn_mfma_f32_16x16x32_bf16(aq1, b1, acc, 0, 0, 0);
    int t = n * 16 + c;
    for (int r4 = 0; r4 < 4; r4++) qzf[w * 16 + g * 4 + r4][t] = acc[r4];
  }
  __syncthreads();

  int dti = dtimes[b * SEQ + qbase + r];
  int t0 = (tid & 3) * 32;
  for (int q4 = 0; q4 < 4; q4++) {
    bf16x8 o;
    for (int e = 0; e < 8; e++) {
      int tau = t0 + q4 * 8 + e;
      int t = min(max(tau - dti, -64), 64) + 64;
      o[e] = (__bf16)qzf[r][t];
    }
    *(bf16x8*)(QZg + ((size_t)(bh * SEQ + qbase + r)) * 128 + t0 + q4 * 8) = o;
  }
}

// ---------------- kernel 2: single-pass attention main (round-3 sync structure)
__global__ __launch_bounds__(256) void attn_main(
    const float* __restrict__ qb, const float* __restrict__ kb,
    const float* __restrict__ vb, const float* __restrict__ dist,
    const int* __restrict__ dtimes, const int* __restrict__ maskp,
    const __bf16* __restrict__ QZg, float* __restrict__ Og,
    float* __restrict__ Cg, float* __restrict__ Lg) {
  __shared__ __attribute__((aligned(16))) __bf16 QL[64][72];
  __shared__ __attribute__((aligned(16))) __bf16 PL[64][72];
  __shared__ __attribute__((aligned(16))) __bf16 KL[64][72];
  __shared__ __attribute__((aligned(16))) __bf16 VT[64][72];    // VT[d][j]
  __shared__ __attribute__((aligned(16))) __bf16 B1h[128][72];  // one-hot[tau][j]
  __shared__ __attribute__((aligned(16))) __bf16 qzL[64][136];  // QZ'[i][tau]
  __shared__ int dtsL[SEQ];
  __shared__ int mskL[SEQ];

  const int tid = threadIdx.x, w = tid >> 6, l = tid & 63, c = l & 15, g = l >> 4;
  const int bid = blockIdx.x;
  const int qt = bid & 7, h = (bid >> 3) & 7, b = bid >> 6, bh = bid >> 3;
  const int qbase = qt * 64;
  const int r = tid >> 2, d0 = (tid & 3) * 16;

  // prologue
  cvt16(qb + ((size_t)(b * SEQ + qbase + r)) * EDIM + h * HDIM + d0, &QL[r][d0]);
  {
    int ch = (tid & 3) * 32;
    const __bf16* src = QZg + ((size_t)(bh * SEQ + qbase + r)) * 128 + ch;
    for (int q4 = 0; q4 < 4; q4++)
      *(bf16x8*)&qzL[r][ch + q4 * 8] = *(const bf16x8*)(src + q4 * 8);
  }
  for (int idx = tid; idx < SEQ; idx += 256) {
    dtsL[idx] = dtimes[b * SEQ + idx];
    mskL[idx] = maskp[b * SEQ + idx];
  }
  {
    bf16x8 z = {};
    for (int idx = tid; idx < 128 * 9; idx += 256)
      *(bf16x8*)&B1h[idx / 9][(idx % 9) * 8] = z;
  }
  __syncthreads();

  bf16x8 aq0 = *(bf16x8*)&QL[w * 16 + c][g * 8];
  bf16x8 aq1 = *(bf16x8*)&QL[w * 16 + c][32 + g * 8];
  float lsum[4] = {0.f, 0.f, 0.f, 0.f};
  f32x4 Oacc[4] = {};
  f32x4 Cacc[8] = {};

  for (int jt = 0; jt < 8; jt++) {
    __syncthreads();  // (A) prev tile's LDS reads drained
    cvt16(kb + ((size_t)(b * SEQ + jt * 64 + r)) * EDIM + h * HDIM + d0, &KL[r][d0]);
    {
      float vals[16];
      const float* vp = vb + ((size_t)(b * SEQ + jt * 64 + r)) * EDIM + h * HDIM + d0;
      *(float4*)&vals[0]  = *(const float4*)(vp);
      *(float4*)&vals[4]  = *(const float4*)(vp + 4);
      *(float4*)&vals[8]  = *(const float4*)(vp + 8);
      *(float4*)&vals[12] = *(const float4*)(vp + 12);
      for (int q = 0; q < 16; q++) {
        int kk = (q + r) & 15;
        VT[d0 + kk][r] = (__bf16)vals[kk];
      }
    }
    if (tid < 64) {  // one-hot maintenance (same thread, same column, ordered)
      if (jt > 0) {
        int tp = dtsL[(jt - 1) * 64 + tid], tn = dtsL[jt * 64 + tid];
        if (tp != tn) B1h[tp][tid] = (__bf16)0.f;
        B1h[tn][tid] = (__bf16)1.f;
      } else {
        B1h[dtsL[tid]][tid] = (__bf16)1.f;
      }
    }
    __syncthreads();  // (B)

    // dist direct from global (no reuse; L2/HBM path)
    float dv[4][4];
#pragma unroll
    for (int n = 0; n < 4; n++) {
      int jg = jt * 64 + n * 16 + c;
#pragma unroll
      for (int r4 = 0; r4 < 4; r4++) {
        int il = w * 16 + g * 4 + r4;
        dv[n][r4] = dist[((size_t)(b * SEQ + qbase + il)) * SEQ + jg];
      }
    }

    // scores -> P (exp without max; |s| small, softmax shift-invariant)
#pragma unroll
    for (int n = 0; n < 4; n++) {
      f32x4 acc = {};
      bf16x8 bk0 = *(bf16x8*)&KL[n * 16 + c][g * 8];
      bf16x8 bk1 = *(bf16x8*)&KL[n * 16 + c][32 + g * 8];
      acc = __builtin_amdgcn_mfma_f32_16x16x32_bf16(aq0, bk0, acc, 0, 0, 0);
      acc = __builtin_amdgcn_mfma_f32_16x16x32_bf16(aq1, bk1, acc, 0, 0, 0);
      int jl = n * 16 + c, jg = jt * 64 + jl;
      int dtj = dtsL[jg];
      int mk = mskL[jg];
#pragma unroll
      for (int r4 = 0; r4 < 4; r4++) {
        int il = w * 16 + g * 4 + r4;
        float s = (acc[r4] + (float)qzL[il][dtj]) * 0.125f + 0.6f * dv[n][r4];
        float p = mk ? __expf(s) : 0.f;
        lsum[r4] += p;
        PL[il][jl] = (__bf16)p;
      }
    }
    __syncthreads();  // (C) P visible before fragment reads (round-3 proven)

    bf16x8 ap0 = *(bf16x8*)&PL[w * 16 + c][g * 8];
    bf16x8 ap1 = *(bf16x8*)&PL[w * 16 + c][32 + g * 8];
#pragma unroll
    for (int dn = 0; dn < 4; dn++) {
      bf16x8 bv0 = *(bf16x8*)&VT[dn * 16 + c][g * 8];
      bf16x8 bv1 = *(bf16x8*)&VT[dn * 16 + c][32 + g * 8];
      Oacc[dn] = __builtin_amdgcn_mfma_f32_16x16x32_bf16(ap0, bv0, Oacc[dn], 0, 0, 0);
      Oacc[dn] = __builtin_amdgcn_mfma_f32_16x16x32_bf16(ap1, bv1, Oacc[dn], 0, 0, 0);
    }
#pragma unroll
    for (int tn = 0; tn < 8; tn++) {
      bf16x8 bz0 = *(bf16x8*)&B1h[tn * 16 + c][g * 8];
      bf16x8 bz1 = *(bf16x8*)&B1h[tn * 16 + c][32 + g * 8];
      Cacc[tn] = __builtin_amdgcn_mfma_f32_16x16x32_bf16(ap0, bz0, Cacc[tn], 0, 0, 0);
      Cacc[tn] = __builtin_amdgcn_mfma_f32_16x16x32_bf16(ap1, bz1, Cacc[tn], 0, 0, 0);
    }
  }

  // epilogue: row sums + unnormalized O, C to global
#pragma unroll
  for (int r4 = 0; r4 < 4; r4++) {
    float s = lsum[r4];
    for (int off = 1; off < 16; off <<= 1) s += __shfl_xor(s, off);
    int il = w * 16 + g * 4 + r4;
    if ((l & 15) == 0) Lg[(size_t)bh * SEQ + qbase + il] = s;
#pragma unroll
    for (int dn = 0; dn < 4; dn++)
      Og[((size_t)(bh * SEQ + qbase + il)) * 64 + dn * 16 + c] = Oacc[dn][r4];
#pragma unroll
    for (int tn = 0; tn < 8; tn++)
      Cg[((size_t)(bh * SEQ + qbase + il)) * 128 + tn * 16 + c] = Cacc[tn][r4];
  }
}

// ---------------- kernel 3: shifted-C scatter + Y = CL @ pe + combine/normalize
__global__ __launch_bounds__(256) void zcombine(
    const float* __restrict__ Cg, const float* __restrict__ Og,
    const float* __restrict__ Lg, const float* __restrict__ pos_emb,
    const int* __restrict__ dtimes, float* __restrict__ outp) {
  __shared__ __attribute__((aligned(16))) float CLs[64][136];
  __shared__ __attribute__((aligned(16))) __bf16 peTs[64][136];  // [d][t]
  __shared__ __attribute__((aligned(16))) float OLs[64][68];
  __shared__ float LLs[64];
  __shared__ int DTs[64];
  const int tid = threadIdx.x, w = tid >> 6, l = tid & 63, c = l & 15, g = l >> 4;
  const int bid = blockIdx.x, qt = bid & 7, bh = bid >> 3, h = bh & 7, b = bh >> 3;
  const int qbase = qt * 64;
  const int r = tid >> 2, d0 = (tid & 3) * 16;

  {
    float4 z = {0.f, 0.f, 0.f, 0.f};
    for (int idx = tid; idx < 64 * 34; idx += 256) ((float4*)CLs)[idx] = z;
  }
  for (int s = 0; s < 3; s++) {
    int t = r + s * 64;
    if (t < 129) {
      float vals[16];
      *(float4*)&vals[0]  = *(const float4*)(pos_emb + t * 64 + d0);
      *(float4*)&vals[4]  = *(const float4*)(pos_emb + t * 64 + d0 + 4);
      *(float4*)&vals[8]  = *(const float4*)(pos_emb + t * 64 + d0 + 8);
      *(float4*)&vals[12] = *(const float4*)(pos_emb + t * 64 + d0 + 12);
      for (int q = 0; q < 16; q++) {
        int kk = (q + t) & 15;
        peTs[d0 + kk][t] = (__bf16)vals[kk];
      }
    }
  }
  {
    const float* op = Og + ((size_t)(bh * SEQ + qbase + r)) * 64 + d0;
    *(float4*)&OLs[r][d0]      = *(const float4*)(op);
    *(float4*)&OLs[r][d0 + 4]  = *(const float4*)(op + 4);
    *(float4*)&OLs[r][d0 + 8]  = *(const float4*)(op + 8);
    *(float4*)&OLs[r][d0 + 12] = *(const float4*)(op + 12);
  }
  if (tid < 64) {
    LLs[tid] = Lg[(size_t)bh * SEQ + qbase + tid];
    DTs[tid] = dtimes[b * SEQ + qbase + tid];
  }
  __syncthreads();

  {  // scatter C -> shifted CL with edge folding
    int dti = DTs[r];
    float e0 = 0.f, e1 = 0.f;
    int t0 = (tid & 3) * 32;
    const float* cp = Cg + ((size_t)(bh * SEQ + qbase + r)) * 128 + t0;
    for (int q = 0; q < 8; q++) {
      float4 v = *(const float4*)(cp + q * 4);
      float vv[4] = {v.x, v.y, v.z, v.w};
      for (int e = 0; e < 4; e++) {
        int tau = t0 + q * 4 + e, d = tau - dti;
        if (d <= -64) e0 += vv[e];
        else if (d >= 64) e1 += vv[e];
        else CLs[r][d + 64] = vv[e];
      }
    }
    if (e0 != 0.f) atomicAdd(&CLs[r][0], e0);
    if (e1 != 0.f) atomicAdd(&CLs[r][128], e1);
  }
  __syncthreads();

  f32x4 acc[4] = {};
#pragma unroll
  for (int ks = 0; ks < 4; ks++) {
    const float* ap = &CLs[w * 16 + c][ks * 32 + g * 8];
    float4 a0 = *(const float4*)ap, a1 = *(const float4*)(ap + 4);
    bf16x8 af;
    af[0]=(__bf16)a0.x; af[1]=(__bf16)a0.y; af[2]=(__bf16)a0.z; af[3]=(__bf16)a0.w;
    af[4]=(__bf16)a1.x; af[5]=(__bf16)a1.y; af[6]=(__bf16)a1.z; af[7]=(__bf16)a1.w;
#pragma unroll
    for (int dn = 0; dn < 4; dn++) {
      bf16x8 bf = *(bf16x8*)&peTs[dn * 16 + c][ks * 32 + g * 8];
      acc[dn] = __builtin_amdgcn_mfma_f32_16x16x32_bf16(af, bf, acc[dn], 0, 0, 0);
    }
  }
#pragma unroll
  for (int r4 = 0; r4 < 4; r4++) {
    int il = w * 16 + g * 4 + r4;
    float inv = 1.0f / LLs[il];
    float c128 = CLs[il][128];
#pragma unroll
    for (int dn = 0; dn < 4; dn++) {
      int d = dn * 16 + c;
      float y = acc[dn][r4] + c128 * (float)peTs[d][128];
      outp[((size_t)(b * SEQ + qbase + il)) * EDIM + h * HDIM + d] = (OLs[il][d] + y) * inv;
    }
  }
}

// ---------------- layernorm over rows of 512
__global__ __launch_bounds__(64) void ln_kernel(
    const float* __restrict__ in, const float* __restrict__ g,
    const float* __restrict__ bta, float* __restrict__ out) {
  int row = blockIdx.x, lane = threadIdx.x;
  const float* p = in + (size_t)row * EDIM;
  float4 v0 = *(const float4*)(p + lane * 8);
  float4 v1 = *(const float4*)(p + lane * 8 + 4);
  float vals[8] = {v0.x, v0.y, v0.z, v0.w, v1.x, v1.y, v1.z, v1.w};
  float s = 0.f;
  for (int j = 0; j < 8; j++) s += vals[j];
  for (int o = 32; o; o >>= 1) s += __shfl_xor(s, o);
  float mu = s * (1.0f / EDIM);
  float vs = 0.f;
  for (int j = 0; j < 8; j++) {
    vals[j] -= mu;
    vs += vals[j] * vals[j];
  }
  for (int o = 32; o; o >>= 1) vs += __shfl_xor(vs, o);
  float rs = rsqrtf(vs * (1.0f / EDIM) + 1e-5f);
  for (int j = 0; j < 8; j++) {
    int col = lane * 8 + j;
    out[(size_t)row * EDIM + col] = vals[j] * rs * g[col] + bta[col];
  }
}

extern "C" void kernel_launch(void* const* d_in, const int* in_sizes, int n_in,
                              void* d_out, int out_size, void* d_ws, size_t ws_size,
                              hipStream_t stream) {
  const float* x = (const float*)d_in[0];
  const float* dist = (const float*)d_in[1];
  const int* dtimes = (const int*)d_in[2];
  const int* maskp = (const int*)d_in[3];
  const float* wq_w = (const float*)d_in[4];
  const float* wq_b = (const float*)d_in[5];
  const float* wk_w = (const float*)d_in[6];
  const float* wk_b = (const float*)d_in[7];
  const float* wv_w = (const float*)d_in[8];
  const float* wv_b = (const float*)d_in[9];
  const float* wo_w = (const float*)d_in[10];
  const float* wo_b = (const float*)d_in[11];
  const float* pos_emb = (const float*)d_in[12];
  const float* w1 = (const float*)d_in[13];
  const float* b1 = (const float*)d_in[14];
  const float* w2 = (const float*)d_in[15];
  const float* b2 = (const float*)d_in[16];
  const float* ln1_g = (const float*)d_in[17];
  const float* ln1_b = (const float*)d_in[18];
  const float* ln2_g = (const float*)d_in[19];
  const float* ln2_b = (const float*)d_in[20];
  float* out = (float*)d_out;

  const int M = TOKENS, E = EDIM, F = FDIM;
  float* fws = (float*)d_ws;
  float* qbuf = fws;
  float* kbuf = qbuf + (size_t)M * E;
  float* vbuf = kbuf + (size_t)M * E;
  float* attnb = vbuf + (size_t)M * E;
  float* attno = attnb + (size_t)M * E;
  float* hid = attno + (size_t)M * E;
  __bf16* wqt = (__bf16*)(hid + (size_t)M * F);
  __bf16* wkt = wqt + (size_t)E * E;
  __bf16* wvt = wkt + (size_t)E * E;
  __bf16* wot = wvt + (size_t)E * E;
  __bf16* w1t = wot + (size_t)E * E;
  __bf16* w2t = w1t + (size_t)E * F;
  // stream-ordered disjoint-lifetime aliases:
  __bf16* QZg = (__bf16*)attnb;                 // qz_shift -> attn_main
  float* Og = hid;                              // attn_main -> zcombine (before w1 gemm)
  float* Cg = Og + (size_t)64 * SEQ * 64;
  float* Lg = Cg + (size_t)64 * SEQ * 128;

  transpose_bf16<<<dim3(E / 32, E / 32), 256, 0, stream>>>(wq_w, wqt, E, E);
  transpose_bf16<<<dim3(E / 32, E / 32), 256, 0, stream>>>(wk_w, wkt, E, E);
  transpose_bf16<<<dim3(E / 32, E / 32), 256, 0, stream>>>(wv_w, wvt, E, E);
  transpose_bf16<<<dim3(E / 32, E / 32), 256, 0, stream>>>(wo_w, wot, E, E);
  transpose_bf16<<<dim3(F / 32, E / 32), 256, 0, stream>>>(w1, w1t, E, F);
  transpose_bf16<<<dim3(E / 32, F / 32), 256, 0, stream>>>(w2, w2t, F, E);

  gemm_bf16<<<dim3(E / 64, M / 64), 256, 0, stream>>>(x, wqt, wq_b, nullptr, qbuf, M, E, E, 0);
  gemm_bf16<<<dim3(E / 64, M / 64), 256, 0, stream>>>(x, wkt, wk_b, nullptr, kbuf, M, E, E, 0);
  gemm_bf16<<<dim3(E / 64, M / 64), 256, 0, stream>>>(x, wvt, wv_b, nullptr, vbuf, M, E, E, 0);

  qz_shift<<<512, 256, 0, stream>>>(qbuf, pos_emb, dtimes, QZg);
  attn_main<<<512, 256, 0, stream>>>(qbuf, kbuf, vbuf, dist, dtimes, maskp, QZg, Og, Cg, Lg);
  zcombine<<<512, 256, 0, stream>>>(Cg, Og, Lg, pos_emb, dtimes, attnb);

  gemm_bf16<<<dim3(E / 64, M / 64), 256, 0, stream>>>(attnb, wot, wo_b, x, qbuf, M, E, E, 0);
  ln_kernel<<<M, 64, 0, stream>>>(qbuf, ln1_g, ln1_b, attno);

  gemm_bf16<<<dim3(F / 64, M / 64), 256, 0, stream>>>(attno, w1t, b1, nullptr, hid, M, F, E, 1);
  gemm_bf16<<<dim3(E / 64, M / 64), 256, 0, stream>>>(hid, w2t, b2, attno, kbuf, M, E, F, 0);
  ln_kernel<<<M, 64, 0, stream>>>(kbuf, ln2_g, ln2_b, out);
}

// Round 6
// 354.957 us; speedup vs baseline: 2.9933x; 1.0376x over previous
//
#include <hip/hip_runtime.h>
#include <hip/hip_bf16.h>

typedef __bf16 bf16x8 __attribute__((ext_vector_type(8)));
typedef float f32x4 __attribute__((ext_vector_type(4)));

#define TOKENS 4096
#define EDIM 512
#define FDIM 2048
#define SEQ 512
#define NHEAD 8
#define HDIM 64
#define QKVS 1536

// ---------------- transpose + f32->bf16 convert: dst[c*R + r] = src[r*C + c]
__global__ __launch_bounds__(256) void transpose_bf16(
    const float* __restrict__ src, __bf16* __restrict__ dst, int R, int C) {
  __shared__ float t[32][33];
  int c0 = blockIdx.x * 32, r0 = blockIdx.y * 32;
  int tx = threadIdx.x & 31, ty = threadIdx.x >> 5;
  for (int rr = ty; rr < 32; rr += 8) {
    int r = r0 + rr, c = c0 + tx;
    if (r < R && c < C) t[rr][tx] = src[(size_t)r * C + c];
  }
  __syncthreads();
  for (int rr = ty; rr < 32; rr += 8) {
    int c = c0 + rr, r = r0 + tx;
    if (r < R && c < C) dst[(size_t)c * R + r] = (__bf16)t[tx][rr];
  }
}

// ---------------- f32 -> bf16 bulk convert (8 els/thread)
__global__ __launch_bounds__(256) void f32_to_bf16(
    const float* __restrict__ in, __bf16* __restrict__ out, int n8) {
  int i = blockIdx.x * 256 + threadIdx.x;
  if (i >= n8) return;
  float4 a = ((const float4*)in)[i * 2];
  float4 b = ((const float4*)in)[i * 2 + 1];
  bf16x8 p;
  p[0] = (__bf16)a.x; p[1] = (__bf16)a.y; p[2] = (__bf16)a.z; p[3] = (__bf16)a.w;
  p[4] = (__bf16)b.x; p[5] = (__bf16)b.y; p[6] = (__bf16)b.z; p[7] = (__bf16)b.w;
  ((bf16x8*)out)[i] = p;
}

// ---------------- concat 3x512 bias vectors
__global__ __launch_bounds__(256) void concat3(
    const float* __restrict__ a, const float* __restrict__ b,
    const float* __restrict__ c, float* __restrict__ d) {
  int i = blockIdx.x * 256 + threadIdx.x;
  if (i < 512) d[i] = a[i];
  else if (i < 1024) d[i] = b[i - 512];
  else if (i < 1536) d[i] = c[i - 1024];
}

// async global->LDS, 16B per lane; lds dest = wave-uniform base + lane*16 (HW)
__device__ __forceinline__ void gl_lds16(const void* g, void* l) {
  __builtin_amdgcn_global_load_lds(
      (const __attribute__((address_space(1))) unsigned int*)(size_t)g,
      (__attribute__((address_space(3))) unsigned int*)(size_t)l, 16, 0, 0);
}

// ---------------- m97-style GEMM: C = op(A(bf16,[M][K]) @ Bt(bf16,[N][K])^T)
// 128xBN tile, BK=64, 4 waves (2x2). LDS XOR-swizzled (slot ^= row&7), staged
// via global_load_lds w/ inverse-swizzled global source (rule #21).
template <int BN>
__global__ __launch_bounds__(256) void gemm128(
    const __bf16* __restrict__ A, const __bf16* __restrict__ Bt,
    const float* __restrict__ bias, const float* __restrict__ resid,
    float* __restrict__ Cf, __bf16* __restrict__ Cb,
    int M, int N, int K, int relu) {
  constexpr int NI = BN / 32;  // n-frags per wave (and B staging issues)
  __shared__ __attribute__((aligned(16))) __bf16 Asl[128 * 64];
  __shared__ __attribute__((aligned(16))) __bf16 Bsl[BN * 64];
  const int tid = threadIdx.x, w = tid >> 6, lane = tid & 63;
  const int c = lane & 15, g = lane >> 4;
  const int m0 = blockIdx.y * 128, n0 = blockIdx.x * BN;
  const int wr = w >> 1, wc = w & 1;
  f32x4 acc[4][NI] = {};
  const __bf16* Ab = A + (size_t)m0 * K;
  const __bf16* Bb = Bt + (size_t)n0 * K;

  for (int k0 = 0; k0 < K; k0 += 64) {
#pragma unroll
    for (int s = 0; s < 4; s++) {  // A: 128x64x2B = 16KB = 4 issues
      int L = (s * 256 + tid) * 16;               // linear dest byte
      int row = L >> 7;                            // 128B per row
      int lslot = ((L >> 4) & 7) ^ (row & 7);      // inverse-swizzled source slot
      gl_lds16(Ab + (size_t)row * K + k0 + lslot * 8,
               (char*)Asl + s * 4096 + w * 1024);
    }
#pragma unroll
    for (int s = 0; s < NI; s++) {  // B: BN/32 issues
      int L = (s * 256 + tid) * 16;
      int row = L >> 7;
      int lslot = ((L >> 4) & 7) ^ (row & 7);
      gl_lds16(Bb + (size_t)row * K + k0 + lslot * 8,
               (char*)Bsl + s * 4096 + w * 1024);
    }
    __syncthreads();  // vmcnt(0) drain inserted by compiler

    bf16x8 af[4][2], bfr[NI][2];
#pragma unroll
    for (int mi = 0; mi < 4; mi++)
#pragma unroll
      for (int ko = 0; ko < 2; ko++) {
        int row = wr * 64 + mi * 16 + c;
        int ps = (ko * 4 + g) ^ (row & 7);         // swizzled read slot
        af[mi][ko] = *(const bf16x8*)&Asl[row * 64 + ps * 8];
      }
#pragma unroll
    for (int ni = 0; ni < NI; ni++)
#pragma unroll
      for (int ko = 0; ko < 2; ko++) {
        int row = wc * (BN / 2) + ni * 16 + c;
        int ps = (ko * 4 + g) ^ (row & 7);
        bfr[ni][ko] = *(const bf16x8*)&Bsl[row * 64 + ps * 8];
      }
#pragma unroll
    for (int mi = 0; mi < 4; mi++)
#pragma unroll
      for (int ni = 0; ni < NI; ni++) {
        acc[mi][ni] = __builtin_amdgcn_mfma_f32_16x16x32_bf16(af[mi][0], bfr[ni][0], acc[mi][ni], 0, 0, 0);
        acc[mi][ni] = __builtin_amdgcn_mfma_f32_16x16x32_bf16(af[mi][1], bfr[ni][1], acc[mi][ni], 0, 0, 0);
      }
    __syncthreads();
  }

#pragma unroll
  for (int mi = 0; mi < 4; mi++)
#pragma unroll
    for (int ni = 0; ni < NI; ni++)
#pragma unroll
      for (int r = 0; r < 4; r++) {
        int row = m0 + wr * 64 + mi * 16 + g * 4 + r;
        int col = n0 + wc * (BN / 2) + ni * 16 + c;
        float v = acc[mi][ni][r] + bias[col];
        if (resid) v += resid[(size_t)row * N + col];
        if (relu) v = fmaxf(v, 0.f);
        if (Cf) Cf[(size_t)row * N + col] = v;
        if (Cb) Cb[(size_t)row * N + col] = (__bf16)v;
      }
}

// read 16 f32, convert, store as two bf16x8 (dst 16B-aligned)
__device__ inline void cvt16(const float* __restrict__ src, __bf16* dst) {
  float4 f0 = *(const float4*)(src);
  float4 f1 = *(const float4*)(src + 4);
  float4 f2 = *(const float4*)(src + 8);
  float4 f3 = *(const float4*)(src + 12);
  bf16x8 p0, p1;
  p0[0]=(__bf16)f0.x; p0[1]=(__bf16)f0.y; p0[2]=(__bf16)f0.z; p0[3]=(__bf16)f0.w;
  p0[4]=(__bf16)f1.x; p0[5]=(__bf16)f1.y; p0[6]=(__bf16)f1.z; p0[7]=(__bf16)f1.w;
  p1[0]=(__bf16)f2.x; p1[1]=(__bf16)f2.y; p1[2]=(__bf16)f2.z; p1[3]=(__bf16)f2.w;
  p1[4]=(__bf16)f3.x; p1[5]=(__bf16)f3.y; p1[6]=(__bf16)f3.z; p1[7]=(__bf16)f3.w;
  *(bf16x8*)(dst) = p0;
  *(bf16x8*)(dst + 8) = p1;
}

// ---------------- kernel 1: QZ'[bh][i][tau] = (q_i . pe)[clip(tau - dti,-64,64)+64]
__global__ __launch_bounds__(256) void qz_shift(
    const float* __restrict__ qb, const float* __restrict__ pos_emb,
    const int* __restrict__ dtimes, __bf16* __restrict__ QZg) {
  __shared__ __attribute__((aligned(16))) __bf16 peL[144][72];
  __shared__ __attribute__((aligned(16))) __bf16 QL[64][72];
  __shared__ __attribute__((aligned(16))) float qzf[64][144];
  const int tid = threadIdx.x, w = tid >> 6, l = tid & 63, c = l & 15, g = l >> 4;
  const int bid = blockIdx.x, qt = bid & 7, bh = bid >> 3, h = bh & 7, b = bh >> 3;
  const int qbase = qt * 64;
  const int r = tid >> 2, d0 = (tid & 3) * 16;

  for (int s = 0; s < 3; s++) {
    int rr = r + s * 64;
    if (rr >= 144) break;
    if (rr < 129) {
      cvt16(pos_emb + rr * 64 + d0, &peL[rr][d0]);
    } else {
      bf16x8 z = {};
      *(bf16x8*)&peL[rr][d0] = z;
      *(bf16x8*)&peL[rr][d0 + 8] = z;
    }
  }
  cvt16(qb + ((size_t)(b * SEQ + qbase + r)) * QKVS + h * HDIM + d0, &QL[r][d0]);
  __syncthreads();

  bf16x8 aq0 = *(bf16x8*)&QL[w * 16 + c][g * 8];
  bf16x8 aq1 = *(bf16x8*)&QL[w * 16 + c][32 + g * 8];
  for (int n = 0; n < 9; n++) {
    f32x4 acc = {};
    bf16x8 b0 = *(bf16x8*)&peL[n * 16 + c][g * 8];
    bf16x8 b1 = *(bf16x8*)&peL[n * 16 + c][32 + g * 8];
    acc = __builtin_amdgcn_mfma_f32_16x16x32_bf16(aq0, b0, acc, 0, 0, 0);
    acc = __builtin_amdgcn_mfma_f32_16x16x32_bf16(aq1, b1, acc, 0, 0, 0);
    int t = n * 16 + c;
    for (int r4 = 0; r4 < 4; r4++) qzf[w * 16 + g * 4 + r4][t] = acc[r4];
  }
  __syncthreads();

  int dti = dtimes[b * SEQ + qbase + r];
  int t0 = (tid & 3) * 32;
  for (int q4 = 0; q4 < 4; q4++) {
    bf16x8 o;
    for (int e = 0; e < 8; e++) {
      int tau = t0 + q4 * 8 + e;
      int t = min(max(tau - dti, -64), 64) + 64;
      o[e] = (__bf16)qzf[r][t];
    }
    *(bf16x8*)(QZg + ((size_t)(bh * SEQ + qbase + r)) * 128 + t0 + q4 * 8) = o;
  }
}

// ---------------- kernel 2: single-pass attention main
__global__ __launch_bounds__(256) void attn_main(
    const float* __restrict__ qb, const float* __restrict__ kb,
    const float* __restrict__ vb, const float* __restrict__ dist,
    const int* __restrict__ dtimes, const int* __restrict__ maskp,
    const __bf16* __restrict__ QZg, float* __restrict__ Og,
    float* __restrict__ Cg, float* __restrict__ Lg) {
  __shared__ __attribute__((aligned(16))) __bf16 QL[64][72];
  __shared__ __attribute__((aligned(16))) __bf16 PL[64][72];
  __shared__ __attribute__((aligned(16))) __bf16 KL[64][72];
  __shared__ __attribute__((aligned(16))) __bf16 VT[64][72];    // VT[d][j]
  __shared__ __attribute__((aligned(16))) __bf16 B1h[128][72];  // one-hot[tau][j]
  __shared__ __attribute__((aligned(16))) __bf16 qzL[64][136];  // QZ'[i][tau]
  __shared__ int dtsL[SEQ];
  __shared__ int mskL[SEQ];

  const int tid = threadIdx.x, w = tid >> 6, l = tid & 63, c = l & 15, g = l >> 4;
  const int bid = blockIdx.x;
  const int qt = bid & 7, h = (bid >> 3) & 7, b = bid >> 6, bh = bid >> 3;
  const int qbase = qt * 64;
  const int r = tid >> 2, d0 = (tid & 3) * 16;

  // prologue
  cvt16(qb + ((size_t)(b * SEQ + qbase + r)) * QKVS + h * HDIM + d0, &QL[r][d0]);
  {
    int ch = (tid & 3) * 32;
    const __bf16* src = QZg + ((size_t)(bh * SEQ + qbase + r)) * 128 + ch;
    for (int q4 = 0; q4 < 4; q4++)
      *(bf16x8*)&qzL[r][ch + q4 * 8] = *(const bf16x8*)(src + q4 * 8);
  }
  for (int idx = tid; idx < SEQ; idx += 256) {
    dtsL[idx] = dtimes[b * SEQ + idx];
    mskL[idx] = maskp[b * SEQ + idx];
  }
  {
    bf16x8 z = {};
    for (int idx = tid; idx < 128 * 9; idx += 256)
      *(bf16x8*)&B1h[idx / 9][(idx % 9) * 8] = z;
  }
  __syncthreads();

  bf16x8 aq0 = *(bf16x8*)&QL[w * 16 + c][g * 8];
  bf16x8 aq1 = *(bf16x8*)&QL[w * 16 + c][32 + g * 8];
  float lsum[4] = {0.f, 0.f, 0.f, 0.f};
  f32x4 Oacc[4] = {};
  f32x4 Cacc[8] = {};

  for (int jt = 0; jt < 8; jt++) {
    __syncthreads();  // (A) prev tile's LDS reads drained
    cvt16(kb + ((size_t)(b * SEQ + jt * 64 + r)) * QKVS + h * HDIM + d0, &KL[r][d0]);
    {
      float vals[16];
      const float* vp = vb + ((size_t)(b * SEQ + jt * 64 + r)) * QKVS + h * HDIM + d0;
      *(float4*)&vals[0]  = *(const float4*)(vp);
      *(float4*)&vals[4]  = *(const float4*)(vp + 4);
      *(float4*)&vals[8]  = *(const float4*)(vp + 8);
      *(float4*)&vals[12] = *(const float4*)(vp + 12);
      for (int q = 0; q < 16; q++) {
        int kk = (q + r) & 15;
        VT[d0 + kk][r] = (__bf16)vals[kk];
      }
    }
    if (tid < 64) {  // one-hot maintenance (same thread, same column, ordered)
      if (jt > 0) {
        int tp = dtsL[(jt - 1) * 64 + tid], tn = dtsL[jt * 64 + tid];
        if (tp != tn) B1h[tp][tid] = (__bf16)0.f;
        B1h[tn][tid] = (__bf16)1.f;
      } else {
        B1h[dtsL[tid]][tid] = (__bf16)1.f;
      }
    }
    __syncthreads();  // (B)

    // dist direct from global (no reuse)
    float dv[4][4];
#pragma unroll
    for (int n = 0; n < 4; n++) {
      int jg = jt * 64 + n * 16 + c;
#pragma unroll
      for (int r4 = 0; r4 < 4; r4++) {
        int il = w * 16 + g * 4 + r4;
        dv[n][r4] = dist[((size_t)(b * SEQ + qbase + il)) * SEQ + jg];
      }
    }

    // scores -> P (exp without max; |s| small, softmax shift-invariant)
#pragma unroll
    for (int n = 0; n < 4; n++) {
      f32x4 acc = {};
      bf16x8 bk0 = *(bf16x8*)&KL[n * 16 + c][g * 8];
      bf16x8 bk1 = *(bf16x8*)&KL[n * 16 + c][32 + g * 8];
      acc = __builtin_amdgcn_mfma_f32_16x16x32_bf16(aq0, bk0, acc, 0, 0, 0);
      acc = __builtin_amdgcn_mfma_f32_16x16x32_bf16(aq1, bk1, acc, 0, 0, 0);
      int jl = n * 16 + c, jg = jt * 64 + jl;
      int dtj = dtsL[jg];
      int mk = mskL[jg];
#pragma unroll
      for (int r4 = 0; r4 < 4; r4++) {
        int il = w * 16 + g * 4 + r4;
        float s = (acc[r4] + (float)qzL[il][dtj]) * 0.125f + 0.6f * dv[n][r4];
        float p = mk ? __expf(s) : 0.f;
        lsum[r4] += p;
        PL[il][jl] = (__bf16)p;
      }
    }
    __syncthreads();  // (C) P visible before fragment reads

    bf16x8 ap0 = *(bf16x8*)&PL[w * 16 + c][g * 8];
    bf16x8 ap1 = *(bf16x8*)&PL[w * 16 + c][32 + g * 8];
#pragma unroll
    for (int dn = 0; dn < 4; dn++) {
      bf16x8 bv0 = *(bf16x8*)&VT[dn * 16 + c][g * 8];
      bf16x8 bv1 = *(bf16x8*)&VT[dn * 16 + c][32 + g * 8];
      Oacc[dn] = __builtin_amdgcn_mfma_f32_16x16x32_bf16(ap0, bv0, Oacc[dn], 0, 0, 0);
      Oacc[dn] = __builtin_amdgcn_mfma_f32_16x16x32_bf16(ap1, bv1, Oacc[dn], 0, 0, 0);
    }
#pragma unroll
    for (int tn = 0; tn < 8; tn++) {
      bf16x8 bz0 = *(bf16x8*)&B1h[tn * 16 + c][g * 8];
      bf16x8 bz1 = *(bf16x8*)&B1h[tn * 16 + c][32 + g * 8];
      Cacc[tn] = __builtin_amdgcn_mfma_f32_16x16x32_bf16(ap0, bz0, Cacc[tn], 0, 0, 0);
      Cacc[tn] = __builtin_amdgcn_mfma_f32_16x16x32_bf16(ap1, bz1, Cacc[tn], 0, 0, 0);
    }
  }

  // epilogue
#pragma unroll
  for (int r4 = 0; r4 < 4; r4++) {
    float s = lsum[r4];
    for (int off = 1; off < 16; off <<= 1) s += __shfl_xor(s, off);
    int il = w * 16 + g * 4 + r4;
    if ((l & 15) == 0) Lg[(size_t)bh * SEQ + qbase + il] = s;
#pragma unroll
    for (int dn = 0; dn < 4; dn++)
      Og[((size_t)(bh * SEQ + qbase + il)) * 64 + dn * 16 + c] = Oacc[dn][r4];
#pragma unroll
    for (int tn = 0; tn < 8; tn++)
      Cg[((size_t)(bh * SEQ + qbase + il)) * 128 + tn * 16 + c] = Cacc[tn][r4];
  }
}

// ---------------- kernel 3: shifted-C scatter + Y = CL @ pe + combine/normalize -> bf16
__global__ __launch_bounds__(256) void zcombine(
    const float* __restrict__ Cg, const float* __restrict__ Og,
    const float* __restrict__ Lg, const float* __restrict__ pos_emb,
    const int* __restrict__ dtimes, __bf16* __restrict__ outb) {
  __shared__ __attribute__((aligned(16))) float CLs[64][136];
  __shared__ __attribute__((aligned(16))) __bf16 peTs[64][136];  // [d][t]
  __shared__ __attribute__((aligned(16))) float OLs[64][68];
  __shared__ float LLs[64];
  __shared__ int DTs[64];
  const int tid = threadIdx.x, w = tid >> 6, l = tid & 63, c = l & 15, g = l >> 4;
  const int bid = blockIdx.x, qt = bid & 7, bh = bid >> 3, h = bh & 7, b = bh >> 3;
  const int qbase = qt * 64;
  const int r = tid >> 2, d0 = (tid & 3) * 16;

  {
    float4 z = {0.f, 0.f, 0.f, 0.f};
    for (int idx = tid; idx < 64 * 34; idx += 256) ((float4*)CLs)[idx] = z;
  }
  for (int s = 0; s < 3; s++) {
    int t = r + s * 64;
    if (t < 129) {
      float vals[16];
      *(float4*)&vals[0]  = *(const float4*)(pos_emb + t * 64 + d0);
      *(float4*)&vals[4]  = *(const float4*)(pos_emb + t * 64 + d0 + 4);
      *(float4*)&vals[8]  = *(const float4*)(pos_emb + t * 64 + d0 + 8);
      *(float4*)&vals[12] = *(const float4*)(pos_emb + t * 64 + d0 + 12);
      for (int q = 0; q < 16; q++) {
        int kk = (q + t) & 15;
        peTs[d0 + kk][t] = (__bf16)vals[kk];
      }
    }
  }
  {
    const float* op = Og + ((size_t)(bh * SEQ + qbase + r)) * 64 + d0;
    *(float4*)&OLs[r][d0]      = *(const float4*)(op);
    *(float4*)&OLs[r][d0 + 4]  = *(const float4*)(op + 4);
    *(float4*)&OLs[r][d0 + 8]  = *(const float4*)(op + 8);
    *(float4*)&OLs[r][d0 + 12] = *(const float4*)(op + 12);
  }
  if (tid < 64) {
    LLs[tid] = Lg[(size_t)bh * SEQ + qbase + tid];
    DTs[tid] = dtimes[b * SEQ + qbase + tid];
  }
  __syncthreads();

  {  // scatter C -> shifted CL with edge folding
    int dti = DTs[r];
    float e0 = 0.f, e1 = 0.f;
    int t0 = (tid & 3) * 32;
    const float* cp = Cg + ((size_t)(bh * SEQ + qbase + r)) * 128 + t0;
    for (int q = 0; q < 8; q++) {
      float4 v = *(const float4*)(cp + q * 4);
      float vv[4] = {v.x, v.y, v.z, v.w};
      for (int e = 0; e < 4; e++) {
        int tau = t0 + q * 4 + e, d = tau - dti;
        if (d <= -64) e0 += vv[e];
        else if (d >= 64) e1 += vv[e];
        else CLs[r][d + 64] = vv[e];
      }
    }
    if (e0 != 0.f) atomicAdd(&CLs[r][0], e0);
    if (e1 != 0.f) atomicAdd(&CLs[r][128], e1);
  }
  __syncthreads();

  f32x4 acc[4] = {};
#pragma unroll
  for (int ks = 0; ks < 4; ks++) {
    const float* ap = &CLs[w * 16 + c][ks * 32 + g * 8];
    float4 a0 = *(const float4*)ap, a1 = *(const float4*)(ap + 4);
    bf16x8 af;
    af[0]=(__bf16)a0.x; af[1]=(__bf16)a0.y; af[2]=(__bf16)a0.z; af[3]=(__bf16)a0.w;
    af[4]=(__bf16)a1.x; af[5]=(__bf16)a1.y; af[6]=(__bf16)a1.z; af[7]=(__bf16)a1.w;
#pragma unroll
    for (int dn = 0; dn < 4; dn++) {
      bf16x8 bf = *(bf16x8*)&peTs[dn * 16 + c][ks * 32 + g * 8];
      acc[dn] = __builtin_amdgcn_mfma_f32_16x16x32_bf16(af, bf, acc[dn], 0, 0, 0);
    }
  }
#pragma unroll
  for (int r4 = 0; r4 < 4; r4++) {
    int il = w * 16 + g * 4 + r4;
    float inv = 1.0f / LLs[il];
    float c128 = CLs[il][128];
#pragma unroll
    for (int dn = 0; dn < 4; dn++) {
      int d = dn * 16 + c;
      float y = acc[dn][r4] + c128 * (float)peTs[d][128];
      outb[((size_t)(b * SEQ + qbase + il)) * EDIM + h * HDIM + d] =
          (__bf16)((OLs[il][d] + y) * inv);
    }
  }
}

// ---------------- layernorm over rows of 512 (optional extra bf16 output)
__global__ __launch_bounds__(64) void ln_kernel(
    const float* __restrict__ in, const float* __restrict__ g,
    const float* __restrict__ bta, float* __restrict__ out,
    __bf16* __restrict__ outb) {
  int row = blockIdx.x, lane = threadIdx.x;
  const float* p = in + (size_t)row * EDIM;
  float4 v0 = *(const float4*)(p + lane * 8);
  float4 v1 = *(const float4*)(p + lane * 8 + 4);
  float vals[8] = {v0.x, v0.y, v0.z, v0.w, v1.x, v1.y, v1.z, v1.w};
  float s = 0.f;
  for (int j = 0; j < 8; j++) s += vals[j];
  for (int o = 32; o; o >>= 1) s += __shfl_xor(s, o);
  float mu = s * (1.0f / EDIM);
  float vs = 0.f;
  for (int j = 0; j < 8; j++) {
    vals[j] -= mu;
    vs += vals[j] * vals[j];
  }
  for (int o = 32; o; o >>= 1) vs += __shfl_xor(vs, o);
  float rs = rsqrtf(vs * (1.0f / EDIM) + 1e-5f);
  for (int j = 0; j < 8; j++) {
    int col = lane * 8 + j;
    float v = vals[j] * rs * g[col] + bta[col];
    out[(size_t)row * EDIM + col] = v;
    if (outb) outb[(size_t)row * EDIM + col] = (__bf16)v;
  }
}

extern "C" void kernel_launch(void* const* d_in, const int* in_sizes, int n_in,
                              void* d_out, int out_size, void* d_ws, size_t ws_size,
                              hipStream_t stream) {
  const float* x = (const float*)d_in[0];
  const float* dist = (const float*)d_in[1];
  const int* dtimes = (const int*)d_in[2];
  const int* maskp = (const int*)d_in[3];
  const float* wq_w = (const float*)d_in[4];
  const float* wq_b = (const float*)d_in[5];
  const float* wk_w = (const float*)d_in[6];
  const float* wk_b = (const float*)d_in[7];
  const float* wv_w = (const float*)d_in[8];
  const float* wv_b = (const float*)d_in[9];
  const float* wo_w = (const float*)d_in[10];
  const float* wo_b = (const float*)d_in[11];
  const float* pos_emb = (const float*)d_in[12];
  const float* w1 = (const float*)d_in[13];
  const float* b1 = (const float*)d_in[14];
  const float* w2 = (const float*)d_in[15];
  const float* b2 = (const float*)d_in[16];
  const float* ln1_g = (const float*)d_in[17];
  const float* ln1_b = (const float*)d_in[18];
  const float* ln2_g = (const float*)d_in[19];
  const float* ln2_b = (const float*)d_in[20];
  float* out = (float*)d_out;

  const int M = TOKENS, E = EDIM, F = FDIM;
  const size_t T = TOKENS;
  float* fws = (float*)d_ws;

  // ---- workspace layout (f32 units), lifetime-aliased; total ~19.4M f32 (77.6MB)
  float*  qkv    = fws;                               // [0, T*1536) qkv f32
  float*  ln2in  = fws;                               // alias [0, T*512) (w2 out)
  float*  wo_out = fws + T * 512;                     // alias [T*512, T*1024)
  __bf16* QZg    = (__bf16*)(fws + T * 1536);         // T*512 f32 worth (bh*SEQ*128 bf16)
  const size_t oC = T * 1536 + T * 512;
  float*  Og     = fws + oC;                          // [oC, oC+T*512)
  float*  attno  = fws + oC;                          // alias (after zcombine)
  float*  Cg     = fws + oC + T * 512;                // [.. +T*1024)
  __bf16* attnob = (__bf16*)(fws + oC + T * 512);     // alias, T*256 f32
  __bf16* hid    = (__bf16*)(fws + oC + T * 768);     // T*1024 f32
  float*  Lg     = fws + oC + T * 1536;               // 32K f32 (dead before hid write)
  const size_t oD = oC + T * 1792;
  __bf16* attnb  = (__bf16*)(fws + oD);               // T*256 f32
  __bf16* xb     = (__bf16*)(fws + oD + T * 256);     // T*256 f32
  __bf16* wqkvt  = (__bf16*)(fws + oD + T * 512);     // 1536*512 bf16
  __bf16* wot    = wqkvt + 1536 * 512;
  __bf16* w1t    = wot + 512 * 512;
  __bf16* w2t    = w1t + 512 * 2048;
  float*  qkvb   = (float*)(w2t + 2048 * 512);        // 1536 f32

  // ---- prep: weight transposes (f32->bf16), bias concat, x->bf16
  transpose_bf16<<<dim3(16, 16), 256, 0, stream>>>(wq_w, wqkvt, E, E);
  transpose_bf16<<<dim3(16, 16), 256, 0, stream>>>(wk_w, wqkvt + 512 * 512, E, E);
  transpose_bf16<<<dim3(16, 16), 256, 0, stream>>>(wv_w, wqkvt + 2 * 512 * 512, E, E);
  transpose_bf16<<<dim3(16, 16), 256, 0, stream>>>(wo_w, wot, E, E);
  transpose_bf16<<<dim3(64, 16), 256, 0, stream>>>(w1, w1t, E, F);
  transpose_bf16<<<dim3(16, 64), 256, 0, stream>>>(w2, w2t, F, E);
  concat3<<<6, 256, 0, stream>>>(wq_b, wk_b, wv_b, qkvb);
  f32_to_bf16<<<(M * E / 8 + 255) / 256, 256, 0, stream>>>(x, xb, M * E / 8);

  // ---- fused QKV projection: [4096x512] @ [512x1536]
  gemm128<128><<<dim3(1536 / 128, M / 128), 256, 0, stream>>>(
      xb, wqkvt, qkvb, nullptr, qkv, nullptr, M, 1536, 512, 0);

  // ---- attention
  qz_shift<<<512, 256, 0, stream>>>(qkv, pos_emb, dtimes, QZg);
  attn_main<<<512, 256, 0, stream>>>(qkv, qkv + 512, qkv + 1024, dist, dtimes, maskp,
                                     QZg, Og, Cg, Lg);
  zcombine<<<512, 256, 0, stream>>>(Cg, Og, Lg, pos_emb, dtimes, attnb);

  // ---- output projection + residual, LN1 (dual f32/bf16 out)
  gemm128<64><<<dim3(512 / 64, M / 128), 256, 0, stream>>>(
      attnb, wot, wo_b, x, wo_out, nullptr, M, 512, 512, 0);
  ln_kernel<<<M, 64, 0, stream>>>(wo_out, ln1_g, ln1_b, attno, attnob);

  // ---- FFN
  gemm128<128><<<dim3(2048 / 128, M / 128), 256, 0, stream>>>(
      attnob, w1t, b1, nullptr, nullptr, hid, M, 2048, 512, 1);
  gemm128<64><<<dim3(512 / 64, M / 128), 256, 0, stream>>>(
      hid, w2t, b2, attno, ln2in, nullptr, M, 512, 2048, 0);
  ln_kernel<<<M, 64, 0, stream>>>(ln2in, ln2_g, ln2_b, out, nullptr);
}

// Round 7
// 307.540 us; speedup vs baseline: 3.4548x; 1.1542x over previous
//
#include <hip/hip_runtime.h>
#include <hip/hip_bf16.h>

typedef __bf16 bf16x8 __attribute__((ext_vector_type(8)));
typedef float f32x4 __attribute__((ext_vector_type(4)));

#define TOKENS 4096
#define EDIM 512
#define FDIM 2048
#define SEQ 512
#define NHEAD 8
#define HDIM 64
#define QKVS 1536

// ---------------- prep: all weight transposes (f32->bf16), bias concat, x->bf16
__global__ __launch_bounds__(256) void prep(
    const float* __restrict__ wq_w, const float* __restrict__ wk_w,
    const float* __restrict__ wv_w, const float* __restrict__ wo_w,
    const float* __restrict__ w1, const float* __restrict__ w2,
    const float* __restrict__ x,
    const float* __restrict__ wq_b, const float* __restrict__ wk_b,
    const float* __restrict__ wv_b,
    __bf16* __restrict__ wqkvt, __bf16* __restrict__ wot,
    __bf16* __restrict__ w1t, __bf16* __restrict__ w2t,
    __bf16* __restrict__ xb, float* __restrict__ qkvb) {
  __shared__ float t[32][33];
  int bid = blockIdx.x;
  if (bid < 4096) {
    const float* src;
    __bf16* dst;
    int R = 512, C = 512, bx, by;
    if (bid < 1024) {
      int seg = bid >> 8, local = bid & 255;
      src = seg == 0 ? wq_w : seg == 1 ? wk_w : seg == 2 ? wv_w : wo_w;
      dst = seg == 0 ? wqkvt : seg == 1 ? wqkvt + 262144 : seg == 2 ? wqkvt + 524288 : wot;
      bx = local & 15; by = local >> 4;
    } else if (bid < 2048) {
      int local = bid - 1024; src = w1; dst = w1t; C = 2048;
      bx = local & 63; by = local >> 6;
    } else if (bid < 3072) {
      int local = bid - 2048; src = w2; dst = w2t; R = 2048;
      bx = local & 15; by = local >> 4;
    } else {  // x f32 -> bf16, 8 els/thread
      int i = (bid - 3072) * 256 + threadIdx.x;
      float4 a = ((const float4*)x)[i * 2];
      float4 b4 = ((const float4*)x)[i * 2 + 1];
      bf16x8 p;
      p[0] = (__bf16)a.x; p[1] = (__bf16)a.y; p[2] = (__bf16)a.z; p[3] = (__bf16)a.w;
      p[4] = (__bf16)b4.x; p[5] = (__bf16)b4.y; p[6] = (__bf16)b4.z; p[7] = (__bf16)b4.w;
      ((bf16x8*)xb)[i] = p;
      return;
    }
    int c0 = bx * 32, r0 = by * 32;
    int tx = threadIdx.x & 31, ty = threadIdx.x >> 5;
    for (int rr = ty; rr < 32; rr += 8)
      t[rr][tx] = src[(size_t)(r0 + rr) * C + c0 + tx];
    __syncthreads();
    for (int rr = ty; rr < 32; rr += 8)
      dst[(size_t)(c0 + rr) * R + r0 + tx] = (__bf16)t[tx][rr];
  } else {
    for (int i = threadIdx.x; i < 1536; i += 256)
      qkvb[i] = i < 512 ? wq_b[i] : i < 1024 ? wk_b[i - 512] : wv_b[i - 1024];
  }
}

// async global->LDS, 16B per lane; lds dest = wave-uniform base + lane*16 (HW)
__device__ __forceinline__ void gl_lds16(const void* g, void* l) {
  __builtin_amdgcn_global_load_lds(
      (const __attribute__((address_space(1))) unsigned int*)(size_t)g,
      (__attribute__((address_space(3))) unsigned int*)(size_t)l, 16, 0, 0);
}

// ---------------- m97-style GEMM: C = op(A(bf16,[M][K]) @ Bt(bf16,[N][K])^T)
template <int BN>
__global__ __launch_bounds__(256) void gemm128(
    const __bf16* __restrict__ A, const __bf16* __restrict__ Bt,
    const float* __restrict__ bias, const float* __restrict__ resid,
    float* __restrict__ Cf, __bf16* __restrict__ Cb,
    int M, int N, int K, int relu) {
  constexpr int NI = BN / 32;
  __shared__ __attribute__((aligned(16))) __bf16 Asl[128 * 64];
  __shared__ __attribute__((aligned(16))) __bf16 Bsl[BN * 64];
  const int tid = threadIdx.x, w = tid >> 6, lane = tid & 63;
  const int c = lane & 15, g = lane >> 4;
  const int m0 = blockIdx.y * 128, n0 = blockIdx.x * BN;
  const int wr = w >> 1, wc = w & 1;
  f32x4 acc[4][NI] = {};
  const __bf16* Ab = A + (size_t)m0 * K;
  const __bf16* Bb = Bt + (size_t)n0 * K;

  for (int k0 = 0; k0 < K; k0 += 64) {
#pragma unroll
    for (int s = 0; s < 4; s++) {
      int L = (s * 256 + tid) * 16;
      int row = L >> 7;
      int lslot = ((L >> 4) & 7) ^ (row & 7);
      gl_lds16(Ab + (size_t)row * K + k0 + lslot * 8,
               (char*)Asl + s * 4096 + w * 1024);
    }
#pragma unroll
    for (int s = 0; s < NI; s++) {
      int L = (s * 256 + tid) * 16;
      int row = L >> 7;
      int lslot = ((L >> 4) & 7) ^ (row & 7);
      gl_lds16(Bb + (size_t)row * K + k0 + lslot * 8,
               (char*)Bsl + s * 4096 + w * 1024);
    }
    __syncthreads();

    bf16x8 af[4][2], bfr[NI][2];
#pragma unroll
    for (int mi = 0; mi < 4; mi++)
#pragma unroll
      for (int ko = 0; ko < 2; ko++) {
        int row = wr * 64 + mi * 16 + c;
        int ps = (ko * 4 + g) ^ (row & 7);
        af[mi][ko] = *(const bf16x8*)&Asl[row * 64 + ps * 8];
      }
#pragma unroll
    for (int ni = 0; ni < NI; ni++)
#pragma unroll
      for (int ko = 0; ko < 2; ko++) {
        int row = wc * (BN / 2) + ni * 16 + c;
        int ps = (ko * 4 + g) ^ (row & 7);
        bfr[ni][ko] = *(const bf16x8*)&Bsl[row * 64 + ps * 8];
      }
#pragma unroll
    for (int mi = 0; mi < 4; mi++)
#pragma unroll
      for (int ni = 0; ni < NI; ni++) {
        acc[mi][ni] = __builtin_amdgcn_mfma_f32_16x16x32_bf16(af[mi][0], bfr[ni][0], acc[mi][ni], 0, 0, 0);
        acc[mi][ni] = __builtin_amdgcn_mfma_f32_16x16x32_bf16(af[mi][1], bfr[ni][1], acc[mi][ni], 0, 0, 0);
      }
    __syncthreads();
  }

#pragma unroll
  for (int mi = 0; mi < 4; mi++)
#pragma unroll
    for (int ni = 0; ni < NI; ni++)
#pragma unroll
      for (int r = 0; r < 4; r++) {
        int row = m0 + wr * 64 + mi * 16 + g * 4 + r;
        int col = n0 + wc * (BN / 2) + ni * 16 + c;
        float v = acc[mi][ni][r] + bias[col];
        if (resid) v += resid[(size_t)row * N + col];
        if (relu) v = fmaxf(v, 0.f);
        if (Cf) Cf[(size_t)row * N + col] = v;
        if (Cb) Cb[(size_t)row * N + col] = (__bf16)v;
      }
}

// read 16 f32, convert, store as two bf16x8 (dst 16B-aligned)
__device__ inline void cvt16(const float* __restrict__ src, __bf16* dst) {
  float4 f0 = *(const float4*)(src);
  float4 f1 = *(const float4*)(src + 4);
  float4 f2 = *(const float4*)(src + 8);
  float4 f3 = *(const float4*)(src + 12);
  bf16x8 p0, p1;
  p0[0]=(__bf16)f0.x; p0[1]=(__bf16)f0.y; p0[2]=(__bf16)f0.z; p0[3]=(__bf16)f0.w;
  p0[4]=(__bf16)f1.x; p0[5]=(__bf16)f1.y; p0[6]=(__bf16)f1.z; p0[7]=(__bf16)f1.w;
  p1[0]=(__bf16)f2.x; p1[1]=(__bf16)f2.y; p1[2]=(__bf16)f2.z; p1[3]=(__bf16)f2.w;
  p1[4]=(__bf16)f3.x; p1[5]=(__bf16)f3.y; p1[6]=(__bf16)f3.z; p1[7]=(__bf16)f3.w;
  *(bf16x8*)(dst) = p0;
  *(bf16x8*)(dst + 8) = p1;
}

// ---------------- kernel 1: QZ'[bh][i][tau] = (q_i . pe)[clip(tau - dti,-64,64)+64]
__global__ __launch_bounds__(256) void qz_shift(
    const float* __restrict__ qb, const float* __restrict__ pos_emb,
    const int* __restrict__ dtimes, __bf16* __restrict__ QZg) {
  __shared__ __attribute__((aligned(16))) __bf16 peL[144][72];
  __shared__ __attribute__((aligned(16))) __bf16 QL[64][72];
  __shared__ __attribute__((aligned(16))) float qzf[64][144];
  const int tid = threadIdx.x, w = tid >> 6, l = tid & 63, c = l & 15, g = l >> 4;
  const int bid = blockIdx.x, qt = bid & 7, bh = bid >> 3, h = bh & 7, b = bh >> 3;
  const int qbase = qt * 64;
  const int r = tid >> 2, d0 = (tid & 3) * 16;

  for (int s = 0; s < 3; s++) {
    int rr = r + s * 64;
    if (rr >= 144) break;
    if (rr < 129) {
      cvt16(pos_emb + rr * 64 + d0, &peL[rr][d0]);
    } else {
      bf16x8 z = {};
      *(bf16x8*)&peL[rr][d0] = z;
      *(bf16x8*)&peL[rr][d0 + 8] = z;
    }
  }
  cvt16(qb + ((size_t)(b * SEQ + qbase + r)) * QKVS + h * HDIM + d0, &QL[r][d0]);
  __syncthreads();

  bf16x8 aq0 = *(bf16x8*)&QL[w * 16 + c][g * 8];
  bf16x8 aq1 = *(bf16x8*)&QL[w * 16 + c][32 + g * 8];
  for (int n = 0; n < 9; n++) {
    f32x4 acc = {};
    bf16x8 b0 = *(bf16x8*)&peL[n * 16 + c][g * 8];
    bf16x8 b1 = *(bf16x8*)&peL[n * 16 + c][32 + g * 8];
    acc = __builtin_amdgcn_mfma_f32_16x16x32_bf16(aq0, b0, acc, 0, 0, 0);
    acc = __builtin_amdgcn_mfma_f32_16x16x32_bf16(aq1, b1, acc, 0, 0, 0);
    int t = n * 16 + c;
    for (int r4 = 0; r4 < 4; r4++) qzf[w * 16 + g * 4 + r4][t] = acc[r4];
  }
  __syncthreads();

  int dti = dtimes[b * SEQ + qbase + r];
  int t0 = (tid & 3) * 32;
  for (int q4 = 0; q4 < 4; q4++) {
    bf16x8 o;
    for (int e = 0; e < 8; e++) {
      int tau = t0 + q4 * 8 + e;
      int t = min(max(tau - dti, -64), 64) + 64;
      o[e] = (__bf16)qzf[r][t];
    }
    *(bf16x8*)(QZg + ((size_t)(bh * SEQ + qbase + r)) * 128 + t0 + q4 * 8) = o;
  }
}

// ---------------- kernel 2: fused attention (main + zcombine), T14 reg prefetch
__global__ __launch_bounds__(256) void attn_fused(
    const float* __restrict__ qb, const float* __restrict__ kb,
    const float* __restrict__ vb, const float* __restrict__ dist,
    const int* __restrict__ dtimes, const int* __restrict__ maskp,
    const __bf16* __restrict__ QZg, const float* __restrict__ pos_emb,
    __bf16* __restrict__ outb) {
  __shared__ __attribute__((aligned(16))) char smem[76800];
  auto QL  = (__bf16(*)[72])(smem);            //  9216 B
  auto PL  = (__bf16(*)[72])(smem + 9216);     //  9216
  auto KL  = (__bf16(*)[72])(smem + 18432);    //  9216
  auto VT  = (__bf16(*)[72])(smem + 27648);    //  9216  VT[d][j]
  auto B1h = (__bf16(*)[72])(smem + 36864);    // 18432  one-hot[tau][j]
  auto qzL = (__bf16(*)[136])(smem + 55296);   // 17408
  int* dtsL = (int*)(smem + 72704);            //  2048
  int* mskL = (int*)(smem + 74752);            //  2048
  // epilogue aliases (over dead QL/PL/KL/VT/B1h):
  auto CLs = (float(*)[136])(smem);            // 34816
  auto peT = (__bf16(*)[136])(smem + 34816);   // 17408 -> ends 52224 < 55296

  const int tid = threadIdx.x, w = tid >> 6, l = tid & 63, c = l & 15, g = l >> 4;
  const int bid = blockIdx.x;
  const int qt = bid & 7, h = (bid >> 3) & 7, b = bid >> 6, bh = bid >> 3;
  const int qbase = qt * 64;
  const int r = tid >> 2, d0 = (tid & 3) * 16;
  const int vd = l, vj0 = w * 16;  // V-transpose mapping: lane owns d-row

  // prefetch registers
  float kreg[16], vreg[16], dA[16], dB[16];
  auto loadK = [&](int jt) {
    const float* kp = kb + ((size_t)(b * SEQ + jt * 64 + r)) * QKVS + h * HDIM + d0;
    *(float4*)&kreg[0]  = *(const float4*)kp;
    *(float4*)&kreg[4]  = *(const float4*)(kp + 4);
    *(float4*)&kreg[8]  = *(const float4*)(kp + 8);
    *(float4*)&kreg[12] = *(const float4*)(kp + 12);
  };
  auto loadV = [&](int jt) {
    const float* vp = vb + ((size_t)(b * SEQ + jt * 64 + vj0)) * QKVS + h * HDIM + vd;
#pragma unroll
    for (int q = 0; q < 16; q++) vreg[q] = vp[(size_t)q * QKVS];
  };
  auto loadD = [&](int jt, float (&dd)[16]) {
#pragma unroll
    for (int n = 0; n < 4; n++)
#pragma unroll
      for (int r4 = 0; r4 < 4; r4++) {
        int il = w * 16 + g * 4 + r4;
        dd[n * 4 + r4] = dist[((size_t)(b * SEQ + qbase + il)) * SEQ + jt * 64 + n * 16 + c];
      }
  };

  // issue tile-0 loads first (overlap with prologue staging)
  loadK(0); loadV(0); loadD(0, dA);

  // prologue staging
  cvt16(qb + ((size_t)(b * SEQ + qbase + r)) * QKVS + h * HDIM + d0, &QL[r][d0]);
  {
    int ch = (tid & 3) * 32;
    const __bf16* src = QZg + ((size_t)(bh * SEQ + qbase + r)) * 128 + ch;
    for (int q4 = 0; q4 < 4; q4++)
      *(bf16x8*)&qzL[r][ch + q4 * 8] = *(const bf16x8*)(src + q4 * 8);
  }
  for (int idx = tid; idx < SEQ; idx += 256) {
    dtsL[idx] = dtimes[b * SEQ + idx];
    mskL[idx] = maskp[b * SEQ + idx];
  }
  {
    bf16x8 z = {};
    for (int idx = tid; idx < 128 * 9; idx += 256)
      *(bf16x8*)&B1h[idx / 9][(idx % 9) * 8] = z;
  }
  __syncthreads();

  bf16x8 aq0 = *(bf16x8*)&QL[w * 16 + c][g * 8];
  bf16x8 aq1 = *(bf16x8*)&QL[w * 16 + c][32 + g * 8];
  float lsum[4] = {0.f, 0.f, 0.f, 0.f};
  f32x4 Oacc[4] = {};
  f32x4 Cacc[8] = {};

  auto body = [&](int jt, float (&dcur)[16], float (&dnxt)[16]) {
    __syncthreads();  // (A) prev tile's LDS reads drained
    {  // KL from kreg
      bf16x8 pk0, pk1;
#pragma unroll
      for (int q = 0; q < 8; q++) { pk0[q] = (__bf16)kreg[q]; pk1[q] = (__bf16)kreg[q + 8]; }
      *(bf16x8*)&KL[r][d0] = pk0;
      *(bf16x8*)&KL[r][d0 + 8] = pk1;
    }
    {  // VT from vreg (lane-owns-d-row: vector stores, static idx)
      bf16x8 pv0, pv1;
#pragma unroll
      for (int q = 0; q < 8; q++) { pv0[q] = (__bf16)vreg[q]; pv1[q] = (__bf16)vreg[q + 8]; }
      *(bf16x8*)&VT[vd][vj0] = pv0;
      *(bf16x8*)&VT[vd][vj0 + 8] = pv1;
    }
    if (tid < 64) {  // one-hot maintenance (same thread, same column, ordered)
      if (jt > 0) {
        int tp = dtsL[(jt - 1) * 64 + tid], tn = dtsL[jt * 64 + tid];
        if (tp != tn) B1h[tp][tid] = (__bf16)0.f;
        B1h[tn][tid] = (__bf16)1.f;
      } else {
        B1h[dtsL[tid]][tid] = (__bf16)1.f;
      }
    }
    if (jt < 7) { loadK(jt + 1); loadV(jt + 1); loadD(jt + 1, dnxt); }  // T14 prefetch
    __syncthreads();  // (B)

    // scores -> P
#pragma unroll
    for (int n = 0; n < 4; n++) {
      f32x4 acc = {};
      bf16x8 bk0 = *(bf16x8*)&KL[n * 16 + c][g * 8];
      bf16x8 bk1 = *(bf16x8*)&KL[n * 16 + c][32 + g * 8];
      acc = __builtin_amdgcn_mfma_f32_16x16x32_bf16(aq0, bk0, acc, 0, 0, 0);
      acc = __builtin_amdgcn_mfma_f32_16x16x32_bf16(aq1, bk1, acc, 0, 0, 0);
      int jl = n * 16 + c, jg = jt * 64 + jl;
      int dtj = dtsL[jg];
      int mk = mskL[jg];
#pragma unroll
      for (int r4 = 0; r4 < 4; r4++) {
        int il = w * 16 + g * 4 + r4;
        float s = (acc[r4] + (float)qzL[il][dtj]) * 0.125f + 0.6f * dcur[n * 4 + r4];
        float p = mk ? __expf(s) : 0.f;
        lsum[r4] += p;
        PL[il][jl] = (__bf16)p;
      }
    }
    __syncthreads();  // (C)

    bf16x8 ap0 = *(bf16x8*)&PL[w * 16 + c][g * 8];
    bf16x8 ap1 = *(bf16x8*)&PL[w * 16 + c][32 + g * 8];
#pragma unroll
    for (int dn = 0; dn < 4; dn++) {
      bf16x8 bv0 = *(bf16x8*)&VT[dn * 16 + c][g * 8];
      bf16x8 bv1 = *(bf16x8*)&VT[dn * 16 + c][32 + g * 8];
      Oacc[dn] = __builtin_amdgcn_mfma_f32_16x16x32_bf16(ap0, bv0, Oacc[dn], 0, 0, 0);
      Oacc[dn] = __builtin_amdgcn_mfma_f32_16x16x32_bf16(ap1, bv1, Oacc[dn], 0, 0, 0);
    }
#pragma unroll
    for (int tn = 0; tn < 8; tn++) {
      bf16x8 bz0 = *(bf16x8*)&B1h[tn * 16 + c][g * 8];
      bf16x8 bz1 = *(bf16x8*)&B1h[tn * 16 + c][32 + g * 8];
      Cacc[tn] = __builtin_amdgcn_mfma_f32_16x16x32_bf16(ap0, bz0, Cacc[tn], 0, 0, 0);
      Cacc[tn] = __builtin_amdgcn_mfma_f32_16x16x32_bf16(ap1, bz1, Cacc[tn], 0, 0, 0);
    }
  };
  for (int jt2 = 0; jt2 < 8; jt2 += 2) {
    body(jt2, dA, dB);
    body(jt2 + 1, dB, dA);
  }

  // ======== fused zcombine epilogue ========
  __syncthreads();  // main-loop LDS reads done before reusing space
  {
    float4 z4 = {0.f, 0.f, 0.f, 0.f};
    for (int idx = tid; idx < 64 * 34; idx += 256) ((float4*)CLs)[idx] = z4;
  }
  for (int s = 0; s < 3; s++) {  // stage peT[d][t]
    int t = r + s * 64;
    if (t < 129) {
      float vals[16];
      *(float4*)&vals[0]  = *(const float4*)(pos_emb + t * 64 + d0);
      *(float4*)&vals[4]  = *(const float4*)(pos_emb + t * 64 + d0 + 4);
      *(float4*)&vals[8]  = *(const float4*)(pos_emb + t * 64 + d0 + 8);
      *(float4*)&vals[12] = *(const float4*)(pos_emb + t * 64 + d0 + 12);
#pragma unroll
      for (int q = 0; q < 16; q++) peT[d0 + q][t] = (__bf16)vals[q];
    }
  }
  __syncthreads();

  {  // scatter Cacc -> shifted CLs (interior 1-1 per row; edges via atomicAdd)
    int dti_r4[4];
#pragma unroll
    for (int r4 = 0; r4 < 4; r4++) dti_r4[r4] = dtsL[qbase + w * 16 + g * 4 + r4];
#pragma unroll
    for (int tn = 0; tn < 8; tn++)
#pragma unroll
      for (int r4 = 0; r4 < 4; r4++) {
        int il = w * 16 + g * 4 + r4;
        int tau = tn * 16 + c, d = tau - dti_r4[r4];
        float val = Cacc[tn][r4];
        if (d <= -64) atomicAdd(&CLs[il][0], val);
        else if (d >= 64) atomicAdd(&CLs[il][128], val);
        else CLs[il][d + 64] = val;
      }
  }
  __syncthreads();

  float linv[4];
#pragma unroll
  for (int r4 = 0; r4 < 4; r4++) {
    float s = lsum[r4];
    for (int off = 1; off < 16; off <<= 1) s += __shfl_xor(s, off);
    linv[r4] = 1.0f / s;
  }

  f32x4 acc2[4] = {};
#pragma unroll
  for (int ks = 0; ks < 4; ks++) {
    const float* ap = &CLs[w * 16 + c][ks * 32 + g * 8];
    float4 a0 = *(const float4*)ap, a1 = *(const float4*)(ap + 4);
    bf16x8 af;
    af[0]=(__bf16)a0.x; af[1]=(__bf16)a0.y; af[2]=(__bf16)a0.z; af[3]=(__bf16)a0.w;
    af[4]=(__bf16)a1.x; af[5]=(__bf16)a1.y; af[6]=(__bf16)a1.z; af[7]=(__bf16)a1.w;
#pragma unroll
    for (int dn = 0; dn < 4; dn++) {
      bf16x8 bf = *(bf16x8*)&peT[dn * 16 + c][ks * 32 + g * 8];
      acc2[dn] = __builtin_amdgcn_mfma_f32_16x16x32_bf16(af, bf, acc2[dn], 0, 0, 0);
    }
  }
#pragma unroll
  for (int r4 = 0; r4 < 4; r4++) {
    int il = w * 16 + g * 4 + r4;
    float c128 = CLs[il][128];
#pragma unroll
    for (int dn = 0; dn < 4; dn++) {
      int d = dn * 16 + c;
      float y = acc2[dn][r4] + c128 * (float)peT[d][128];
      outb[((size_t)(b * SEQ + qbase + il)) * EDIM + h * HDIM + d] =
          (__bf16)((Oacc[dn][r4] + y) * linv[r4]);
    }
  }
}

// ---------------- layernorm over rows of 512; 4 rows/block (wave per row)
__global__ __launch_bounds__(256) void ln_kernel(
    const float* __restrict__ in, const float* __restrict__ g,
    const float* __restrict__ bta, float* __restrict__ out,
    __bf16* __restrict__ outb) {
  int row = blockIdx.x * 4 + (threadIdx.x >> 6), lane = threadIdx.x & 63;
  const float* p = in + (size_t)row * EDIM;
  float4 v0 = *(const float4*)(p + lane * 8);
  float4 v1 = *(const float4*)(p + lane * 8 + 4);
  float vals[8] = {v0.x, v0.y, v0.z, v0.w, v1.x, v1.y, v1.z, v1.w};
  float s = 0.f;
  for (int j = 0; j < 8; j++) s += vals[j];
  for (int o = 32; o; o >>= 1) s += __shfl_xor(s, o);
  float mu = s * (1.0f / EDIM);
  float vs = 0.f;
  for (int j = 0; j < 8; j++) {
    vals[j] -= mu;
    vs += vals[j] * vals[j];
  }
  for (int o = 32; o; o >>= 1) vs += __shfl_xor(vs, o);
  float rs = rsqrtf(vs * (1.0f / EDIM) + 1e-5f);
  for (int j = 0; j < 8; j++) {
    int col = lane * 8 + j;
    float v = vals[j] * rs * g[col] + bta[col];
    out[(size_t)row * EDIM + col] = v;
    if (outb) outb[(size_t)row * EDIM + col] = (__bf16)v;
  }
}

extern "C" void kernel_launch(void* const* d_in, const int* in_sizes, int n_in,
                              void* d_out, int out_size, void* d_ws, size_t ws_size,
                              hipStream_t stream) {
  const float* x = (const float*)d_in[0];
  const float* dist = (const float*)d_in[1];
  const int* dtimes = (const int*)d_in[2];
  const int* maskp = (const int*)d_in[3];
  const float* wq_w = (const float*)d_in[4];
  const float* wq_b = (const float*)d_in[5];
  const float* wk_w = (const float*)d_in[6];
  const float* wk_b = (const float*)d_in[7];
  const float* wv_w = (const float*)d_in[8];
  const float* wv_b = (const float*)d_in[9];
  const float* wo_w = (const float*)d_in[10];
  const float* wo_b = (const float*)d_in[11];
  const float* pos_emb = (const float*)d_in[12];
  const float* w1 = (const float*)d_in[13];
  const float* b1 = (const float*)d_in[14];
  const float* w2 = (const float*)d_in[15];
  const float* b2 = (const float*)d_in[16];
  const float* ln1_g = (const float*)d_in[17];
  const float* ln1_b = (const float*)d_in[18];
  const float* ln2_g = (const float*)d_in[19];
  const float* ln2_b = (const float*)d_in[20];
  float* out = (float*)d_out;

  const int M = TOKENS;
  const size_t T = TOKENS;
  float* fws = (float*)d_ws;

  // ---- workspace layout (f32 units), lifetime-aliased (~69 MB total)
  float*  qkv    = fws;                               // [0, T*1536)
  float*  ln2in  = fws;                               // alias [0, T*512)
  float*  wo_out = fws + T * 512;                     // alias [T*512, T*1024)
  float*  attno  = fws + T * 1024;                    // alias [T*1024, T*1536)
  __bf16* QZg    = (__bf16*)(fws + T * 1536);         // [T*1536, T*2048)
  __bf16* attnob = (__bf16*)(fws + T * 2048);         // [T*2048, T*2304)
  __bf16* hid    = (__bf16*)(fws + T * 2304);         // [T*2304, T*3328)
  __bf16* attnb  = (__bf16*)(fws + T * 3328);         // [T*3328, T*3584)
  __bf16* xb     = (__bf16*)(fws + T * 3584);         // [T*3584, T*3840)
  __bf16* wqkvt  = (__bf16*)(fws + T * 3840);         // 1536*512 bf16
  __bf16* wot    = wqkvt + 1536 * 512;
  __bf16* w1t    = wot + 512 * 512;
  __bf16* w2t    = w1t + 512 * 2048;
  float*  qkvb   = (float*)(w2t + 2048 * 512);        // 1536 f32

  // ---- prep (all transposes + concat + x->bf16 in one launch)
  prep<<<4097, 256, 0, stream>>>(wq_w, wk_w, wv_w, wo_w, w1, w2, x,
                                 wq_b, wk_b, wv_b,
                                 wqkvt, wot, w1t, w2t, xb, qkvb);

  // ---- fused QKV projection: [4096x512] @ [512x1536]
  gemm128<128><<<dim3(1536 / 128, M / 128), 256, 0, stream>>>(
      xb, wqkvt, qkvb, nullptr, qkv, nullptr, M, 1536, 512, 0);

  // ---- attention
  qz_shift<<<512, 256, 0, stream>>>(qkv, pos_emb, dtimes, QZg);
  attn_fused<<<512, 256, 0, stream>>>(qkv, qkv + 512, qkv + 1024, dist, dtimes, maskp,
                                      QZg, pos_emb, attnb);

  // ---- output projection + residual, LN1 (dual f32/bf16 out)
  gemm128<64><<<dim3(512 / 64, M / 128), 256, 0, stream>>>(
      attnb, wot, wo_b, x, wo_out, nullptr, M, 512, 512, 0);
  ln_kernel<<<M / 4, 256, 0, stream>>>(wo_out, ln1_g, ln1_b, attno, attnob);

  // ---- FFN
  gemm128<128><<<dim3(2048 / 128, M / 128), 256, 0, stream>>>(
      attnob, w1t, b1, nullptr, nullptr, hid, M, 2048, 512, 1);
  gemm128<64><<<dim3(512 / 64, M / 128), 256, 0, stream>>>(
      hid, w2t, b2, attno, ln2in, nullptr, M, 512, 2048, 0);
  ln_kernel<<<M / 4, 256, 0, stream>>>(ln2in, ln2_g, ln2_b, out, nullptr);
}

// Round 8
// 286.113 us; speedup vs baseline: 3.7136x; 1.0749x over previous
//
#include <hip/hip_runtime.h>
#include <hip/hip_bf16.h>

typedef __bf16 bf16x8 __attribute__((ext_vector_type(8)));
typedef float f32x4 __attribute__((ext_vector_type(4)));

#define TOKENS 4096
#define EDIM 512
#define FDIM 2048
#define SEQ 512
#define NHEAD 8
#define HDIM 64
#define QKVS 1536

// ---------------- prep: weight transposes (f32->bf16), bias concat, x/dist->bf16
__global__ __launch_bounds__(256) void prep(
    const float* __restrict__ wq_w, const float* __restrict__ wk_w,
    const float* __restrict__ wv_w, const float* __restrict__ wo_w,
    const float* __restrict__ w1, const float* __restrict__ w2,
    const float* __restrict__ x, const float* __restrict__ dist,
    const float* __restrict__ wq_b, const float* __restrict__ wk_b,
    const float* __restrict__ wv_b,
    __bf16* __restrict__ wqkvt, __bf16* __restrict__ wot,
    __bf16* __restrict__ w1t, __bf16* __restrict__ w2t,
    __bf16* __restrict__ xb, __bf16* __restrict__ distb,
    float* __restrict__ qkvb) {
  __shared__ float t[32][33];
  int bid = blockIdx.x;
  if (bid < 3072) {  // transposes
    const float* src;
    __bf16* dst;
    int R = 512, C = 512, bx, by;
    if (bid < 1024) {
      int seg = bid >> 8, local = bid & 255;
      src = seg == 0 ? wq_w : seg == 1 ? wk_w : seg == 2 ? wv_w : wo_w;
      dst = seg == 0 ? wqkvt : seg == 1 ? wqkvt + 262144 : seg == 2 ? wqkvt + 524288 : wot;
      bx = local & 15; by = local >> 4;
    } else if (bid < 2048) {
      int local = bid - 1024; src = w1; dst = w1t; C = 2048;
      bx = local & 63; by = local >> 6;
    } else {
      int local = bid - 2048; src = w2; dst = w2t; R = 2048;
      bx = local & 15; by = local >> 4;
    }
    int c0 = bx * 32, r0 = by * 32;
    int tx = threadIdx.x & 31, ty = threadIdx.x >> 5;
    for (int rr = ty; rr < 32; rr += 8)
      t[rr][tx] = src[(size_t)(r0 + rr) * C + c0 + tx];
    __syncthreads();
    for (int rr = ty; rr < 32; rr += 8)
      dst[(size_t)(c0 + rr) * R + r0 + tx] = (__bf16)t[tx][rr];
  } else if (bid < 4096) {  // x f32->bf16
    int i = (bid - 3072) * 256 + threadIdx.x;
    float4 a = ((const float4*)x)[i * 2];
    float4 b4 = ((const float4*)x)[i * 2 + 1];
    bf16x8 p;
    p[0] = (__bf16)a.x; p[1] = (__bf16)a.y; p[2] = (__bf16)a.z; p[3] = (__bf16)a.w;
    p[4] = (__bf16)b4.x; p[5] = (__bf16)b4.y; p[6] = (__bf16)b4.z; p[7] = (__bf16)b4.w;
    ((bf16x8*)xb)[i] = p;
  } else if (bid == 4096) {  // bias concat
    for (int i = threadIdx.x; i < 1536; i += 256)
      qkvb[i] = i < 512 ? wq_b[i] : i < 1024 ? wk_b[i - 512] : wv_b[i - 1024];
  } else {  // dist f32->bf16
    int i = (bid - 4097) * 256 + threadIdx.x;
    float4 a = ((const float4*)dist)[i * 2];
    float4 b4 = ((const float4*)dist)[i * 2 + 1];
    bf16x8 p;
    p[0] = (__bf16)a.x; p[1] = (__bf16)a.y; p[2] = (__bf16)a.z; p[3] = (__bf16)a.w;
    p[4] = (__bf16)b4.x; p[5] = (__bf16)b4.y; p[6] = (__bf16)b4.z; p[7] = (__bf16)b4.w;
    ((bf16x8*)distb)[i] = p;
  }
}

// async global->LDS, 16B per lane; lds dest = wave-uniform base + lane*16 (HW)
__device__ __forceinline__ void gl_lds16(const void* g, void* l) {
  __builtin_amdgcn_global_load_lds(
      (const __attribute__((address_space(1))) unsigned int*)(size_t)g,
      (__attribute__((address_space(3))) unsigned int*)(size_t)l, 16, 0, 0);
}

// ---------------- m97-style GEMM: C = op(A(bf16,[M][K]) @ Bt(bf16,[N][K])^T)
template <int BN>
__global__ __launch_bounds__(256) void gemm128(
    const __bf16* __restrict__ A, const __bf16* __restrict__ Bt,
    const float* __restrict__ bias, const float* __restrict__ resid,
    float* __restrict__ Cf, __bf16* __restrict__ Cb,
    int M, int N, int K, int relu) {
  constexpr int NI = BN / 32;
  __shared__ __attribute__((aligned(16))) __bf16 Asl[128 * 64];
  __shared__ __attribute__((aligned(16))) __bf16 Bsl[BN * 64];
  const int tid = threadIdx.x, w = tid >> 6, lane = tid & 63;
  const int c = lane & 15, g = lane >> 4;
  const int m0 = blockIdx.y * 128, n0 = blockIdx.x * BN;
  const int wr = w >> 1, wc = w & 1;
  f32x4 acc[4][NI] = {};
  const __bf16* Ab = A + (size_t)m0 * K;
  const __bf16* Bb = Bt + (size_t)n0 * K;

  for (int k0 = 0; k0 < K; k0 += 64) {
#pragma unroll
    for (int s = 0; s < 4; s++) {
      int L = (s * 256 + tid) * 16;
      int row = L >> 7;
      int lslot = ((L >> 4) & 7) ^ (row & 7);
      gl_lds16(Ab + (size_t)row * K + k0 + lslot * 8,
               (char*)Asl + s * 4096 + w * 1024);
    }
#pragma unroll
    for (int s = 0; s < NI; s++) {
      int L = (s * 256 + tid) * 16;
      int row = L >> 7;
      int lslot = ((L >> 4) & 7) ^ (row & 7);
      gl_lds16(Bb + (size_t)row * K + k0 + lslot * 8,
               (char*)Bsl + s * 4096 + w * 1024);
    }
    __syncthreads();

    bf16x8 af[4][2], bfr[NI][2];
#pragma unroll
    for (int mi = 0; mi < 4; mi++)
#pragma unroll
      for (int ko = 0; ko < 2; ko++) {
        int row = wr * 64 + mi * 16 + c;
        int ps = (ko * 4 + g) ^ (row & 7);
        af[mi][ko] = *(const bf16x8*)&Asl[row * 64 + ps * 8];
      }
#pragma unroll
    for (int ni = 0; ni < NI; ni++)
#pragma unroll
      for (int ko = 0; ko < 2; ko++) {
        int row = wc * (BN / 2) + ni * 16 + c;
        int ps = (ko * 4 + g) ^ (row & 7);
        bfr[ni][ko] = *(const bf16x8*)&Bsl[row * 64 + ps * 8];
      }
#pragma unroll
    for (int mi = 0; mi < 4; mi++)
#pragma unroll
      for (int ni = 0; ni < NI; ni++) {
        acc[mi][ni] = __builtin_amdgcn_mfma_f32_16x16x32_bf16(af[mi][0], bfr[ni][0], acc[mi][ni], 0, 0, 0);
        acc[mi][ni] = __builtin_amdgcn_mfma_f32_16x16x32_bf16(af[mi][1], bfr[ni][1], acc[mi][ni], 0, 0, 0);
      }
    __syncthreads();
  }

#pragma unroll
  for (int mi = 0; mi < 4; mi++)
#pragma unroll
    for (int ni = 0; ni < NI; ni++)
#pragma unroll
      for (int r = 0; r < 4; r++) {
        int row = m0 + wr * 64 + mi * 16 + g * 4 + r;
        int col = n0 + wc * (BN / 2) + ni * 16 + c;
        float v = acc[mi][ni][r] + bias[col];
        if (resid) v += resid[(size_t)row * N + col];
        if (relu) v = fmaxf(v, 0.f);
        if (Cf) Cf[(size_t)row * N + col] = v;
        if (Cb) Cb[(size_t)row * N + col] = (__bf16)v;
      }
}

// read 16 f32, convert, store as two bf16x8 (dst 16B-aligned)
__device__ inline void cvt16(const float* __restrict__ src, __bf16* dst) {
  float4 f0 = *(const float4*)(src);
  float4 f1 = *(const float4*)(src + 4);
  float4 f2 = *(const float4*)(src + 8);
  float4 f3 = *(const float4*)(src + 12);
  bf16x8 p0, p1;
  p0[0]=(__bf16)f0.x; p0[1]=(__bf16)f0.y; p0[2]=(__bf16)f0.z; p0[3]=(__bf16)f0.w;
  p0[4]=(__bf16)f1.x; p0[5]=(__bf16)f1.y; p0[6]=(__bf16)f1.z; p0[7]=(__bf16)f1.w;
  p1[0]=(__bf16)f2.x; p1[1]=(__bf16)f2.y; p1[2]=(__bf16)f2.z; p1[3]=(__bf16)f2.w;
  p1[4]=(__bf16)f3.x; p1[5]=(__bf16)f3.y; p1[6]=(__bf16)f3.z; p1[7]=(__bf16)f3.w;
  *(bf16x8*)(dst) = p0;
  *(bf16x8*)(dst + 8) = p1;
}

// ---------------- kernel 1: QZ'[bh][i][tau] = (q_i . pe)[clip(tau - dti,-64,64)+64]
__global__ __launch_bounds__(256) void qz_shift(
    const __bf16* __restrict__ qb, const float* __restrict__ pos_emb,
    const int* __restrict__ dtimes, __bf16* __restrict__ QZg) {
  __shared__ __attribute__((aligned(16))) __bf16 peL[144][72];
  __shared__ __attribute__((aligned(16))) __bf16 QL[64][72];
  __shared__ __attribute__((aligned(16))) float qzf[64][144];
  const int tid = threadIdx.x, w = tid >> 6, l = tid & 63, c = l & 15, g = l >> 4;
  const int bid = blockIdx.x, qt = bid & 7, bh = bid >> 3, h = bh & 7, b = bh >> 3;
  const int qbase = qt * 64;
  const int r = tid >> 2, d0 = (tid & 3) * 16;

  for (int s = 0; s < 3; s++) {
    int rr = r + s * 64;
    if (rr >= 144) break;
    if (rr < 129) {
      cvt16(pos_emb + rr * 64 + d0, &peL[rr][d0]);
    } else {
      bf16x8 z = {};
      *(bf16x8*)&peL[rr][d0] = z;
      *(bf16x8*)&peL[rr][d0 + 8] = z;
    }
  }
  {
    const __bf16* qp = qb + ((size_t)(b * SEQ + qbase + r)) * QKVS + h * HDIM + d0;
    *(bf16x8*)&QL[r][d0] = *(const bf16x8*)qp;
    *(bf16x8*)&QL[r][d0 + 8] = *(const bf16x8*)(qp + 8);
  }
  __syncthreads();

  bf16x8 aq0 = *(bf16x8*)&QL[w * 16 + c][g * 8];
  bf16x8 aq1 = *(bf16x8*)&QL[w * 16 + c][32 + g * 8];
  for (int n = 0; n < 9; n++) {
    f32x4 acc = {};
    bf16x8 b0 = *(bf16x8*)&peL[n * 16 + c][g * 8];
    bf16x8 b1 = *(bf16x8*)&peL[n * 16 + c][32 + g * 8];
    acc = __builtin_amdgcn_mfma_f32_16x16x32_bf16(aq0, b0, acc, 0, 0, 0);
    acc = __builtin_amdgcn_mfma_f32_16x16x32_bf16(aq1, b1, acc, 0, 0, 0);
    int t = n * 16 + c;
    for (int r4 = 0; r4 < 4; r4++) qzf[w * 16 + g * 4 + r4][t] = acc[r4];
  }
  __syncthreads();

  int dti = dtimes[b * SEQ + qbase + r];
  int t0 = (tid & 3) * 32;
  for (int q4 = 0; q4 < 4; q4++) {
    bf16x8 o;
    for (int e = 0; e < 8; e++) {
      int tau = t0 + q4 * 8 + e;
      int t = min(max(tau - dti, -64), 64) + 64;
      o[e] = (__bf16)qzf[r][t];
    }
    *(bf16x8*)(QZg + ((size_t)(bh * SEQ + qbase + r)) * 128 + t0 + q4 * 8) = o;
  }
}

// ---------------- kernel 2: fused attention; K via global_load_lds (XOR swizzle)
#define KL_OFF 18432
__global__ __launch_bounds__(256) void attn_fused(
    const __bf16* __restrict__ qb, const __bf16* __restrict__ kb,
    const __bf16* __restrict__ vb, const __bf16* __restrict__ distb,
    const int* __restrict__ dtimes, const int* __restrict__ maskp,
    const __bf16* __restrict__ QZg, const float* __restrict__ pos_emb,
    __bf16* __restrict__ outb) {
  __shared__ __attribute__((aligned(16))) char smem[75776];
  auto QL  = (__bf16(*)[72])(smem);            //  9216 B
  auto PL  = (__bf16(*)[72])(smem + 9216);     //  9216
  char* KLb = smem + KL_OFF;                   //  8192  linear [64][64] swizzled
  auto VT  = (__bf16(*)[72])(smem + 26624);    //  9216  VT[d][j]
  auto B1h = (__bf16(*)[72])(smem + 35840);    // 18432  one-hot[tau][j]
  auto qzL = (__bf16(*)[136])(smem + 54272);   // 17408
  int* dtsL = (int*)(smem + 71680);            //  2048
  int* mskL = (int*)(smem + 73728);            //  2048
  // epilogue aliases (over dead QL/PL/KL/VT/B1h):
  auto CLs = (float(*)[136])(smem);            // 34816
  auto peT = (__bf16(*)[136])(smem + 34816);   // 17408 -> ends 52224 < 54272

  const int tid = threadIdx.x, w = tid >> 6, l = tid & 63, c = l & 15, g = l >> 4;
  const int bid = blockIdx.x;
  const int qt = bid & 7, h = (bid >> 3) & 7, b = bid >> 6, bh = bid >> 3;
  const int qbase = qt * 64;
  const int r = tid >> 2, d0 = (tid & 3) * 16;
  const int vd = l, vj0 = w * 16;  // V-transpose: lane owns d-row

  // K tile DMA: 64x64 bf16 = 8KB = 2 issues; linear dest + inverse-swizzled src
  auto stageK = [&](int jt) {
#pragma unroll
    for (int s = 0; s < 2; s++) {
      int L = (s * 256 + tid) * 16;
      int row = L >> 7;
      int sl = ((L >> 4) & 7) ^ (row & 7);
      gl_lds16(kb + ((size_t)(b * SEQ + jt * 64 + row)) * QKVS + h * HDIM + sl * 8,
               KLb + s * 4096 + w * 1024);
    }
  };
  __bf16 vreg[16];
  float dA[16], dB[16];
  auto loadV = [&](int jt) {
    const __bf16* vp = vb + ((size_t)(b * SEQ + jt * 64 + vj0)) * QKVS + h * HDIM + vd;
#pragma unroll
    for (int q = 0; q < 16; q++) vreg[q] = vp[(size_t)q * QKVS];
  };
  auto loadD = [&](int jt, float (&dd)[16]) {
#pragma unroll
    for (int n = 0; n < 4; n++)
#pragma unroll
      for (int r4 = 0; r4 < 4; r4++) {
        int il = w * 16 + g * 4 + r4;
        dd[n * 4 + r4] =
            (float)distb[((size_t)(b * SEQ + qbase + il)) * SEQ + jt * 64 + n * 16 + c];
      }
  };

  // issue tile-0 loads first
  stageK(0); loadV(0); loadD(0, dA);

  // prologue staging
  {
    const __bf16* qp = qb + ((size_t)(b * SEQ + qbase + r)) * QKVS + h * HDIM + d0;
    *(bf16x8*)&QL[r][d0] = *(const bf16x8*)qp;
    *(bf16x8*)&QL[r][d0 + 8] = *(const bf16x8*)(qp + 8);
  }
  {
    int ch = (tid & 3) * 32;
    const __bf16* src = QZg + ((size_t)(bh * SEQ + qbase + r)) * 128 + ch;
    for (int q4 = 0; q4 < 4; q4++)
      *(bf16x8*)&qzL[r][ch + q4 * 8] = *(const bf16x8*)(src + q4 * 8);
  }
  for (int idx = tid; idx < SEQ; idx += 256) {
    dtsL[idx] = dtimes[b * SEQ + idx];
    mskL[idx] = maskp[b * SEQ + idx];
  }
  {
    bf16x8 z = {};
    for (int idx = tid; idx < 128 * 9; idx += 256)
      *(bf16x8*)&B1h[idx / 9][(idx % 9) * 8] = z;
  }
  __syncthreads();

  bf16x8 aq0 = *(bf16x8*)&QL[w * 16 + c][g * 8];
  bf16x8 aq1 = *(bf16x8*)&QL[w * 16 + c][32 + g * 8];
  float lsum[4] = {0.f, 0.f, 0.f, 0.f};
  f32x4 Oacc[4] = {};
  f32x4 Cacc[8] = {};

  auto body = [&](int jt, float (&dcur)[16], float (&dnxt)[16]) {
    __syncthreads();  // (A) prev-tile LDS reads drained; K DMA landed
    {  // VT from vreg
      bf16x8 pv0, pv1;
#pragma unroll
      for (int q = 0; q < 8; q++) { pv0[q] = vreg[q]; pv1[q] = vreg[q + 8]; }
      *(bf16x8*)&VT[vd][vj0] = pv0;
      *(bf16x8*)&VT[vd][vj0 + 8] = pv1;
    }
    if (tid < 64) {  // one-hot maintenance
      if (jt > 0) {
        int tp = dtsL[(jt - 1) * 64 + tid], tn = dtsL[jt * 64 + tid];
        if (tp != tn) B1h[tp][tid] = (__bf16)0.f;
        B1h[tn][tid] = (__bf16)1.f;
      } else {
        B1h[dtsL[tid]][tid] = (__bf16)1.f;
      }
    }
    if (jt < 7) { loadV(jt + 1); loadD(jt + 1, dnxt); }  // reg prefetch
    __syncthreads();  // (B)

    // scores -> P (swizzled KL reads)
#pragma unroll
    for (int n = 0; n < 4; n++) {
      f32x4 acc = {};
      int row = n * 16 + c;
      bf16x8 bk0 = *(const bf16x8*)(KLb + row * 128 + ((g ^ (row & 7)) * 16));
      bf16x8 bk1 = *(const bf16x8*)(KLb + row * 128 + (((g + 4) ^ (row & 7)) * 16));
      acc = __builtin_amdgcn_mfma_f32_16x16x32_bf16(aq0, bk0, acc, 0, 0, 0);
      acc = __builtin_amdgcn_mfma_f32_16x16x32_bf16(aq1, bk1, acc, 0, 0, 0);
      int jl = n * 16 + c, jg = jt * 64 + jl;
      int dtj = dtsL[jg];
      int mk = mskL[jg];
#pragma unroll
      for (int r4 = 0; r4 < 4; r4++) {
        int il = w * 16 + g * 4 + r4;
        float s = (acc[r4] + (float)qzL[il][dtj]) * 0.125f + 0.6f * dcur[n * 4 + r4];
        float p = mk ? __expf(s) : 0.f;
        lsum[r4] += p;
        PL[il][jl] = (__bf16)p;
      }
    }
    __syncthreads();  // (C) P visible; all KL reads done
    if (jt < 7) stageK(jt + 1);  // K DMA overlaps PV phase

    bf16x8 ap0 = *(bf16x8*)&PL[w * 16 + c][g * 8];
    bf16x8 ap1 = *(bf16x8*)&PL[w * 16 + c][32 + g * 8];
#pragma unroll
    for (int dn = 0; dn < 4; dn++) {
      bf16x8 bv0 = *(bf16x8*)&VT[dn * 16 + c][g * 8];
      bf16x8 bv1 = *(bf16x8*)&VT[dn * 16 + c][32 + g * 8];
      Oacc[dn] = __builtin_amdgcn_mfma_f32_16x16x32_bf16(ap0, bv0, Oacc[dn], 0, 0, 0);
      Oacc[dn] = __builtin_amdgcn_mfma_f32_16x16x32_bf16(ap1, bv1, Oacc[dn], 0, 0, 0);
    }
#pragma unroll
    for (int tn = 0; tn < 8; tn++) {
      bf16x8 bz0 = *(bf16x8*)&B1h[tn * 16 + c][g * 8];
      bf16x8 bz1 = *(bf16x8*)&B1h[tn * 16 + c][32 + g * 8];
      Cacc[tn] = __builtin_amdgcn_mfma_f32_16x16x32_bf16(ap0, bz0, Cacc[tn], 0, 0, 0);
      Cacc[tn] = __builtin_amdgcn_mfma_f32_16x16x32_bf16(ap1, bz1, Cacc[tn], 0, 0, 0);
    }
  };
  for (int jt2 = 0; jt2 < 8; jt2 += 2) {
    body(jt2, dA, dB);
    body(jt2 + 1, dB, dA);
  }

  // ======== fused zcombine epilogue ========
  __syncthreads();
  {
    float4 z4 = {0.f, 0.f, 0.f, 0.f};
    for (int idx = tid; idx < 64 * 34; idx += 256) ((float4*)CLs)[idx] = z4;
  }
  for (int s = 0; s < 3; s++) {
    int t = r + s * 64;
    if (t < 129) {
      float vals[16];
      *(float4*)&vals[0]  = *(const float4*)(pos_emb + t * 64 + d0);
      *(float4*)&vals[4]  = *(const float4*)(pos_emb + t * 64 + d0 + 4);
      *(float4*)&vals[8]  = *(const float4*)(pos_emb + t * 64 + d0 + 8);
      *(float4*)&vals[12] = *(const float4*)(pos_emb + t * 64 + d0 + 12);
#pragma unroll
      for (int q = 0; q < 16; q++) peT[d0 + q][t] = (__bf16)vals[q];
    }
  }
  __syncthreads();

  {
    int dti_r4[4];
#pragma unroll
    for (int r4 = 0; r4 < 4; r4++) dti_r4[r4] = dtsL[qbase + w * 16 + g * 4 + r4];
#pragma unroll
    for (int tn = 0; tn < 8; tn++)
#pragma unroll
      for (int r4 = 0; r4 < 4; r4++) {
        int il = w * 16 + g * 4 + r4;
        int tau = tn * 16 + c, d = tau - dti_r4[r4];
        float val = Cacc[tn][r4];
        if (d <= -64) atomicAdd(&CLs[il][0], val);
        else if (d >= 64) atomicAdd(&CLs[il][128], val);
        else CLs[il][d + 64] = val;
      }
  }
  __syncthreads();

  float linv[4];
#pragma unroll
  for (int r4 = 0; r4 < 4; r4++) {
    float s = lsum[r4];
    for (int off = 1; off < 16; off <<= 1) s += __shfl_xor(s, off);
    linv[r4] = 1.0f / s;
  }

  f32x4 acc2[4] = {};
#pragma unroll
  for (int ks = 0; ks < 4; ks++) {
    const float* ap = &CLs[w * 16 + c][ks * 32 + g * 8];
    float4 a0 = *(const float4*)ap, a1 = *(const float4*)(ap + 4);
    bf16x8 af;
    af[0]=(__bf16)a0.x; af[1]=(__bf16)a0.y; af[2]=(__bf16)a0.z; af[3]=(__bf16)a0.w;
    af[4]=(__bf16)a1.x; af[5]=(__bf16)a1.y; af[6]=(__bf16)a1.z; af[7]=(__bf16)a1.w;
#pragma unroll
    for (int dn = 0; dn < 4; dn++) {
      bf16x8 bf = *(bf16x8*)&peT[dn * 16 + c][ks * 32 + g * 8];
      acc2[dn] = __builtin_amdgcn_mfma_f32_16x16x32_bf16(af, bf, acc2[dn], 0, 0, 0);
    }
  }
#pragma unroll
  for (int r4 = 0; r4 < 4; r4++) {
    int il = w * 16 + g * 4 + r4;
    float c128 = CLs[il][128];
#pragma unroll
    for (int dn = 0; dn < 4; dn++) {
      int d = dn * 16 + c;
      float y = acc2[dn][r4] + c128 * (float)peT[d][128];
      outb[((size_t)(b * SEQ + qbase + il)) * EDIM + h * HDIM + d] =
          (__bf16)((Oacc[dn][r4] + y) * linv[r4]);
    }
  }
}

// ---------------- layernorm over rows of 512; 4 rows/block
__global__ __launch_bounds__(256) void ln_kernel(
    const float* __restrict__ in, const float* __restrict__ g,
    const float* __restrict__ bta, float* __restrict__ out,
    __bf16* __restrict__ outb) {
  int row = blockIdx.x * 4 + (threadIdx.x >> 6), lane = threadIdx.x & 63;
  const float* p = in + (size_t)row * EDIM;
  float4 v0 = *(const float4*)(p + lane * 8);
  float4 v1 = *(const float4*)(p + lane * 8 + 4);
  float vals[8] = {v0.x, v0.y, v0.z, v0.w, v1.x, v1.y, v1.z, v1.w};
  float s = 0.f;
  for (int j = 0; j < 8; j++) s += vals[j];
  for (int o = 32; o; o >>= 1) s += __shfl_xor(s, o);
  float mu = s * (1.0f / EDIM);
  float vs = 0.f;
  for (int j = 0; j < 8; j++) {
    vals[j] -= mu;
    vs += vals[j] * vals[j];
  }
  for (int o = 32; o; o >>= 1) vs += __shfl_xor(vs, o);
  float rs = rsqrtf(vs * (1.0f / EDIM) + 1e-5f);
  for (int j = 0; j < 8; j++) {
    int col = lane * 8 + j;
    float v = vals[j] * rs * g[col] + bta[col];
    out[(size_t)row * EDIM + col] = v;
    if (outb) outb[(size_t)row * EDIM + col] = (__bf16)v;
  }
}

extern "C" void kernel_launch(void* const* d_in, const int* in_sizes, int n_in,
                              void* d_out, int out_size, void* d_ws, size_t ws_size,
                              hipStream_t stream) {
  const float* x = (const float*)d_in[0];
  const float* dist = (const float*)d_in[1];
  const int* dtimes = (const int*)d_in[2];
  const int* maskp = (const int*)d_in[3];
  const float* wq_w = (const float*)d_in[4];
  const float* wq_b = (const float*)d_in[5];
  const float* wk_w = (const float*)d_in[6];
  const float* wk_b = (const float*)d_in[7];
  const float* wv_w = (const float*)d_in[8];
  const float* wv_b = (const float*)d_in[9];
  const float* wo_w = (const float*)d_in[10];
  const float* wo_b = (const float*)d_in[11];
  const float* pos_emb = (const float*)d_in[12];
  const float* w1 = (const float*)d_in[13];
  const float* b1 = (const float*)d_in[14];
  const float* w2 = (const float*)d_in[15];
  const float* b2 = (const float*)d_in[16];
  const float* ln1_g = (const float*)d_in[17];
  const float* ln1_b = (const float*)d_in[18];
  const float* ln2_g = (const float*)d_in[19];
  const float* ln2_b = (const float*)d_in[20];
  float* out = (float*)d_out;

  const int M = TOKENS;
  const size_t T = TOKENS;
  float* fws = (float*)d_ws;

  // ---- workspace layout (f32 units), lifetime-aliased (~77.6 MB)
  __bf16* qkvB   = (__bf16*)fws;                      // T*1536 bf16 = T*768 f32
  float*  ln2in  = fws;                               // alias (after attn)
  float*  wo_out = fws + T * 768;
  float*  attno  = fws + T * 1280;
  __bf16* QZg    = (__bf16*)(fws + T * 1792);         // T*1024 bf16
  __bf16* attnob = (__bf16*)(fws + T * 2304);
  __bf16* hid    = (__bf16*)(fws + T * 2560);         // T*2048 bf16
  __bf16* attnb  = (__bf16*)(fws + T * 3584);
  __bf16* xb     = (__bf16*)(fws + T * 3840);
  __bf16* wqkvt  = (__bf16*)(fws + T * 4096);         // 786432 bf16
  __bf16* wot    = wqkvt + 1536 * 512;
  __bf16* w1t    = wot + 512 * 512;
  __bf16* w2t    = w1t + 512 * 2048;
  __bf16* distb  = w2t + 2048 * 512;                  // 2097152 bf16
  float*  qkvb   = (float*)(distb + 2097152);         // 1536 f32

  // ---- prep
  prep<<<5121, 256, 0, stream>>>(wq_w, wk_w, wv_w, wo_w, w1, w2, x, dist,
                                 wq_b, wk_b, wv_b,
                                 wqkvt, wot, w1t, w2t, xb, distb, qkvb);

  // ---- fused QKV projection (bf16 out): [4096x512] @ [512x1536]
  gemm128<128><<<dim3(1536 / 128, M / 128), 256, 0, stream>>>(
      xb, wqkvt, qkvb, nullptr, nullptr, qkvB, M, 1536, 512, 0);

  // ---- attention
  qz_shift<<<512, 256, 0, stream>>>(qkvB, pos_emb, dtimes, QZg);
  attn_fused<<<512, 256, 0, stream>>>(qkvB, qkvB + 512, qkvB + 1024, distb,
                                      dtimes, maskp, QZg, pos_emb, attnb);

  // ---- output projection + residual, LN1
  gemm128<64><<<dim3(512 / 64, M / 128), 256, 0, stream>>>(
      attnb, wot, wo_b, x, wo_out, nullptr, M, 512, 512, 0);
  ln_kernel<<<M / 4, 256, 0, stream>>>(wo_out, ln1_g, ln1_b, attno, attnob);

  // ---- FFN
  gemm128<128><<<dim3(2048 / 128, M / 128), 256, 0, stream>>>(
      attnob, w1t, b1, nullptr, nullptr, hid, M, 2048, 512, 1);
  gemm128<64><<<dim3(512 / 64, M / 128), 256, 0, stream>>>(
      hid, w2t, b2, attno, ln2in, nullptr, M, 512, 2048, 0);
  ln_kernel<<<M / 4, 256, 0, stream>>>(ln2in, ln2_g, ln2_b, out, nullptr);
}

// Round 9
// 249.688 us; speedup vs baseline: 4.2553x; 1.1459x over previous
//
#include <hip/hip_runtime.h>
#include <hip/hip_bf16.h>

typedef __bf16 bf16x8 __attribute__((ext_vector_type(8)));
typedef float f32x4 __attribute__((ext_vector_type(4)));

#define TOKENS 4096
#define EDIM 512
#define FDIM 2048
#define SEQ 512
#define NHEAD 8
#define HDIM 64
#define QKVS 1536

// ---------------- prep: weight transposes (f32->bf16), bias concat, x/dist->bf16
__global__ __launch_bounds__(256) void prep(
    const float* __restrict__ wq_w, const float* __restrict__ wk_w,
    const float* __restrict__ wv_w, const float* __restrict__ wo_w,
    const float* __restrict__ w1, const float* __restrict__ w2,
    const float* __restrict__ x, const float* __restrict__ dist,
    const float* __restrict__ wq_b, const float* __restrict__ wk_b,
    const float* __restrict__ wv_b,
    __bf16* __restrict__ wqkvt, __bf16* __restrict__ wot,
    __bf16* __restrict__ w1t, __bf16* __restrict__ w2t,
    __bf16* __restrict__ xb, __bf16* __restrict__ distb,
    float* __restrict__ qkvb) {
  __shared__ float t[32][33];
  int bid = blockIdx.x;
  if (bid < 3072) {  // transposes
    const float* src;
    __bf16* dst;
    int R = 512, C = 512, bx, by;
    if (bid < 1024) {
      int seg = bid >> 8, local = bid & 255;
      src = seg == 0 ? wq_w : seg == 1 ? wk_w : seg == 2 ? wv_w : wo_w;
      dst = seg == 0 ? wqkvt : seg == 1 ? wqkvt + 262144 : seg == 2 ? wqkvt + 524288 : wot;
      bx = local & 15; by = local >> 4;
    } else if (bid < 2048) {
      int local = bid - 1024; src = w1; dst = w1t; C = 2048;
      bx = local & 63; by = local >> 6;
    } else {
      int local = bid - 2048; src = w2; dst = w2t; R = 2048;
      bx = local & 15; by = local >> 4;
    }
    int c0 = bx * 32, r0 = by * 32;
    int tx = threadIdx.x & 31, ty = threadIdx.x >> 5;
    for (int rr = ty; rr < 32; rr += 8)
      t[rr][tx] = src[(size_t)(r0 + rr) * C + c0 + tx];
    __syncthreads();
    for (int rr = ty; rr < 32; rr += 8)
      dst[(size_t)(c0 + rr) * R + r0 + tx] = (__bf16)t[tx][rr];
  } else if (bid < 4096) {  // x f32->bf16
    int i = (bid - 3072) * 256 + threadIdx.x;
    float4 a = ((const float4*)x)[i * 2];
    float4 b4 = ((const float4*)x)[i * 2 + 1];
    bf16x8 p;
    p[0] = (__bf16)a.x; p[1] = (__bf16)a.y; p[2] = (__bf16)a.z; p[3] = (__bf16)a.w;
    p[4] = (__bf16)b4.x; p[5] = (__bf16)b4.y; p[6] = (__bf16)b4.z; p[7] = (__bf16)b4.w;
    ((bf16x8*)xb)[i] = p;
  } else if (bid == 4096) {  // bias concat
    for (int i = threadIdx.x; i < 1536; i += 256)
      qkvb[i] = i < 512 ? wq_b[i] : i < 1024 ? wk_b[i - 512] : wv_b[i - 1024];
  } else {  // dist f32->bf16
    int i = (bid - 4097) * 256 + threadIdx.x;
    float4 a = ((const float4*)dist)[i * 2];
    float4 b4 = ((const float4*)dist)[i * 2 + 1];
    bf16x8 p;
    p[0] = (__bf16)a.x; p[1] = (__bf16)a.y; p[2] = (__bf16)a.z; p[3] = (__bf16)a.w;
    p[4] = (__bf16)b4.x; p[5] = (__bf16)b4.y; p[6] = (__bf16)b4.z; p[7] = (__bf16)b4.w;
    ((bf16x8*)distb)[i] = p;
  }
}

// async global->LDS, 16B per lane; lds dest = wave-uniform base + lane*16 (HW)
__device__ __forceinline__ void gl_lds16(const void* g, void* l) {
  __builtin_amdgcn_global_load_lds(
      (const __attribute__((address_space(1))) unsigned int*)(size_t)g,
      (__attribute__((address_space(3))) unsigned int*)(size_t)l, 16, 0, 0);
}

// ---------------- m97-style GEMM + T1 XCD swizzle.
// C = op(A(bf16,[M][K]) @ Bt(bf16,[N][K])^T); BMxBN tile, BK=64, 4 waves (2x2).
template <int BM, int BN>
__global__ __launch_bounds__(256) void gemm128(
    const __bf16* __restrict__ A, const __bf16* __restrict__ Bt,
    const float* __restrict__ bias, const float* __restrict__ resid,
    const __bf16* __restrict__ residb,
    float* __restrict__ Cf, __bf16* __restrict__ Cb,
    int M, int N, int K, int relu) {
  constexpr int MI = BM / 32, NI = BN / 32;
  __shared__ __attribute__((aligned(16))) __bf16 Asl[BM * 64];
  __shared__ __attribute__((aligned(16))) __bf16 Bsl[BN * 64];
  const int tid = threadIdx.x, w = tid >> 6, lane = tid & 63;
  const int c = lane & 15, g = lane >> 4;
  // T1 bijective XCD swizzle (nwg % 8 == 0 for all our grids): each XCD gets
  // a contiguous y-band -> A-panels fetched once per chip, B L2-resident.
  const int nwg = gridDim.x * gridDim.y;
  const int orig = blockIdx.y * gridDim.x + blockIdx.x;
  const int swz = (orig & 7) * (nwg >> 3) + (orig >> 3);
  const int m0 = (swz / gridDim.x) * BM, n0 = (swz % gridDim.x) * BN;
  const int wr = w >> 1, wc = w & 1;
  f32x4 acc[MI][NI] = {};
  const __bf16* Ab = A + (size_t)m0 * K;
  const __bf16* Bb = Bt + (size_t)n0 * K;

  for (int k0 = 0; k0 < K; k0 += 64) {
#pragma unroll
    for (int s = 0; s < BM / 32; s++) {  // A: BM x 64 x 2B, 4KB/issue
      int L = (s * 256 + tid) * 16;
      int row = L >> 7;
      int lslot = ((L >> 4) & 7) ^ (row & 7);
      gl_lds16(Ab + (size_t)row * K + k0 + lslot * 8,
               (char*)Asl + s * 4096 + w * 1024);
    }
#pragma unroll
    for (int s = 0; s < BN / 32; s++) {
      int L = (s * 256 + tid) * 16;
      int row = L >> 7;
      int lslot = ((L >> 4) & 7) ^ (row & 7);
      gl_lds16(Bb + (size_t)row * K + k0 + lslot * 8,
               (char*)Bsl + s * 4096 + w * 1024);
    }
    __syncthreads();

    bf16x8 af[MI][2], bfr[NI][2];
#pragma unroll
    for (int mi = 0; mi < MI; mi++)
#pragma unroll
      for (int ko = 0; ko < 2; ko++) {
        int row = wr * (BM / 2) + mi * 16 + c;
        int ps = (ko * 4 + g) ^ (row & 7);
        af[mi][ko] = *(const bf16x8*)&Asl[row * 64 + ps * 8];
      }
#pragma unroll
    for (int ni = 0; ni < NI; ni++)
#pragma unroll
      for (int ko = 0; ko < 2; ko++) {
        int row = wc * (BN / 2) + ni * 16 + c;
        int ps = (ko * 4 + g) ^ (row & 7);
        bfr[ni][ko] = *(const bf16x8*)&Bsl[row * 64 + ps * 8];
      }
#pragma unroll
    for (int mi = 0; mi < MI; mi++)
#pragma unroll
      for (int ni = 0; ni < NI; ni++) {
        acc[mi][ni] = __builtin_amdgcn_mfma_f32_16x16x32_bf16(af[mi][0], bfr[ni][0], acc[mi][ni], 0, 0, 0);
        acc[mi][ni] = __builtin_amdgcn_mfma_f32_16x16x32_bf16(af[mi][1], bfr[ni][1], acc[mi][ni], 0, 0, 0);
      }
    __syncthreads();
  }

#pragma unroll
  for (int mi = 0; mi < MI; mi++)
#pragma unroll
    for (int ni = 0; ni < NI; ni++)
#pragma unroll
      for (int r = 0; r < 4; r++) {
        int row = m0 + wr * (BM / 2) + mi * 16 + g * 4 + r;
        int col = n0 + wc * (BN / 2) + ni * 16 + c;
        float v = acc[mi][ni][r] + bias[col];
        if (resid) v += resid[(size_t)row * N + col];
        if (residb) v += (float)residb[(size_t)row * N + col];
        if (relu) v = fmaxf(v, 0.f);
        if (Cf) Cf[(size_t)row * N + col] = v;
        if (Cb) Cb[(size_t)row * N + col] = (__bf16)v;
      }
}

// read 16 f32, convert, store as two bf16x8 (dst 16B-aligned)
__device__ inline void cvt16(const float* __restrict__ src, __bf16* dst) {
  float4 f0 = *(const float4*)(src);
  float4 f1 = *(const float4*)(src + 4);
  float4 f2 = *(const float4*)(src + 8);
  float4 f3 = *(const float4*)(src + 12);
  bf16x8 p0, p1;
  p0[0]=(__bf16)f0.x; p0[1]=(__bf16)f0.y; p0[2]=(__bf16)f0.z; p0[3]=(__bf16)f0.w;
  p0[4]=(__bf16)f1.x; p0[5]=(__bf16)f1.y; p0[6]=(__bf16)f1.z; p0[7]=(__bf16)f1.w;
  p1[0]=(__bf16)f2.x; p1[1]=(__bf16)f2.y; p1[2]=(__bf16)f2.z; p1[3]=(__bf16)f2.w;
  p1[4]=(__bf16)f3.x; p1[5]=(__bf16)f3.y; p1[6]=(__bf16)f3.z; p1[7]=(__bf16)f3.w;
  *(bf16x8*)(dst) = p0;
  *(bf16x8*)(dst + 8) = p1;
}

// ---------------- kernel 1: QZ'[bh][i][tau] = (q_i . pe)[clip(tau - dti,-64,64)+64]
__global__ __launch_bounds__(256) void qz_shift(
    const __bf16* __restrict__ qb, const float* __restrict__ pos_emb,
    const int* __restrict__ dtimes, __bf16* __restrict__ QZg) {
  __shared__ __attribute__((aligned(16))) __bf16 peL[144][72];
  __shared__ __attribute__((aligned(16))) __bf16 QL[64][72];
  __shared__ __attribute__((aligned(16))) float qzf[64][144];
  const int tid = threadIdx.x, w = tid >> 6, l = tid & 63, c = l & 15, g = l >> 4;
  const int bid = blockIdx.x, qt = bid & 7, bh = bid >> 3, h = bh & 7, b = bh >> 3;
  const int qbase = qt * 64;
  const int r = tid >> 2, d0 = (tid & 3) * 16;

  for (int s = 0; s < 3; s++) {
    int rr = r + s * 64;
    if (rr >= 144) break;
    if (rr < 129) {
      cvt16(pos_emb + rr * 64 + d0, &peL[rr][d0]);
    } else {
      bf16x8 z = {};
      *(bf16x8*)&peL[rr][d0] = z;
      *(bf16x8*)&peL[rr][d0 + 8] = z;
    }
  }
  {
    const __bf16* qp = qb + ((size_t)(b * SEQ + qbase + r)) * QKVS + h * HDIM + d0;
    *(bf16x8*)&QL[r][d0] = *(const bf16x8*)qp;
    *(bf16x8*)&QL[r][d0 + 8] = *(const bf16x8*)(qp + 8);
  }
  __syncthreads();

  bf16x8 aq0 = *(bf16x8*)&QL[w * 16 + c][g * 8];
  bf16x8 aq1 = *(bf16x8*)&QL[w * 16 + c][32 + g * 8];
  for (int n = 0; n < 9; n++) {
    f32x4 acc = {};
    bf16x8 b0 = *(bf16x8*)&peL[n * 16 + c][g * 8];
    bf16x8 b1 = *(bf16x8*)&peL[n * 16 + c][32 + g * 8];
    acc = __builtin_amdgcn_mfma_f32_16x16x32_bf16(aq0, b0, acc, 0, 0, 0);
    acc = __builtin_amdgcn_mfma_f32_16x16x32_bf16(aq1, b1, acc, 0, 0, 0);
    int t = n * 16 + c;
    for (int r4 = 0; r4 < 4; r4++) qzf[w * 16 + g * 4 + r4][t] = acc[r4];
  }
  __syncthreads();

  int dti = dtimes[b * SEQ + qbase + r];
  int t0 = (tid & 3) * 32;
  for (int q4 = 0; q4 < 4; q4++) {
    bf16x8 o;
    for (int e = 0; e < 8; e++) {
      int tau = t0 + q4 * 8 + e;
      int t = min(max(tau - dti, -64), 64) + 64;
      o[e] = (__bf16)qzf[r][t];
    }
    *(bf16x8*)(QZg + ((size_t)(bh * SEQ + qbase + r)) * 128 + t0 + q4 * 8) = o;
  }
}

// ---------------- kernel 2: fused attention; K via global_load_lds (XOR swizzle)
#define KL_OFF 18432
__global__ __launch_bounds__(256) void attn_fused(
    const __bf16* __restrict__ qb, const __bf16* __restrict__ kb,
    const __bf16* __restrict__ vb, const __bf16* __restrict__ distb,
    const int* __restrict__ dtimes, const int* __restrict__ maskp,
    const __bf16* __restrict__ QZg, const float* __restrict__ pos_emb,
    __bf16* __restrict__ outb) {
  __shared__ __attribute__((aligned(16))) char smem[75776];
  auto QL  = (__bf16(*)[72])(smem);            //  9216 B
  auto PL  = (__bf16(*)[72])(smem + 9216);     //  9216
  char* KLb = smem + KL_OFF;                   //  8192  linear [64][64] swizzled
  auto VT  = (__bf16(*)[72])(smem + 26624);    //  9216  VT[d][j]
  auto B1h = (__bf16(*)[72])(smem + 35840);    // 18432  one-hot[tau][j]
  auto qzL = (__bf16(*)[136])(smem + 54272);   // 17408
  int* dtsL = (int*)(smem + 71680);            //  2048
  int* mskL = (int*)(smem + 73728);            //  2048
  // epilogue aliases (over dead QL/PL/KL/VT/B1h):
  auto CLs = (float(*)[136])(smem);            // 34816
  auto peT = (__bf16(*)[136])(smem + 34816);   // 17408 -> ends 52224 < 54272

  const int tid = threadIdx.x, w = tid >> 6, l = tid & 63, c = l & 15, g = l >> 4;
  const int bid = blockIdx.x;
  const int qt = bid & 7, h = (bid >> 3) & 7, b = bid >> 6, bh = bid >> 3;
  const int qbase = qt * 64;
  const int r = tid >> 2, d0 = (tid & 3) * 16;
  const int vd = l, vj0 = w * 16;  // V-transpose: lane owns d-row

  auto stageK = [&](int jt) {
#pragma unroll
    for (int s = 0; s < 2; s++) {
      int L = (s * 256 + tid) * 16;
      int row = L >> 7;
      int sl = ((L >> 4) & 7) ^ (row & 7);
      gl_lds16(kb + ((size_t)(b * SEQ + jt * 64 + row)) * QKVS + h * HDIM + sl * 8,
               KLb + s * 4096 + w * 1024);
    }
  };
  __bf16 vreg[16];
  float dA[16], dB[16];
  auto loadV = [&](int jt) {
    const __bf16* vp = vb + ((size_t)(b * SEQ + jt * 64 + vj0)) * QKVS + h * HDIM + vd;
#pragma unroll
    for (int q = 0; q < 16; q++) vreg[q] = vp[(size_t)q * QKVS];
  };
  auto loadD = [&](int jt, float (&dd)[16]) {
#pragma unroll
    for (int n = 0; n < 4; n++)
#pragma unroll
      for (int r4 = 0; r4 < 4; r4++) {
        int il = w * 16 + g * 4 + r4;
        dd[n * 4 + r4] =
            (float)distb[((size_t)(b * SEQ + qbase + il)) * SEQ + jt * 64 + n * 16 + c];
      }
  };

  stageK(0); loadV(0); loadD(0, dA);

  {
    const __bf16* qp = qb + ((size_t)(b * SEQ + qbase + r)) * QKVS + h * HDIM + d0;
    *(bf16x8*)&QL[r][d0] = *(const bf16x8*)qp;
    *(bf16x8*)&QL[r][d0 + 8] = *(const bf16x8*)(qp + 8);
  }
  {
    int ch = (tid & 3) * 32;
    const __bf16* src = QZg + ((size_t)(bh * SEQ + qbase + r)) * 128 + ch;
    for (int q4 = 0; q4 < 4; q4++)
      *(bf16x8*)&qzL[r][ch + q4 * 8] = *(const bf16x8*)(src + q4 * 8);
  }
  for (int idx = tid; idx < SEQ; idx += 256) {
    dtsL[idx] = dtimes[b * SEQ + idx];
    mskL[idx] = maskp[b * SEQ + idx];
  }
  {
    bf16x8 z = {};
    for (int idx = tid; idx < 128 * 9; idx += 256)
      *(bf16x8*)&B1h[idx / 9][(idx % 9) * 8] = z;
  }
  __syncthreads();

  bf16x8 aq0 = *(bf16x8*)&QL[w * 16 + c][g * 8];
  bf16x8 aq1 = *(bf16x8*)&QL[w * 16 + c][32 + g * 8];
  float lsum[4] = {0.f, 0.f, 0.f, 0.f};
  f32x4 Oacc[4] = {};
  f32x4 Cacc[8] = {};

  auto body = [&](int jt, float (&dcur)[16], float (&dnxt)[16]) {
    __syncthreads();  // (A) prev-tile LDS reads drained; K DMA landed
    {
      bf16x8 pv0, pv1;
#pragma unroll
      for (int q = 0; q < 8; q++) { pv0[q] = vreg[q]; pv1[q] = vreg[q + 8]; }
      *(bf16x8*)&VT[vd][vj0] = pv0;
      *(bf16x8*)&VT[vd][vj0 + 8] = pv1;
    }
    if (tid < 64) {
      if (jt > 0) {
        int tp = dtsL[(jt - 1) * 64 + tid], tn = dtsL[jt * 64 + tid];
        if (tp != tn) B1h[tp][tid] = (__bf16)0.f;
        B1h[tn][tid] = (__bf16)1.f;
      } else {
        B1h[dtsL[tid]][tid] = (__bf16)1.f;
      }
    }
    if (jt < 7) { loadV(jt + 1); loadD(jt + 1, dnxt); }
    __syncthreads();  // (B)

#pragma unroll
    for (int n = 0; n < 4; n++) {
      f32x4 acc = {};
      int row = n * 16 + c;
      bf16x8 bk0 = *(const bf16x8*)(KLb + row * 128 + ((g ^ (row & 7)) * 16));
      bf16x8 bk1 = *(const bf16x8*)(KLb + row * 128 + (((g + 4) ^ (row & 7)) * 16));
      acc = __builtin_amdgcn_mfma_f32_16x16x32_bf16(aq0, bk0, acc, 0, 0, 0);
      acc = __builtin_amdgcn_mfma_f32_16x16x32_bf16(aq1, bk1, acc, 0, 0, 0);
      int jl = n * 16 + c, jg = jt * 64 + jl;
      int dtj = dtsL[jg];
      int mk = mskL[jg];
#pragma unroll
      for (int r4 = 0; r4 < 4; r4++) {
        int il = w * 16 + g * 4 + r4;
        float s = (acc[r4] + (float)qzL[il][dtj]) * 0.125f + 0.6f * dcur[n * 4 + r4];
        float p = mk ? __expf(s) : 0.f;
        lsum[r4] += p;
        PL[il][jl] = (__bf16)p;
      }
    }
    __syncthreads();  // (C)
    if (jt < 7) stageK(jt + 1);  // K DMA overlaps PV phase

    bf16x8 ap0 = *(bf16x8*)&PL[w * 16 + c][g * 8];
    bf16x8 ap1 = *(bf16x8*)&PL[w * 16 + c][32 + g * 8];
#pragma unroll
    for (int dn = 0; dn < 4; dn++) {
      bf16x8 bv0 = *(bf16x8*)&VT[dn * 16 + c][g * 8];
      bf16x8 bv1 = *(bf16x8*)&VT[dn * 16 + c][32 + g * 8];
      Oacc[dn] = __builtin_amdgcn_mfma_f32_16x16x32_bf16(ap0, bv0, Oacc[dn], 0, 0, 0);
      Oacc[dn] = __builtin_amdgcn_mfma_f32_16x16x32_bf16(ap1, bv1, Oacc[dn], 0, 0, 0);
    }
#pragma unroll
    for (int tn = 0; tn < 8; tn++) {
      bf16x8 bz0 = *(bf16x8*)&B1h[tn * 16 + c][g * 8];
      bf16x8 bz1 = *(bf16x8*)&B1h[tn * 16 + c][32 + g * 8];
      Cacc[tn] = __builtin_amdgcn_mfma_f32_16x16x32_bf16(ap0, bz0, Cacc[tn], 0, 0, 0);
      Cacc[tn] = __builtin_amdgcn_mfma_f32_16x16x32_bf16(ap1, bz1, Cacc[tn], 0, 0, 0);
    }
  };
  for (int jt2 = 0; jt2 < 8; jt2 += 2) {
    body(jt2, dA, dB);
    body(jt2 + 1, dB, dA);
  }

  // ======== fused zcombine epilogue ========
  __syncthreads();
  {
    float4 z4 = {0.f, 0.f, 0.f, 0.f};
    for (int idx = tid; idx < 64 * 34; idx += 256) ((float4*)CLs)[idx] = z4;
  }
  for (int s = 0; s < 3; s++) {
    int t = r + s * 64;
    if (t < 129) {
      float vals[16];
      *(float4*)&vals[0]  = *(const float4*)(pos_emb + t * 64 + d0);
      *(float4*)&vals[4]  = *(const float4*)(pos_emb + t * 64 + d0 + 4);
      *(float4*)&vals[8]  = *(const float4*)(pos_emb + t * 64 + d0 + 8);
      *(float4*)&vals[12] = *(const float4*)(pos_emb + t * 64 + d0 + 12);
#pragma unroll
      for (int q = 0; q < 16; q++) peT[d0 + q][t] = (__bf16)vals[q];
    }
  }
  __syncthreads();

  {
    int dti_r4[4];
#pragma unroll
    for (int r4 = 0; r4 < 4; r4++) dti_r4[r4] = dtsL[qbase + w * 16 + g * 4 + r4];
#pragma unroll
    for (int tn = 0; tn < 8; tn++)
#pragma unroll
      for (int r4 = 0; r4 < 4; r4++) {
        int il = w * 16 + g * 4 + r4;
        int tau = tn * 16 + c, d = tau - dti_r4[r4];
        float val = Cacc[tn][r4];
        if (d <= -64) atomicAdd(&CLs[il][0], val);
        else if (d >= 64) atomicAdd(&CLs[il][128], val);
        else CLs[il][d + 64] = val;
      }
  }
  __syncthreads();

  float linv[4];
#pragma unroll
  for (int r4 = 0; r4 < 4; r4++) {
    float s = lsum[r4];
    for (int off = 1; off < 16; off <<= 1) s += __shfl_xor(s, off);
    linv[r4] = 1.0f / s;
  }

  f32x4 acc2[4] = {};
#pragma unroll
  for (int ks = 0; ks < 4; ks++) {
    const float* ap = &CLs[w * 16 + c][ks * 32 + g * 8];
    float4 a0 = *(const float4*)ap, a1 = *(const float4*)(ap + 4);
    bf16x8 af;
    af[0]=(__bf16)a0.x; af[1]=(__bf16)a0.y; af[2]=(__bf16)a0.z; af[3]=(__bf16)a0.w;
    af[4]=(__bf16)a1.x; af[5]=(__bf16)a1.y; af[6]=(__bf16)a1.z; af[7]=(__bf16)a1.w;
#pragma unroll
    for (int dn = 0; dn < 4; dn++) {
      bf16x8 bf = *(bf16x8*)&peT[dn * 16 + c][ks * 32 + g * 8];
      acc2[dn] = __builtin_amdgcn_mfma_f32_16x16x32_bf16(af, bf, acc2[dn], 0, 0, 0);
    }
  }
#pragma unroll
  for (int r4 = 0; r4 < 4; r4++) {
    int il = w * 16 + g * 4 + r4;
    float c128 = CLs[il][128];
#pragma unroll
    for (int dn = 0; dn < 4; dn++) {
      int d = dn * 16 + c;
      float y = acc2[dn][r4] + c128 * (float)peT[d][128];
      outb[((size_t)(b * SEQ + qbase + il)) * EDIM + h * HDIM + d] =
          (__bf16)((Oacc[dn][r4] + y) * linv[r4]);
    }
  }
}

// ---------------- layernorm over rows of 512; 4 rows/block; f32 and/or bf16 out
__global__ __launch_bounds__(256) void ln_kernel(
    const float* __restrict__ in, const float* __restrict__ g,
    const float* __restrict__ bta, float* __restrict__ out,
    __bf16* __restrict__ outb) {
  int row = blockIdx.x * 4 + (threadIdx.x >> 6), lane = threadIdx.x & 63;
  const float* p = in + (size_t)row * EDIM;
  float4 v0 = *(const float4*)(p + lane * 8);
  float4 v1 = *(const float4*)(p + lane * 8 + 4);
  float vals[8] = {v0.x, v0.y, v0.z, v0.w, v1.x, v1.y, v1.z, v1.w};
  float s = 0.f;
  for (int j = 0; j < 8; j++) s += vals[j];
  for (int o = 32; o; o >>= 1) s += __shfl_xor(s, o);
  float mu = s * (1.0f / EDIM);
  float vs = 0.f;
  for (int j = 0; j < 8; j++) {
    vals[j] -= mu;
    vs += vals[j] * vals[j];
  }
  for (int o = 32; o; o >>= 1) vs += __shfl_xor(vs, o);
  float rs = rsqrtf(vs * (1.0f / EDIM) + 1e-5f);
  for (int j = 0; j < 8; j++) {
    int col = lane * 8 + j;
    float v = vals[j] * rs * g[col] + bta[col];
    if (out) out[(size_t)row * EDIM + col] = v;
    if (outb) outb[(size_t)row * EDIM + col] = (__bf16)v;
  }
}

extern "C" void kernel_launch(void* const* d_in, const int* in_sizes, int n_in,
                              void* d_out, int out_size, void* d_ws, size_t ws_size,
                              hipStream_t stream) {
  const float* x = (const float*)d_in[0];
  const float* dist = (const float*)d_in[1];
  const int* dtimes = (const int*)d_in[2];
  const int* maskp = (const int*)d_in[3];
  const float* wq_w = (const float*)d_in[4];
  const float* wq_b = (const float*)d_in[5];
  const float* wk_w = (const float*)d_in[6];
  const float* wk_b = (const float*)d_in[7];
  const float* wv_w = (const float*)d_in[8];
  const float* wv_b = (const float*)d_in[9];
  const float* wo_w = (const float*)d_in[10];
  const float* wo_b = (const float*)d_in[11];
  const float* pos_emb = (const float*)d_in[12];
  const float* w1 = (const float*)d_in[13];
  const float* b1 = (const float*)d_in[14];
  const float* w2 = (const float*)d_in[15];
  const float* b2 = (const float*)d_in[16];
  const float* ln1_g = (const float*)d_in[17];
  const float* ln1_b = (const float*)d_in[18];
  const float* ln2_g = (const float*)d_in[19];
  const float* ln2_b = (const float*)d_in[20];
  float* out = (float*)d_out;

  const int M = TOKENS;
  const size_t T = TOKENS;
  float* fws = (float*)d_ws;

  // ---- workspace layout (f32 units), lifetime-aliased
  __bf16* qkvB   = (__bf16*)fws;                      // T*1536 bf16 = T*768 f32
  float*  ln2in  = fws;                               // alias (after attn)
  float*  wo_out = fws + T * 768;
  __bf16* QZg    = (__bf16*)(fws + T * 1792);         // T*1024 bf16
  __bf16* attnob = (__bf16*)(fws + T * 2304);
  __bf16* hid    = (__bf16*)(fws + T * 2560);         // T*2048 bf16
  __bf16* attnb  = (__bf16*)(fws + T * 3584);
  __bf16* xb     = (__bf16*)(fws + T * 3840);
  __bf16* wqkvt  = (__bf16*)(fws + T * 4096);         // 786432 bf16
  __bf16* wot    = wqkvt + 1536 * 512;
  __bf16* w1t    = wot + 512 * 512;
  __bf16* w2t    = w1t + 512 * 2048;
  __bf16* distb  = w2t + 2048 * 512;                  // 2097152 bf16
  float*  qkvb   = (float*)(distb + 2097152);         // 1536 f32

  // ---- prep
  prep<<<5121, 256, 0, stream>>>(wq_w, wk_w, wv_w, wo_w, w1, w2, x, dist,
                                 wq_b, wk_b, wv_b,
                                 wqkvt, wot, w1t, w2t, xb, distb, qkvb);

  // ---- fused QKV projection (bf16 out): [4096x512] @ [512x1536]
  gemm128<64, 128><<<dim3(1536 / 128, M / 64), 256, 0, stream>>>(
      xb, wqkvt, qkvb, nullptr, nullptr, nullptr, qkvB, M, 1536, 512, 0);

  // ---- attention
  qz_shift<<<512, 256, 0, stream>>>(qkvB, pos_emb, dtimes, QZg);
  attn_fused<<<512, 256, 0, stream>>>(qkvB, qkvB + 512, qkvB + 1024, distb,
                                      dtimes, maskp, QZg, pos_emb, attnb);

  // ---- output projection + residual, LN1 (bf16 out only)
  gemm128<64, 64><<<dim3(512 / 64, M / 64), 256, 0, stream>>>(
      attnb, wot, wo_b, x, nullptr, wo_out, nullptr, M, 512, 512, 0);
  ln_kernel<<<M / 4, 256, 0, stream>>>(wo_out, ln1_g, ln1_b, nullptr, attnob);

  // ---- FFN (w2 residual reads bf16 attnob)
  gemm128<64, 128><<<dim3(2048 / 128, M / 64), 256, 0, stream>>>(
      attnob, w1t, b1, nullptr, nullptr, nullptr, hid, M, 2048, 512, 1);
  gemm128<64, 64><<<dim3(512 / 64, M / 64), 256, 0, stream>>>(
      hid, w2t, b2, nullptr, attnob, ln2in, nullptr, M, 512, 2048, 0);
  ln_kernel<<<M / 4, 256, 0, stream>>>(ln2in, ln2_g, ln2_b, out, nullptr);
}

// Round 10
// 245.606 us; speedup vs baseline: 4.3260x; 1.0166x over previous
//
#include <hip/hip_runtime.h>
#include <hip/hip_bf16.h>

typedef __bf16 bf16x8 __attribute__((ext_vector_type(8)));
typedef float f32x4 __attribute__((ext_vector_type(4)));

#define TOKENS 4096
#define EDIM 512
#define FDIM 2048
#define SEQ 512
#define NHEAD 8
#define HDIM 64
#define QKVS 1536

// ---------------- prep: weight transposes (f32->bf16), bias concat, x/dist->bf16
__global__ __launch_bounds__(256) void prep(
    const float* __restrict__ wq_w, const float* __restrict__ wk_w,
    const float* __restrict__ wv_w, const float* __restrict__ wo_w,
    const float* __restrict__ w1, const float* __restrict__ w2,
    const float* __restrict__ x, const float* __restrict__ dist,
    const float* __restrict__ wq_b, const float* __restrict__ wk_b,
    const float* __restrict__ wv_b,
    __bf16* __restrict__ wqkvt, __bf16* __restrict__ wot,
    __bf16* __restrict__ w1t, __bf16* __restrict__ w2t,
    __bf16* __restrict__ xb, __bf16* __restrict__ distb,
    float* __restrict__ qkvb) {
  __shared__ float t[32][33];
  int bid = blockIdx.x;
  if (bid < 3072) {  // transposes
    const float* src;
    __bf16* dst;
    int R = 512, C = 512, bx, by;
    if (bid < 1024) {
      int seg = bid >> 8, local = bid & 255;
      src = seg == 0 ? wq_w : seg == 1 ? wk_w : seg == 2 ? wv_w : wo_w;
      dst = seg == 0 ? wqkvt : seg == 1 ? wqkvt + 262144 : seg == 2 ? wqkvt + 524288 : wot;
      bx = local & 15; by = local >> 4;
    } else if (bid < 2048) {
      int local = bid - 1024; src = w1; dst = w1t; C = 2048;
      bx = local & 63; by = local >> 6;
    } else {
      int local = bid - 2048; src = w2; dst = w2t; R = 2048;
      bx = local & 15; by = local >> 4;
    }
    int c0 = bx * 32, r0 = by * 32;
    int tx = threadIdx.x & 31, ty = threadIdx.x >> 5;
    for (int rr = ty; rr < 32; rr += 8)
      t[rr][tx] = src[(size_t)(r0 + rr) * C + c0 + tx];
    __syncthreads();
    for (int rr = ty; rr < 32; rr += 8)
      dst[(size_t)(c0 + rr) * R + r0 + tx] = (__bf16)t[tx][rr];
  } else if (bid < 4096) {  // x f32->bf16
    int i = (bid - 3072) * 256 + threadIdx.x;
    float4 a = ((const float4*)x)[i * 2];
    float4 b4 = ((const float4*)x)[i * 2 + 1];
    bf16x8 p;
    p[0] = (__bf16)a.x; p[1] = (__bf16)a.y; p[2] = (__bf16)a.z; p[3] = (__bf16)a.w;
    p[4] = (__bf16)b4.x; p[5] = (__bf16)b4.y; p[6] = (__bf16)b4.z; p[7] = (__bf16)b4.w;
    ((bf16x8*)xb)[i] = p;
  } else if (bid == 4096) {  // bias concat
    for (int i = threadIdx.x; i < 1536; i += 256)
      qkvb[i] = i < 512 ? wq_b[i] : i < 1024 ? wk_b[i - 512] : wv_b[i - 1024];
  } else {  // dist f32->bf16
    int i = (bid - 4097) * 256 + threadIdx.x;
    float4 a = ((const float4*)dist)[i * 2];
    float4 b4 = ((const float4*)dist)[i * 2 + 1];
    bf16x8 p;
    p[0] = (__bf16)a.x; p[1] = (__bf16)a.y; p[2] = (__bf16)a.z; p[3] = (__bf16)a.w;
    p[4] = (__bf16)b4.x; p[5] = (__bf16)b4.y; p[6] = (__bf16)b4.z; p[7] = (__bf16)b4.w;
    ((bf16x8*)distb)[i] = p;
  }
}

// async global->LDS, 16B per lane; lds dest = wave-uniform base + lane*16 (HW)
__device__ __forceinline__ void gl_lds16(const void* g, void* l) {
  __builtin_amdgcn_global_load_lds(
      (const __attribute__((address_space(1))) unsigned int*)(size_t)g,
      (__attribute__((address_space(3))) unsigned int*)(size_t)l, 16, 0, 0);
}

// ---------------- m97-style GEMM + T1 XCD swizzle (unchanged from round 8)
template <int BM, int BN>
__global__ __launch_bounds__(256) void gemm128(
    const __bf16* __restrict__ A, const __bf16* __restrict__ Bt,
    const float* __restrict__ bias, const float* __restrict__ resid,
    const __bf16* __restrict__ residb,
    float* __restrict__ Cf, __bf16* __restrict__ Cb,
    int M, int N, int K, int relu) {
  constexpr int MI = BM / 32, NI = BN / 32;
  __shared__ __attribute__((aligned(16))) __bf16 Asl[BM * 64];
  __shared__ __attribute__((aligned(16))) __bf16 Bsl[BN * 64];
  const int tid = threadIdx.x, w = tid >> 6, lane = tid & 63;
  const int c = lane & 15, g = lane >> 4;
  const int nwg = gridDim.x * gridDim.y;
  const int orig = blockIdx.y * gridDim.x + blockIdx.x;
  const int swz = (orig & 7) * (nwg >> 3) + (orig >> 3);
  const int m0 = (swz / gridDim.x) * BM, n0 = (swz % gridDim.x) * BN;
  const int wr = w >> 1, wc = w & 1;
  f32x4 acc[MI][NI] = {};
  const __bf16* Ab = A + (size_t)m0 * K;
  const __bf16* Bb = Bt + (size_t)n0 * K;

  for (int k0 = 0; k0 < K; k0 += 64) {
#pragma unroll
    for (int s = 0; s < BM / 32; s++) {
      int L = (s * 256 + tid) * 16;
      int row = L >> 7;
      int lslot = ((L >> 4) & 7) ^ (row & 7);
      gl_lds16(Ab + (size_t)row * K + k0 + lslot * 8,
               (char*)Asl + s * 4096 + w * 1024);
    }
#pragma unroll
    for (int s = 0; s < BN / 32; s++) {
      int L = (s * 256 + tid) * 16;
      int row = L >> 7;
      int lslot = ((L >> 4) & 7) ^ (row & 7);
      gl_lds16(Bb + (size_t)row * K + k0 + lslot * 8,
               (char*)Bsl + s * 4096 + w * 1024);
    }
    __syncthreads();

    bf16x8 af[MI][2], bfr[NI][2];
#pragma unroll
    for (int mi = 0; mi < MI; mi++)
#pragma unroll
      for (int ko = 0; ko < 2; ko++) {
        int row = wr * (BM / 2) + mi * 16 + c;
        int ps = (ko * 4 + g) ^ (row & 7);
        af[mi][ko] = *(const bf16x8*)&Asl[row * 64 + ps * 8];
      }
#pragma unroll
    for (int ni = 0; ni < NI; ni++)
#pragma unroll
      for (int ko = 0; ko < 2; ko++) {
        int row = wc * (BN / 2) + ni * 16 + c;
        int ps = (ko * 4 + g) ^ (row & 7);
        bfr[ni][ko] = *(const bf16x8*)&Bsl[row * 64 + ps * 8];
      }
#pragma unroll
    for (int mi = 0; mi < MI; mi++)
#pragma unroll
      for (int ni = 0; ni < NI; ni++) {
        acc[mi][ni] = __builtin_amdgcn_mfma_f32_16x16x32_bf16(af[mi][0], bfr[ni][0], acc[mi][ni], 0, 0, 0);
        acc[mi][ni] = __builtin_amdgcn_mfma_f32_16x16x32_bf16(af[mi][1], bfr[ni][1], acc[mi][ni], 0, 0, 0);
      }
    __syncthreads();
  }

#pragma unroll
  for (int mi = 0; mi < MI; mi++)
#pragma unroll
    for (int ni = 0; ni < NI; ni++)
#pragma unroll
      for (int r = 0; r < 4; r++) {
        int row = m0 + wr * (BM / 2) + mi * 16 + g * 4 + r;
        int col = n0 + wc * (BN / 2) + ni * 16 + c;
        float v = acc[mi][ni][r] + bias[col];
        if (resid) v += resid[(size_t)row * N + col];
        if (residb) v += (float)residb[(size_t)row * N + col];
        if (relu) v = fmaxf(v, 0.f);
        if (Cf) Cf[(size_t)row * N + col] = v;
        if (Cb) Cb[(size_t)row * N + col] = (__bf16)v;
      }
}

// read 16 f32, convert, store as two bf16x8 (dst 16B-aligned)
__device__ inline void cvt16(const float* __restrict__ src, __bf16* dst) {
  float4 f0 = *(const float4*)(src);
  float4 f1 = *(const float4*)(src + 4);
  float4 f2 = *(const float4*)(src + 8);
  float4 f3 = *(const float4*)(src + 12);
  bf16x8 p0, p1;
  p0[0]=(__bf16)f0.x; p0[1]=(__bf16)f0.y; p0[2]=(__bf16)f0.z; p0[3]=(__bf16)f0.w;
  p0[4]=(__bf16)f1.x; p0[5]=(__bf16)f1.y; p0[6]=(__bf16)f1.z; p0[7]=(__bf16)f1.w;
  p1[0]=(__bf16)f2.x; p1[1]=(__bf16)f2.y; p1[2]=(__bf16)f2.z; p1[3]=(__bf16)f2.w;
  p1[4]=(__bf16)f3.x; p1[5]=(__bf16)f3.y; p1[6]=(__bf16)f3.z; p1[7]=(__bf16)f3.w;
  *(bf16x8*)(dst) = p0;
  *(bf16x8*)(dst + 8) = p1;
}

// ---------------- fused attention: qz prologue + main + zcombine epilogue.
// Block decode b = bid & 7 -> all blocks of batch b on XCD b (dist/K/V L2-resident).
#define KL_OFF 18432
__global__ __launch_bounds__(256) void attn_fused(
    const __bf16* __restrict__ qb, const __bf16* __restrict__ kb,
    const __bf16* __restrict__ vb, const __bf16* __restrict__ distb,
    const int* __restrict__ dtimes, const int* __restrict__ maskp,
    const float* __restrict__ pos_emb, __bf16* __restrict__ outb) {
  __shared__ __attribute__((aligned(16))) char smem[75776];
  auto QL  = (__bf16(*)[72])(smem);            //  9216 B
  auto PL  = (__bf16(*)[72])(smem + 9216);     //  9216
  char* KLb = smem + KL_OFF;                   //  8192  linear [64][64] swizzled
  auto VT  = (__bf16(*)[72])(smem + 26624);    //  9216  VT[d][j]
  auto B1h = (__bf16(*)[72])(smem + 35840);    // 18432  one-hot[tau][j]
  auto qzL = (__bf16(*)[136])(smem + 54272);   // 17408
  int* dtsL = (int*)(smem + 71680);            //  2048
  int* mskL = (int*)(smem + 73728);            //  2048
  // qz-prologue aliases (dead before main loop; see barrier ordering):
  auto peL = (__bf16(*)[72])(smem + 9216);     // 144x72 bf16 = 20736 -> ends 29952
  auto qzf = (__bf16(*)[144])(smem + 29952);   // 64x144 bf16 = 18432 -> ends 48384
  // epilogue aliases:
  auto CLs = (float(*)[136])(smem);            // 34816
  auto peT = (__bf16(*)[136])(smem + 34816);   // 17408 -> ends 52224 < 54272

  const int tid = threadIdx.x, w = tid >> 6, l = tid & 63, c = l & 15, g = l >> 4;
  const int bid = blockIdx.x;
  const int b = bid & 7, h = (bid >> 3) & 7, qt = bid >> 6;   // batch-XCD swizzle
  const int qbase = qt * 64;
  const int r = tid >> 2, d0 = (tid & 3) * 16;
  const int vd = l, vj0 = w * 16;  // V-transpose: lane owns d-row

  auto stageK = [&](int jt) {
#pragma unroll
    for (int s = 0; s < 2; s++) {
      int L = (s * 256 + tid) * 16;
      int row = L >> 7;
      int sl = ((L >> 4) & 7) ^ (row & 7);
      gl_lds16(kb + ((size_t)(b * SEQ + jt * 64 + row)) * QKVS + h * HDIM + sl * 8,
               KLb + s * 4096 + w * 1024);
    }
  };
  __bf16 vreg[16];
  float dA[16], dB[16];
  auto loadV = [&](int jt) {
    const __bf16* vp = vb + ((size_t)(b * SEQ + jt * 64 + vj0)) * QKVS + h * HDIM + vd;
#pragma unroll
    for (int q = 0; q < 16; q++) vreg[q] = vp[(size_t)q * QKVS];
  };
  auto loadD = [&](int jt, float (&dd)[16]) {
#pragma unroll
    for (int n = 0; n < 4; n++)
#pragma unroll
      for (int r4 = 0; r4 < 4; r4++) {
        int il = w * 16 + g * 4 + r4;
        dd[n * 4 + r4] =
            (float)distb[((size_t)(b * SEQ + qbase + il)) * SEQ + jt * 64 + n * 16 + c];
      }
  };

  loadV(0); loadD(0, dA);  // register prefetch (no LDS involved)

  // ---- P0: stage Q, peL, dts/msk
  {
    const __bf16* qp = qb + ((size_t)(b * SEQ + qbase + r)) * QKVS + h * HDIM + d0;
    *(bf16x8*)&QL[r][d0] = *(const bf16x8*)qp;
    *(bf16x8*)&QL[r][d0 + 8] = *(const bf16x8*)(qp + 8);
  }
  for (int s = 0; s < 3; s++) {
    int rr = r + s * 64;
    if (rr >= 144) break;
    if (rr < 129) {
      cvt16(pos_emb + rr * 64 + d0, &peL[rr][d0]);
    } else {
      bf16x8 z = {};
      *(bf16x8*)&peL[rr][d0] = z;
      *(bf16x8*)&peL[rr][d0 + 8] = z;
    }
  }
  for (int idx = tid; idx < SEQ; idx += 256) {
    dtsL[idx] = dtimes[b * SEQ + idx];
    mskL[idx] = maskp[b * SEQ + idx];
  }
  __syncthreads();  // S1

  // ---- P1: qz MFMA (Q . pos_emb for all 144 t-bins)
  bf16x8 aq0 = *(bf16x8*)&QL[w * 16 + c][g * 8];
  bf16x8 aq1 = *(bf16x8*)&QL[w * 16 + c][32 + g * 8];
#pragma unroll
  for (int n = 0; n < 9; n++) {
    f32x4 acc = {};
    bf16x8 b0 = *(bf16x8*)&peL[n * 16 + c][g * 8];
    bf16x8 b1 = *(bf16x8*)&peL[n * 16 + c][32 + g * 8];
    acc = __builtin_amdgcn_mfma_f32_16x16x32_bf16(aq0, b0, acc, 0, 0, 0);
    acc = __builtin_amdgcn_mfma_f32_16x16x32_bf16(aq1, b1, acc, 0, 0, 0);
    int t = n * 16 + c;
#pragma unroll
    for (int r4 = 0; r4 < 4; r4++) qzf[w * 16 + g * 4 + r4][t] = (__bf16)acc[r4];
  }
  __syncthreads();  // S2

  // ---- P2a: gather shifted qz values into regs (qzf dies after this)
  __bf16 qzv[32];
  {
    int dti = dtsL[qbase + r];
    int t0 = (tid & 3) * 32;
#pragma unroll
    for (int e = 0; e < 32; e++) {
      int tt = min(max(t0 + e - dti, -64), 64) + 64;
      qzv[e] = qzf[r][tt];
    }
  }
  __syncthreads();  // S3 (all qzf reads done before B1h zero overwrites region)

  // ---- P2b: write qzL, zero B1h, start K DMA
  {
    int t0 = (tid & 3) * 32;
#pragma unroll
    for (int q4 = 0; q4 < 4; q4++) {
      bf16x8 o;
#pragma unroll
      for (int e = 0; e < 8; e++) o[e] = qzv[q4 * 8 + e];
      *(bf16x8*)&qzL[r][t0 + q4 * 8] = o;
    }
  }
  {
    bf16x8 z = {};
    for (int idx = tid; idx < 128 * 9; idx += 256)
      *(bf16x8*)&B1h[idx / 9][(idx % 9) * 8] = z;
  }
  stageK(0);
  __syncthreads();  // S4

  float lsum[4] = {0.f, 0.f, 0.f, 0.f};
  f32x4 Oacc[4] = {};
  f32x4 Cacc[8] = {};
  const float SCL = 0.125f * 1.44269504f;  // fold log2(e): exp2 path
  const float DCO = 0.6f * 1.44269504f;

  auto body = [&](int jt, float (&dcur)[16], float (&dnxt)[16]) {
    __syncthreads();  // (A) prev-tile LDS reads drained; K DMA landed
    {
      bf16x8 pv0, pv1;
#pragma unroll
      for (int q = 0; q < 8; q++) { pv0[q] = vreg[q]; pv1[q] = vreg[q + 8]; }
      *(bf16x8*)&VT[vd][vj0] = pv0;
      *(bf16x8*)&VT[vd][vj0 + 8] = pv1;
    }
    if (tid < 64) {
      if (jt > 0) {
        int tp = dtsL[(jt - 1) * 64 + tid], tn = dtsL[jt * 64 + tid];
        if (tp != tn) B1h[tp][tid] = (__bf16)0.f;
        B1h[tn][tid] = (__bf16)1.f;
      } else {
        B1h[dtsL[tid]][tid] = (__bf16)1.f;
      }
    }
    if (jt < 7) { loadV(jt + 1); loadD(jt + 1, dnxt); }
    __syncthreads();  // (B)

#pragma unroll
    for (int n = 0; n < 4; n++) {
      f32x4 acc = {};
      int row = n * 16 + c;
      bf16x8 bk0 = *(const bf16x8*)(KLb + row * 128 + ((g ^ (row & 7)) * 16));
      bf16x8 bk1 = *(const bf16x8*)(KLb + row * 128 + (((g + 4) ^ (row & 7)) * 16));
      acc = __builtin_amdgcn_mfma_f32_16x16x32_bf16(aq0, bk0, acc, 0, 0, 0);
      acc = __builtin_amdgcn_mfma_f32_16x16x32_bf16(aq1, bk1, acc, 0, 0, 0);
      int jl = n * 16 + c, jg = jt * 64 + jl;
      int dtj = dtsL[jg];
      int mk = mskL[jg];
#pragma unroll
      for (int r4 = 0; r4 < 4; r4++) {
        int il = w * 16 + g * 4 + r4;
        float s = (acc[r4] + (float)qzL[il][dtj]) * SCL + DCO * dcur[n * 4 + r4];
        float p = mk ? exp2f(s) : 0.f;
        lsum[r4] += p;
        PL[il][jl] = (__bf16)p;
      }
    }
    __syncthreads();  // (C)
    if (jt < 7) stageK(jt + 1);  // K DMA overlaps PV phase

    bf16x8 ap0 = *(bf16x8*)&PL[w * 16 + c][g * 8];
    bf16x8 ap1 = *(bf16x8*)&PL[w * 16 + c][32 + g * 8];
#pragma unroll
    for (int dn = 0; dn < 4; dn++) {
      bf16x8 bv0 = *(bf16x8*)&VT[dn * 16 + c][g * 8];
      bf16x8 bv1 = *(bf16x8*)&VT[dn * 16 + c][32 + g * 8];
      Oacc[dn] = __builtin_amdgcn_mfma_f32_16x16x32_bf16(ap0, bv0, Oacc[dn], 0, 0, 0);
      Oacc[dn] = __builtin_amdgcn_mfma_f32_16x16x32_bf16(ap1, bv1, Oacc[dn], 0, 0, 0);
    }
#pragma unroll
    for (int tn = 0; tn < 8; tn++) {
      bf16x8 bz0 = *(bf16x8*)&B1h[tn * 16 + c][g * 8];
      bf16x8 bz1 = *(bf16x8*)&B1h[tn * 16 + c][32 + g * 8];
      Cacc[tn] = __builtin_amdgcn_mfma_f32_16x16x32_bf16(ap0, bz0, Cacc[tn], 0, 0, 0);
      Cacc[tn] = __builtin_amdgcn_mfma_f32_16x16x32_bf16(ap1, bz1, Cacc[tn], 0, 0, 0);
    }
  };
  for (int jt2 = 0; jt2 < 8; jt2 += 2) {
    body(jt2, dA, dB);
    body(jt2 + 1, dB, dA);
  }

  // ======== fused zcombine epilogue ========
  __syncthreads();
  {
    float4 z4 = {0.f, 0.f, 0.f, 0.f};
    for (int idx = tid; idx < 64 * 34; idx += 256) ((float4*)CLs)[idx] = z4;
  }
  for (int s = 0; s < 3; s++) {
    int t = r + s * 64;
    if (t < 129) {
      float vals[16];
      *(float4*)&vals[0]  = *(const float4*)(pos_emb + t * 64 + d0);
      *(float4*)&vals[4]  = *(const float4*)(pos_emb + t * 64 + d0 + 4);
      *(float4*)&vals[8]  = *(const float4*)(pos_emb + t * 64 + d0 + 8);
      *(float4*)&vals[12] = *(const float4*)(pos_emb + t * 64 + d0 + 12);
#pragma unroll
      for (int q = 0; q < 16; q++) peT[d0 + q][t] = (__bf16)vals[q];
    }
  }
  __syncthreads();

  {
    int dti_r4[4];
#pragma unroll
    for (int r4 = 0; r4 < 4; r4++) dti_r4[r4] = dtsL[qbase + w * 16 + g * 4 + r4];
#pragma unroll
    for (int tn = 0; tn < 8; tn++)
#pragma unroll
      for (int r4 = 0; r4 < 4; r4++) {
        int il = w * 16 + g * 4 + r4;
        int tau = tn * 16 + c, d = tau - dti_r4[r4];
        float val = Cacc[tn][r4];
        if (d <= -64) atomicAdd(&CLs[il][0], val);
        else if (d >= 64) atomicAdd(&CLs[il][128], val);
        else CLs[il][d + 64] = val;
      }
  }
  __syncthreads();

  float linv[4];
#pragma unroll
  for (int r4 = 0; r4 < 4; r4++) {
    float s = lsum[r4];
    for (int off = 1; off < 16; off <<= 1) s += __shfl_xor(s, off);
    linv[r4] = 1.0f / s;
  }

  f32x4 acc2[4] = {};
#pragma unroll
  for (int ks = 0; ks < 4; ks++) {
    const float* ap = &CLs[w * 16 + c][ks * 32 + g * 8];
    float4 a0 = *(const float4*)ap, a1 = *(const float4*)(ap + 4);
    bf16x8 af;
    af[0]=(__bf16)a0.x; af[1]=(__bf16)a0.y; af[2]=(__bf16)a0.z; af[3]=(__bf16)a0.w;
    af[4]=(__bf16)a1.x; af[5]=(__bf16)a1.y; af[6]=(__bf16)a1.z; af[7]=(__bf16)a1.w;
#pragma unroll
    for (int dn = 0; dn < 4; dn++) {
      bf16x8 bf = *(bf16x8*)&peT[dn * 16 + c][ks * 32 + g * 8];
      acc2[dn] = __builtin_amdgcn_mfma_f32_16x16x32_bf16(af, bf, acc2[dn], 0, 0, 0);
    }
  }
#pragma unroll
  for (int r4 = 0; r4 < 4; r4++) {
    int il = w * 16 + g * 4 + r4;
    float c128 = CLs[il][128];
#pragma unroll
    for (int dn = 0; dn < 4; dn++) {
      int d = dn * 16 + c;
      float y = acc2[dn][r4] + c128 * (float)peT[d][128];
      outb[((size_t)(b * SEQ + qbase + il)) * EDIM + h * HDIM + d] =
          (__bf16)((Oacc[dn][r4] + y) * linv[r4]);
    }
  }
}

// ---------------- layernorm over rows of 512; 4 rows/block; f32 and/or bf16 out
__global__ __launch_bounds__(256) void ln_kernel(
    const float* __restrict__ in, const float* __restrict__ g,
    const float* __restrict__ bta, float* __restrict__ out,
    __bf16* __restrict__ outb) {
  int row = blockIdx.x * 4 + (threadIdx.x >> 6), lane = threadIdx.x & 63;
  const float* p = in + (size_t)row * EDIM;
  float4 v0 = *(const float4*)(p + lane * 8);
  float4 v1 = *(const float4*)(p + lane * 8 + 4);
  float vals[8] = {v0.x, v0.y, v0.z, v0.w, v1.x, v1.y, v1.z, v1.w};
  float s = 0.f;
  for (int j = 0; j < 8; j++) s += vals[j];
  for (int o = 32; o; o >>= 1) s += __shfl_xor(s, o);
  float mu = s * (1.0f / EDIM);
  float vs = 0.f;
  for (int j = 0; j < 8; j++) {
    vals[j] -= mu;
    vs += vals[j] * vals[j];
  }
  for (int o = 32; o; o >>= 1) vs += __shfl_xor(vs, o);
  float rs = rsqrtf(vs * (1.0f / EDIM) + 1e-5f);
  for (int j = 0; j < 8; j++) {
    int col = lane * 8 + j;
    float v = vals[j] * rs * g[col] + bta[col];
    if (out) out[(size_t)row * EDIM + col] = v;
    if (outb) outb[(size_t)row * EDIM + col] = (__bf16)v;
  }
}

extern "C" void kernel_launch(void* const* d_in, const int* in_sizes, int n_in,
                              void* d_out, int out_size, void* d_ws, size_t ws_size,
                              hipStream_t stream) {
  const float* x = (const float*)d_in[0];
  const float* dist = (const float*)d_in[1];
  const int* dtimes = (const int*)d_in[2];
  const int* maskp = (const int*)d_in[3];
  const float* wq_w = (const float*)d_in[4];
  const float* wq_b = (const float*)d_in[5];
  const float* wk_w = (const float*)d_in[6];
  const float* wk_b = (const float*)d_in[7];
  const float* wv_w = (const float*)d_in[8];
  const float* wv_b = (const float*)d_in[9];
  const float* wo_w = (const float*)d_in[10];
  const float* wo_b = (const float*)d_in[11];
  const float* pos_emb = (const float*)d_in[12];
  const float* w1 = (const float*)d_in[13];
  const float* b1 = (const float*)d_in[14];
  const float* w2 = (const float*)d_in[15];
  const float* b2 = (const float*)d_in[16];
  const float* ln1_g = (const float*)d_in[17];
  const float* ln1_b = (const float*)d_in[18];
  const float* ln2_g = (const float*)d_in[19];
  const float* ln2_b = (const float*)d_in[20];
  float* out = (float*)d_out;

  const int M = TOKENS;
  const size_t T = TOKENS;
  float* fws = (float*)d_ws;

  // ---- workspace layout (f32 units), lifetime-aliased
  __bf16* qkvB   = (__bf16*)fws;                      // T*1536 bf16 = T*768 f32
  float*  ln2in  = fws;                               // alias (after attn)
  float*  wo_out = fws + T * 768;
  __bf16* attnob = (__bf16*)(fws + T * 2304);
  __bf16* hid    = (__bf16*)(fws + T * 2560);         // T*2048 bf16
  __bf16* attnb  = (__bf16*)(fws + T * 3584);
  __bf16* xb     = (__bf16*)(fws + T * 3840);
  __bf16* wqkvt  = (__bf16*)(fws + T * 4096);         // 786432 bf16
  __bf16* wot    = wqkvt + 1536 * 512;
  __bf16* w1t    = wot + 512 * 512;
  __bf16* w2t    = w1t + 512 * 2048;
  __bf16* distb  = w2t + 2048 * 512;                  // 2097152 bf16
  float*  qkvb   = (float*)(distb + 2097152);         // 1536 f32

  // ---- prep
  prep<<<5121, 256, 0, stream>>>(wq_w, wk_w, wv_w, wo_w, w1, w2, x, dist,
                                 wq_b, wk_b, wv_b,
                                 wqkvt, wot, w1t, w2t, xb, distb, qkvb);

  // ---- fused QKV projection (bf16 out): [4096x512] @ [512x1536]
  gemm128<64, 128><<<dim3(1536 / 128, M / 64), 256, 0, stream>>>(
      xb, wqkvt, qkvb, nullptr, nullptr, nullptr, qkvB, M, 1536, 512, 0);

  // ---- attention (qz fused in prologue; batch-XCD swizzle)
  attn_fused<<<512, 256, 0, stream>>>(qkvB, qkvB + 512, qkvB + 1024, distb,
                                      dtimes, maskp, pos_emb, attnb);

  // ---- output projection + residual, LN1 (bf16 out only)
  gemm128<64, 64><<<dim3(512 / 64, M / 64), 256, 0, stream>>>(
      attnb, wot, wo_b, x, nullptr, wo_out, nullptr, M, 512, 512, 0);
  ln_kernel<<<M / 4, 256, 0, stream>>>(wo_out, ln1_g, ln1_b, nullptr, attnob);

  // ---- FFN (w2 residual reads bf16 attnob)
  gemm128<64, 128><<<dim3(2048 / 128, M / 64), 256, 0, stream>>>(
      attnob, w1t, b1, nullptr, nullptr, nullptr, hid, M, 2048, 512, 1);
  gemm128<64, 64><<<dim3(512 / 64, M / 64), 256, 0, stream>>>(
      hid, w2t, b2, nullptr, attnob, ln2in, nullptr, M, 512, 2048, 0);
  ln_kernel<<<M / 4, 256, 0, stream>>>(ln2in, ln2_g, ln2_b, out, nullptr);
}